// Round 9
// baseline (9498.360 us; speedup 1.0000x reference)
//
#include <hip/hip_runtime.h>

typedef unsigned short ushort_t;
typedef unsigned int uint_t;
typedef float f32x4_t __attribute__((ext_vector_type(4)));
typedef short bf16x8_t __attribute__((ext_vector_type(8)));

// ---- problem constants ----
#define NBATCH 16
#define SMEM   256
#define TSTEPS 400

// ---- workspace layout (float offsets) ----
#define F_XSB   0u         // 400*16*256 bf16 = 819200 floats
#define F_PM    819200u    // 16*256*128 f32
#define F_MMIX  1343488u   // 16*81*256 f32 (M_b = Wctx . mem^T)
#define F_W1T   1675264u   // prenet W1T
#define F_W2T   1695744u
// ---- zeroed region ----
#define F_AHB   1761280u   // 2*16*1024 bf16 = 16384 floats
#define F_DHB   1777664u   // 16384
#define F_CTXB  1794048u   // 2*16*512 bf16 = 8192 floats
#define F_DHF   1802240u   // 2*16*1024 f32 = 32768
#define F_AWG   1835008u   // 4*16*256 f32 = 16384 (aw ring, slot t&3)
#define F_FLG   1851392u   // 344 slots * 16 ints = 5504 floats
#define ZERO_BASE  F_AHB
#define ZERO_COUNT 95616u
// ---- q-partials: [2 slots][64 blk][16 b][128 a] f32 = 262144 floats (1 MB) ----
#define F_QP    1856896u

// flag slot bases (stride 16 ints = 64B/slot: one line per flag)
#define AHF  0
#define CTXF 64     // 32 flags (merged ATT+CTX blocks)
#define DHFL 192
#define AWF  320
#define PRF  336

// ---- dynamic LDS layout (byte offsets); total 160000 B ----
// A-path:
#define A_AH    0        // 32768: ah [16][1024] bf16, swizzled
#define A_XS    49152    // 8192:  xs  [16][256] bf16, swizzled
#define A_RED   57344    // 4096:  cross-half reduce
#define A_QWQ   61440    // 8192:  Wq[:, bid*16..+16] f32 [128 a][16 c]
#define A_QH    69632    // 1024:  h(t) f32 [16 b][16 c]
// D-path:
#define D_AH    0        // 32768
#define D_CTX   32768    // 16384
#define D_DH    49152    // 32768
#define D_COMB  81920    // 6144
// merged ATT+CTX:
#define M_LOCU  0        // 20480
#define M_QSM   20480    // 512
#define M_VSM   20992    // 512
#define M_ESM   21504    // 1024
#define M_RED   22528    // 256
#define M_SMAW  22784    // 1024
#define M_SMAWC 23808    // 1024
#define M_MEM   24832    // 131072: mem[b] half [256 s][256 c] bf16
#define M_PART  155904   // 4096: ctx partials [4][256] f32; ALSO qred overlay (phase-disjoint)
// PROJ:
#define P_DHP   0        // 65536
#define P_AWP   65536    // 16384
#define SMEM_BYTES 160000

struct Ptrs {
  const float *memory, *dec_in, *Wpre1, *Wpre2, *Wih_a, *Whh_a, *bih_a, *bhh_a,
              *Wq, *Wm, *v, *Wc, *Wld, *Wih_d, *Whh_d, *bih_d, *bhh_d,
              *Wproj, *bproj, *Wgate, *bgate;
  const int *mlen;
  float *ws;
  float *out;
};

__device__ __forceinline__ float ftanh(float x) {
  float e = __expf(2.f * x);
  return 1.f - 2.f / (e + 1.f);
}
__device__ __forceinline__ float fsig(float x) { return 1.f / (1.f + __expf(-x)); }

__device__ __forceinline__ unsigned f2bfbits(float x) {
  unsigned u = __builtin_bit_cast(unsigned, x);
  return (u + 0x7FFFu + ((u >> 16) & 1u)) >> 16;
}
__device__ __forceinline__ float bf2f(ushort_t u) {
  unsigned v = ((unsigned)u) << 16;
  return __builtin_bit_cast(float, v);
}
__device__ __forceinline__ bf16x8_t packbf8(const float* f) {
  bf16x8_t r;
#pragma unroll
  for (int j = 0; j < 8; ++j) r[j] = (short)f2bfbits(f[j]);
  return r;
}
__device__ __forceinline__ bf16x8_t pack_from_f4(const float* src) {
  const float4* s4 = (const float4*)src;
  float4 lo = s4[0], hi = s4[1];
  float tmp[8] = {lo.x, lo.y, lo.z, lo.w, hi.x, hi.y, hi.z, hi.w};
  return packbf8(tmp);
}
__device__ __forceinline__ bf16x8_t ldbf8(const ushort_t* p) {
  return *(const bf16x8_t*)p;
}
__device__ __forceinline__ unsigned long long ldull_a(const unsigned long long* p) {
  return __hip_atomic_load(p, __ATOMIC_RELAXED, __HIP_MEMORY_SCOPE_AGENT);
}
struct ull2_t { unsigned long long x, y; };
__device__ __forceinline__ bf16x8_t ldbf8_a(const ushort_t* q) {
  ull2_t v;
  v.x = __hip_atomic_load((const unsigned long long*)q, __ATOMIC_RELAXED, __HIP_MEMORY_SCOPE_AGENT);
  v.y = __hip_atomic_load(((const unsigned long long*)q) + 1, __ATOMIC_RELAXED, __HIP_MEMORY_SCOPE_AGENT);
  return __builtin_bit_cast(bf16x8_t, v);
}
__device__ __forceinline__ void stull_a(unsigned long long* p, unsigned long long v) {
  __hip_atomic_store(p, v, __ATOMIC_RELAXED, __HIP_MEMORY_SCOPE_AGENT);
}
__device__ __forceinline__ void stf_a(float* p, float v) {
  __hip_atomic_store(p, v, __ATOMIC_RELAXED, __HIP_MEMORY_SCOPE_AGENT);
}
__device__ __forceinline__ float ldf_a(const float* p) {
  return __hip_atomic_load(p, __ATOMIC_RELAXED, __HIP_MEMORY_SCOPE_AGENT);
}
__device__ __forceinline__ void pollge(int* flg, int slot, int thr) {
  while (__hip_atomic_load(flg + slot * 16, __ATOMIC_RELAXED, __HIP_MEMORY_SCOPE_AGENT) < thr)
    __builtin_amdgcn_s_sleep(1);
}
__device__ __forceinline__ void sig(int* flg, int slot, int val) {
  __hip_atomic_store(flg + slot * 16, val, __ATOMIC_RELAXED, __HIP_MEMORY_SCOPE_AGENT);
}
// swizzled LDS helpers: byte ^= ((row&7)<<4)
__device__ __forceinline__ void lds_st8(char* smc, int base, int row, int row_sh,
                                        int bytecol, unsigned long long v) {
  *(unsigned long long*)(smc + base + (row << row_sh) + (bytecol ^ ((row & 7) << 4))) = v;
}
__device__ __forceinline__ bf16x8_t lds_bf8(const char* smc, int base, int row,
                                            int row_sh, int bytecol) {
  return *(const bf16x8_t*)(smc + base + (row << row_sh) + (bytecol ^ ((row & 7) << 4)));
}
#define MFMA16(a,b,c) __builtin_amdgcn_mfma_f32_16x16x32_bf16((a),(b),(c),0,0,0)

// ---------------- zero state ----------------
__global__ __launch_bounds__(256) void k_zero(Ptrs p) {
  unsigned i = blockIdx.x * 256 + threadIdx.x;
  if (i < ZERO_COUNT) p.ws[ZERO_BASE + i] = 0.f;
}

// ---------------- weight transposes for prenet ----------------
__global__ __launch_bounds__(256) void k_transpose(Ptrs p) {
  int i = blockIdx.x * 256 + threadIdx.x;
  if (i < 20480) {
    int m = i >> 8, c = i & 255;
    p.ws[F_W1T + i] = p.Wpre1[c * 80 + m];
  } else if (i < 20480 + 65536) {
    int j = i - 20480;
    int pp = j >> 8, q = j & 255;
    p.ws[F_W2T + j] = p.Wpre2[q * 256 + pp];
  }
}

// ---------------- prenet -> xsb (bf16) ----------------
__global__ __launch_bounds__(256) void k_prenet(Ptrs p) {
  __shared__ float dil[NBATCH * 80];
  __shared__ float h1[NBATCH * 256];
  const int t = blockIdx.x, tid = threadIdx.x;
  const float* W1T = p.ws + F_W1T;
  const float* W2T = p.ws + F_W2T;

  for (int i = tid; i < NBATCH * 80; i += 256) {
    int b = i / 80, m = i - b * 80;
    dil[i] = (t == 0) ? 0.f : p.dec_in[((size_t)b * 80 + m) * 400 + (t - 1)];
  }
  __syncthreads();

  float acc[NBATCH];
#pragma unroll
  for (int b = 0; b < NBATCH; ++b) acc[b] = 0.f;
  for (int m = 0; m < 80; ++m) {
    float w = W1T[m * 256 + tid];
#pragma unroll
    for (int b = 0; b < NBATCH; ++b) acc[b] = fmaf(dil[b * 80 + m], w, acc[b]);
  }
#pragma unroll
  for (int b = 0; b < NBATCH; ++b) h1[b * 256 + tid] = fmaxf(acc[b], 0.f);
  __syncthreads();

#pragma unroll
  for (int b = 0; b < NBATCH; ++b) acc[b] = 0.f;
  for (int q = 0; q < 256; ++q) {
    float w = W2T[q * 256 + tid];
#pragma unroll
    for (int b = 0; b < NBATCH; ++b) acc[b] = fmaf(h1[b * 256 + q], w, acc[b]);
  }
  ushort_t* xsbU = (ushort_t*)(p.ws + F_XSB);
#pragma unroll
  for (int b = 0; b < NBATCH; ++b)
    xsbU[((size_t)(t * NBATCH + b)) * 256 + tid] = (ushort_t)f2bfbits(fmaxf(acc[b], 0.f));
}

// ---------------- proc_mem fp32 ----------------
__global__ __launch_bounds__(256) void k_procmem(Ptrs p) {
  __shared__ alignas(16) float msl[16 * 512];
  const int b = blockIdx.x >> 4, s0 = (blockIdx.x & 15) << 4;
  const int tid = threadIdx.x;
  const float4* src = (const float4*)(p.memory + ((size_t)(b * SMEM + s0)) * 512);
  float4* dst = (float4*)msl;
  for (int i = tid; i < 16 * 512 / 4; i += 256) dst[i] = src[i];
  __syncthreads();

  const int a = tid & 127, sg = tid >> 7;
  const float4* wm = (const float4*)(p.Wm + (size_t)a * 512);
  float* pm = p.ws + F_PM;
  float acc[8];
#pragma unroll
  for (int j = 0; j < 8; ++j) acc[j] = 0.f;
  for (int k = 0; k < 128; ++k) {
    float4 w = wm[k];
#pragma unroll
    for (int j = 0; j < 8; ++j) {
      float4 m = ((const float4*)(msl + (size_t)(sg * 8 + j) * 512))[k];
      acc[j] += w.x * m.x + w.y * m.y + w.z * m.z + w.w * m.w;
    }
  }
#pragma unroll
  for (int j = 0; j < 8; ++j)
    pm[((size_t)(b * SMEM + s0 + sg * 8 + j)) * 128 + a] = acc[j];
}

// ---------------- premix: M[b][row][s] = Wctx[row][:] . memory[b][s][:] ----------------
__global__ __launch_bounds__(512) void k_premix(Ptrs p) {
  const int b = blockIdx.x, tid = threadIdx.x;
  float* M = p.ws + F_MMIX;
  for (int i = tid; i < 81 * 256; i += 512) {
    int row = i >> 8, s = i & 255;
    const float* wrow = (row < 80) ? p.Wproj + (size_t)row * 1536 + 1024 : p.Wgate + 1024;
    const float4* w4 = (const float4*)wrow;
    const float4* m4 = (const float4*)(p.memory + ((size_t)(b * 256 + s)) * 512);
    float acc = 0.f;
#pragma unroll 4
    for (int k = 0; k < 128; ++k) {
      float4 w = w4[k], m = m4[k];
      acc += w.x * m.x + w.y * m.y + w.z * m.z + w.w * m.w;
    }
    M[((size_t)b * 81 + row) * 256 + s] = acc;
  }
}

// ---------------- persistent dataflow scan: 232 blocks x 512 threads ----------------
// Cycle (2 hops): A(ah+qp) -> MERGED(aw+ctx) -> A. D/PROJ fully off-cycle
// (write-guards moved to the writes, so D's latency no longer gates A/MERGED).
__global__ __launch_bounds__(512, 1) void k_scan(Ptrs p) {
  extern __shared__ char smc[];
  const int bid = blockIdx.x, tid = threadIdx.x;
  const int wid = tid >> 6, lane = tid & 63;
  const int m16 = lane & 15, kq = lane >> 4;

  float* ws = p.ws;
  ushort_t* xsbU  = (ushort_t*)(ws + F_XSB);
  float*    pmF   = ws + F_PM;
  float*    Mx    = ws + F_MMIX;
  unsigned long long* ahb8 = (unsigned long long*)(ws + F_AHB);
  unsigned long long* dhb8 = (unsigned long long*)(ws + F_DHB);
  unsigned long long* ctxb8 = (unsigned long long*)(ws + F_CTXB);
  float*    dhfF  = ws + F_DHF;
  float*    awGF  = ws + F_AWG;
  float*    qpF   = ws + F_QP;
  int*      flg   = (int*)(ws + F_FLG);
  float* out_mel  = p.out;
  float* out_gate = p.out + 512000;
  float* out_al   = p.out + 518400;

  if (bid < 64) {
    // ======== A-path: A-LSTM(t) + q-partials ========
    // chunk split: half0 = xs0-7 + ah0-11 | ctx0-7 ; half1 = ah12-31 | ctx8-15
    const int ls = wid >> 1, half = wid & 1;
    const int strip = (bid << 2) | ls;
    const int gA = m16 & 3, jA = m16 >> 2;
    const int wrowA = gA * 1024 + strip * 4 + jA;
    bf16x8_t wA[28];
#pragma unroll
    for (int c = 0; c < 28; ++c) {
      int k0; const float* base;
      if (half == 0) {
        if (c < 8)       { k0 = c * 32;              base = p.Wih_a + (size_t)wrowA * 768; }
        else if (c < 20) { k0 = (c - 8) * 32;        base = p.Whh_a + (size_t)wrowA * 1024; }
        else             { k0 = 256 + (c - 20) * 32; base = p.Wih_a + (size_t)wrowA * 768; }
      } else {
        if (c < 20)      { k0 = (12 + c) * 32;       base = p.Whh_a + (size_t)wrowA * 1024; }
        else             { k0 = 256 + (c - 12) * 32; base = p.Wih_a + (size_t)wrowA * 768; }
      }
      wA[c] = pack_from_f4(base + k0 + kq * 8);
    }
    const int nnA = strip * 4 + kq;
    float biasA[4];
#pragma unroll
    for (int r = 0; r < 4; ++r) biasA[r] = p.bih_a[r * 1024 + nnA] + p.bhh_a[r * 1024 + nnA];
    float acState = 0.f;
    float* ared = (float*)(smc + A_RED);
    float* qwq  = (float*)(smc + A_QWQ);
    float* qh   = (float*)(smc + A_QH);
    for (int i = tid; i < 2048; i += 512) {
      int a = i >> 4, c = i & 15;
      qwq[i] = p.Wq[(size_t)a * 1024 + bid * 16 + c];
    }
    __syncthreads();

    for (int t = 0; t < TSTEPS; ++t) {
      const int pc = t & 1, pp = (t + 1) & 1;
      // start poll: ah(t-1) peers only (D guard moved to the write)
      if (tid < 64) pollge(flg, AHF + tid, t);
      __syncthreads();
      // stage ah(t-1) + xs(t)
      {
        const unsigned long long* ag = ahb8 + (size_t)pp * 4096;
        const unsigned long long* xg = (const unsigned long long*)xsbU + (size_t)t * 1024;
        unsigned long long tA[8], tX[2];
#pragma unroll
        for (int i = 0; i < 8; ++i) tA[i] = ldull_a(ag + tid + i * 512);
#pragma unroll
        for (int i = 0; i < 2; ++i) tX[i] = xg[tid + i * 512];
#pragma unroll
        for (int i = 0; i < 8; ++i) { int u = tid + i * 512; lds_st8(smc, A_AH, u >> 8, 11, (u & 255) * 8, tA[i]); }
#pragma unroll
        for (int i = 0; i < 2; ++i) { int u = tid + i * 512; lds_st8(smc, A_XS, u >> 6, 9, (u & 63) * 8, tX[i]); }
      }
      __syncthreads();
      // MFMA phase 1: pre-ctx chunks (runs while MERGED computes aw/ctx)
      f32x4_t a0 = {0,0,0,0}, a1 = {0,0,0,0};
      if (half == 0) {
#pragma unroll
        for (int c = 0; c < 8; ++c) {
          bf16x8_t bf = lds_bf8(smc, A_XS, m16, 9, c * 64 + kq * 16);
          if (c & 1) a1 = MFMA16(wA[c], bf, a1); else a0 = MFMA16(wA[c], bf, a0);
        }
#pragma unroll
        for (int c = 8; c < 20; ++c) {
          bf16x8_t bf = lds_bf8(smc, A_AH, m16, 11, (c - 8) * 64 + kq * 16);
          if (c & 1) a1 = MFMA16(wA[c], bf, a1); else a0 = MFMA16(wA[c], bf, a0);
        }
      } else {
#pragma unroll
        for (int c = 0; c < 20; ++c) {
          bf16x8_t bf = lds_bf8(smc, A_AH, m16, 11, (12 + c) * 64 + kq * 16);
          if (c & 1) a1 = MFMA16(wA[c], bf, a1); else a0 = MFMA16(wA[c], bf, a0);
        }
      }
      // ctx(t-1) ready?
      if (tid < 32) pollge(flg, CTXF + tid, t);
      __syncthreads();
      // MFMA phase 2: direct agent-scope ctx fragment loads, 8 chunks per half
      {
        const ushort_t* cbase = (const ushort_t*)(ctxb8 + (size_t)pp * 2048) + m16 * 512;
#pragma unroll
        for (int c = 20; c < 28; ++c) {
          int cc = (half == 0) ? (c - 20) : (c - 12);
          bf16x8_t bf = ldbf8_a(cbase + cc * 32 + kq * 8);
          if (c & 1) a1 = MFMA16(wA[c], bf, a1); else a0 = MFMA16(wA[c], bf, a0);
        }
      }
      if (half == 1) {
#pragma unroll
        for (int r = 0; r < 4; ++r) ared[((ls * 64 + lane) << 2) + r] = a0[r] + a1[r];
      }
      __syncthreads();
      unsigned long long ahb_u = 0ull;
      if (half == 0) {
        float z[4];
#pragma unroll
        for (int r = 0; r < 4; ++r)
          z[r] = a0[r] + a1[r] + ared[((ls * 64 + lane) << 2) + r] + biasA[r];
        float cn = fsig(z[1]) * acState + fsig(z[0]) * ftanh(z[2]);
        acState = cn;
        float h = fsig(z[3]) * ftanh(cn);
        qh[(m16 << 4) + ls * 4 + kq] = h;
        unsigned hb = f2bfbits(h);
        unsigned b0 = __shfl(hb, m16);
        unsigned b1 = __shfl(hb, m16 + 16);
        unsigned b2 = __shfl(hb, m16 + 32);
        unsigned b3 = __shfl(hb, m16 + 48);
        if (kq == 0)
          ahb_u = (unsigned long long)(b0 | (b1 << 16))
                | ((unsigned long long)(b2 | (b3 << 16)) << 32);
      }
      // D(t-1) write-guard: ahb slot pc overwrite needs D(t-1)'s ah(t-2) stage done.
      // Pre-satisfied in steady state (D had A's whole iteration to finish).
      if (tid < 128) pollge(flg, DHFL + tid, t - 1);
      __syncthreads();
      if (half == 0 && kq == 0)
        stull_a(ahb8 + ((size_t)(pc * 16 + m16)) * 256 + strip, ahb_u);
      // q-partials: qp[blk][b][a] = sum_c Wq[a][blk*16+c] * h[b][blk*16+c]
      {
        int a = tid & 127, bg = tid >> 7;
        const float* wrow = qwq + a * 16;
        float s0 = 0.f, s1 = 0.f, s2 = 0.f, s3 = 0.f;
#pragma unroll
        for (int c = 0; c < 16; ++c) {
          float wv = wrow[c];
          s0 = fmaf(wv, qh[((bg * 4 + 0) << 4) + c], s0);
          s1 = fmaf(wv, qh[((bg * 4 + 1) << 4) + c], s1);
          s2 = fmaf(wv, qh[((bg * 4 + 2) << 4) + c], s2);
          s3 = fmaf(wv, qh[((bg * 4 + 3) << 4) + c], s3);
        }
        float* qps = qpF + (size_t)pc * 131072 + bid * 2048 + a;
        stf_a(qps + (size_t)(bg * 4 + 0) * 128, s0);
        stf_a(qps + (size_t)(bg * 4 + 1) * 128, s1);
        stf_a(qps + (size_t)(bg * 4 + 2) * 128, s2);
        stf_a(qps + (size_t)(bg * 4 + 3) * 128, s3);
      }
      __syncthreads();   // drains ahb + qp stores before flag
      if (tid == 0) sig(flg, AHF + bid, t + 1);
    }
  } else if (bid < 192) {
    // ======== D-path: pure D-LSTM(t-1) ========
    const int ls = wid >> 2, qt = wid & 3;
    const int strip = ((bid - 64) << 1) | ls;
    const int gD = m16 & 3, jD = m16 >> 2;
    const int wrowD = gD * 1024 + strip * 4 + jD;
    bf16x8_t wD[20];
#pragma unroll
    for (int c = 0; c < 20; ++c) {
      int k0 = (qt * 20 + c) * 32 + kq * 8;
      const float* src = (k0 < 1536) ? p.Wih_d + (size_t)wrowD * 1536 + k0
                                     : p.Whh_d + (size_t)wrowD * 1024 + (k0 - 1536);
      wD[c] = pack_from_f4(src);
    }
    const int nnD = strip * 4 + kq;
    float biasD[4];
#pragma unroll
    for (int r = 0; r < 4; ++r) biasD[r] = p.bih_d[r * 1024 + nnD] + p.bhh_d[r * 1024 + nnD];
    float dcState = 0.f;
    float* comb = (float*)(smc + D_COMB);
    __syncthreads();

    for (int t = 1; t <= TSTEPS; ++t) {
      const int pc = t & 1, pw = (t + 1) & 1;
      if (tid < 64) pollge(flg, AHF + tid, t);
      else if (tid >= 96 && tid < 224) pollge(flg, DHFL + (tid - 96), t - 1);
      else if (tid >= 224 && tid < 232) pollge(flg, PRF + (tid - 224), t - 2);
      __syncthreads();
      {
        const unsigned long long* ag = ahb8 + (size_t)pw * 4096;
        const unsigned long long* dg = dhb8 + (size_t)pc * 4096;
        unsigned long long tA[8], tD[8];
#pragma unroll
        for (int i = 0; i < 8; ++i) tA[i] = ldull_a(ag + tid + i * 512);
#pragma unroll
        for (int i = 0; i < 8; ++i) tD[i] = ldull_a(dg + tid + i * 512);
#pragma unroll
        for (int i = 0; i < 8; ++i) { int u = tid + i * 512; lds_st8(smc, D_AH, u >> 8, 11, (u & 255) * 8, tA[i]); }
#pragma unroll
        for (int i = 0; i < 8; ++i) { int u = tid + i * 512; lds_st8(smc, D_DH, u >> 8, 11, (u & 255) * 8, tD[i]); }
      }
      if (tid >= 64 && tid < 96) pollge(flg, CTXF + (tid - 64), t);
      __syncthreads();
      {
        const unsigned long long* cg = ctxb8 + (size_t)pw * 2048;
        unsigned long long tC[4];
#pragma unroll
        for (int i = 0; i < 4; ++i) tC[i] = ldull_a(cg + tid + i * 512);
#pragma unroll
        for (int i = 0; i < 4; ++i) { int u = tid + i * 512; lds_st8(smc, D_CTX, u >> 7, 10, (u & 127) * 8, tC[i]); }
      }
      __syncthreads();

      f32x4_t a0 = {0,0,0,0}, a1 = {0,0,0,0};
#define DFRAG_AH(ch)  lds_bf8(smc, D_AH,  m16, 11, (ch) * 64 + kq * 16)
#define DFRAG_CTX(ch) lds_bf8(smc, D_CTX, m16, 10, (ch) * 64 + kq * 16)
#define DFRAG_DH(ch)  lds_bf8(smc, D_DH,  m16, 11, (ch) * 64 + kq * 16)
#define DMFMA(BF) { bf16x8_t bf = (BF); \
        if (c & 1) a1 = MFMA16(wD[c], bf, a1); else a0 = MFMA16(wD[c], bf, a0); }
      if (qt == 0) {
#pragma unroll
        for (int c = 0; c < 20; ++c) DMFMA(DFRAG_AH(c))
      } else if (qt == 1) {
#pragma unroll
        for (int c = 0; c < 20; ++c) { if (c < 12) DMFMA(DFRAG_AH(20 + c)) else DMFMA(DFRAG_CTX(c - 12)) }
      } else if (qt == 2) {
#pragma unroll
        for (int c = 0; c < 20; ++c) { if (c < 8) DMFMA(DFRAG_CTX(8 + c)) else DMFMA(DFRAG_DH(c - 8)) }
      } else {
#pragma unroll
        for (int c = 0; c < 20; ++c) DMFMA(DFRAG_DH(12 + c))
      }
#undef DMFMA
      if (qt != 0) {
#pragma unroll
        for (int r = 0; r < 4; ++r)
          comb[(((ls * 3 + qt - 1) * 64 + lane) << 2) + r] = a0[r] + a1[r];
      }
      __syncthreads();
      if (qt == 0) {
        float z[4];
#pragma unroll
        for (int r = 0; r < 4; ++r) {
          z[r] = a0[r] + a1[r] + biasD[r];
#pragma unroll
          for (int j = 0; j < 3; ++j) z[r] += comb[(((ls * 3 + j) * 64 + lane) << 2) + r];
        }
        float cn = fsig(z[1]) * dcState + fsig(z[0]) * ftanh(z[2]);
        dcState = cn;
        float h = fsig(z[3]) * ftanh(cn);
        stf_a(dhfF + (size_t)pw * 16384 + m16 * 1024 + nnD, h);
        unsigned hb = f2bfbits(h);
        unsigned b0 = __shfl(hb, m16);
        unsigned b1 = __shfl(hb, m16 + 16);
        unsigned b2 = __shfl(hb, m16 + 32);
        unsigned b3 = __shfl(hb, m16 + 48);
        if (kq == 0) {
          unsigned long long u = (unsigned long long)(b0 | (b1 << 16))
                               | ((unsigned long long)(b2 | (b3 << 16)) << 32);
          stull_a(dhb8 + ((size_t)(pw * 16 + m16)) * 256 + strip, u);
        }
      }
      __syncthreads();
      if (tid == 0) sig(flg, DHFL + (bid - 64), t);
    }
  } else if (bid < 224) {
    // ======== MERGED ATT+CTX: 2 blocks/batch; e/softmax duplicated + ctx half ========
    const int cbid = bid - 192;              // 0..31
    const int b = cbid >> 1, h2 = cbid & 1;
    const int mlenb = p.mlen[b];
    ushort_t* locu = (ushort_t*)(smc + M_LOCU);
    float* qsm   = (float*)(smc + M_QSM);
    float* vsm   = (float*)(smc + M_VSM);
    float* esm   = (float*)(smc + M_ESM);
    float* red   = (float*)(smc + M_RED);
    float* smaw  = (float*)(smc + M_SMAW);
    float* smawc = (float*)(smc + M_SMAWC);
    ushort_t* memu2 = (ushort_t*)(smc + M_MEM);
    float* part  = (float*)(smc + M_PART);
    float* qred  = part;   // overlay: qred (q phase) / part (ctx phase) time-disjoint

    bf16x8_t wLd[8];
#pragma unroll
    for (int at = 0; at < 8; ++at)
      wLd[at] = pack_from_f4(p.Wld + ((size_t)(at * 16 + m16)) * 32 + kq * 8);
    bf16x8_t wC[2][2];
#pragma unroll
    for (int ft = 0; ft < 2; ++ft)
#pragma unroll
      for (int ck = 0; ck < 2; ++ck) {
        float tmp[8];
#pragma unroll
        for (int jj = 0; jj < 8; ++jj) {
          int k2 = ck * 32 + kq * 8 + jj;
          float vv = 0.f;
          if (k2 < 62) { int ch = (k2 < 31) ? 0 : 1; int k = k2 - 31 * ch;
            vv = p.Wc[((size_t)(ft * 16 + m16) * 2 + ch) * 31 + k]; }
          tmp[jj] = vv;
        }
        wC[ft][ck] = packbf8(tmp);
      }
    uint_t pmreg[2][8][2];
#pragma unroll
    for (int u = 0; u < 2; ++u) {
      int sloc = (wid * 2 + u) * 16 + m16;
#pragma unroll
      for (int at = 0; at < 8; ++at)
#pragma unroll
        for (int rp = 0; rp < 2; ++rp) {
          const float* src = pmF + ((size_t)(b * 256 + sloc)) * 128 + at * 16 + kq * 4 + rp * 2;
          pmreg[u][at][rp] = f2bfbits(src[0]) | (f2bfbits(src[1]) << 16);
        }
    }
    // one-time: stage mem[b][:, h2*256 .. +256] as bf16
    for (int i = tid; i < 16384; i += 512) {
      int s = i >> 6, c4 = i & 63;
      float4 m = *(const float4*)(p.memory + ((size_t)(b * 256 + s)) * 512 + h2 * 256 + c4 * 4);
      ushort_t* dst = memu2 + s * 256 + c4 * 4;
      dst[0] = (ushort_t)f2bfbits(m.x);
      dst[1] = (ushort_t)f2bfbits(m.y);
      dst[2] = (ushort_t)f2bfbits(m.z);
      dst[3] = (ushort_t)f2bfbits(m.w);
    }
    if (tid < 128) vsm[tid] = p.v[tid];
    if (tid < 256) { smaw[tid] = 0.f; smawc[tid] = 0.f; }
    __syncthreads();

    for (int t = 0; t < TSTEPS; ++t) {
      const int pc = t & 1;
      // conv(t) from own-LDS aw/awc (prev step): overlaps the ah wait
#pragma unroll
      for (int u = 0; u < 4; ++u) {
        int task = wid * 4 + u;
        int stile = task >> 1, ft = task & 1;
        int scol = stile * 16 + m16;
        f32x4_t acc = {0,0,0,0};
#pragma unroll
        for (int ck = 0; ck < 2; ++ck) {
          float tmp[8];
#pragma unroll
          for (int jj = 0; jj < 8; ++jj) {
            int k2 = ck * 32 + kq * 8 + jj;
            float vv = 0.f;
            if (k2 < 62) {
              int ch = (k2 < 31) ? 0 : 1; int k = k2 - 31 * ch;
              int sp = scol + k - 15;
              if (sp >= 0 && sp < 256) vv = (ch ? smawc : smaw)[sp];
            }
            tmp[jj] = vv;
          }
          acc = MFMA16(wC[ft][ck], packbf8(tmp), acc);
        }
#pragma unroll
        for (int r = 0; r < 4; ++r)
          locu[scol * 40 + ft * 16 + kq * 4 + r] = (ushort_t)f2bfbits(acc[r]);
      }
      // start polls: ah(t)+qp fresh; PRF (awGF ring). D guard moved to ctx store.
      if (tid < 64) pollge(flg, AHF + tid, t + 1);
      else if (tid < 72) pollge(flg, PRF + (tid - 64), t - 3);
      __syncthreads();
      // q[b] = sum over 64 A-block partials
      {
        int a = tid & 127, g = tid >> 7;
        const float* qps = qpF + (size_t)(t & 1) * 131072 + b * 128 + a;
        float s = 0.f;
#pragma unroll
        for (int k = 0; k < 16; ++k)
          s += ldf_a(qps + (size_t)(g * 16 + k) * 2048);
        qred[g * 128 + a] = s;
      }
      __syncthreads();
      if (tid < 128) qsm[tid] = qred[tid] + qred[128 + tid] + qred[256 + tid] + qred[384 + tid];
      __syncthreads();
      // fused pa+e: 2 s-tiles per wave
#pragma unroll
      for (int u = 0; u < 2; ++u) {
        int sloc = (wid * 2 + u) * 16 + m16;
        bf16x8_t Bfrag = ldbf8(locu + sloc * 40 + kq * 8);
        float eacc = 0.f;
#pragma unroll
        for (int at = 0; at < 8; ++at) {
          f32x4_t C = {0,0,0,0};
          C = MFMA16(wLd[at], Bfrag, C);
#pragma unroll
          for (int r = 0; r < 4; ++r) {
            int a = at * 16 + kq * 4 + r;
            uint_t pw_ = pmreg[u][at][r >> 1];
            float pmv = bf2f((ushort_t)((r & 1) ? (pw_ >> 16) : (pw_ & 0xFFFF)));
            eacc = fmaf(vsm[a], ftanh(C[r] + qsm[a] + pmv), eacc);
          }
        }
        eacc += __shfl_xor(eacc, 16);
        eacc += __shfl_xor(eacc, 32);
        if (sloc >= mlenb) eacc = -1.0e9f;
        if (kq == 0) esm[sloc] = eacc;
      }
      __syncthreads();
      // softmax over 256
      float ev = 0.f;
      if (tid < 256) {
        ev = esm[tid];
        float mv = ev;
        for (int o = 32; o; o >>= 1) mv = fmaxf(mv, __shfl_xor(mv, o));
        if (lane == 0) red[wid] = mv;
      }
      __syncthreads();
      float gmax = fmaxf(fmaxf(red[0], red[1]), fmaxf(red[2], red[3]));
      float pv = 0.f;
      if (tid < 256) {
        pv = __expf(ev - gmax);
        float sv = pv;
        for (int o = 32; o; o >>= 1) sv += __shfl_xor(sv, o);
        if (lane == 0) red[8 + wid] = sv;
      }
      __syncthreads();
      float gsum = red[8] + red[9] + red[10] + red[11];
      float awv = 0.f;
      if (tid < 256) {
        awv = pv / gsum;
        smaw[tid] = awv;
        smawc[tid] += awv;
        if (h2 == 0) stf_a(awGF + (size_t)(t & 3) * 4096 + b * 256 + tid, awv);
      }
      __syncthreads();
      // ctx(t) half = aw(t) . mem[b][:, h2*256..+256]  (all in LDS)
      {
        const int c = tid & 127, sg = tid >> 7;
        const uint_t* mrow = (const uint_t*)memu2;
        float c0 = 0.f, c1 = 0.f;
#pragma unroll 8
        for (int si = 0; si < 64; ++si) {
          int s = sg * 64 + si;
          uint_t mm = mrow[s * 128 + c];
          float av = smaw[s];
          c0 = fmaf(bf2f((ushort_t)(mm & 0xFFFF)), av, c0);
          c1 = fmaf(bf2f((ushort_t)(mm >> 16)), av, c1);
        }
        part[sg * 256 + c * 2] = c0;
        part[sg * 256 + c * 2 + 1] = c1;
      }
      // D(t-1) write-guard before ctxb slot overwrite (pre-satisfied in steady state)
      if (tid < 128) pollge(flg, DHFL + tid, t - 1);
      __syncthreads();
      if (tid < 64) {
        unsigned pk[4];
#pragma unroll
        for (int j = 0; j < 4; ++j) {
          int col = tid * 4 + j;
          float v = part[col] + part[256 + col] + part[512 + col] + part[768 + col];
          pk[j] = f2bfbits(v);
        }
        unsigned long long u = (unsigned long long)(pk[0] | (pk[1] << 16))
                             | ((unsigned long long)(pk[2] | (pk[3] << 16)) << 32);
        stull_a(ctxb8 + ((size_t)(pc * 16 + b)) * 128 + h2 * 64 + tid, u);
      }
      __syncthreads();   // drain ctxb + awGF stores
      if (tid == 0) {
        sig(flg, CTXF + cbid, t + 1);
        if (h2 == 0) sig(flg, AWF + b, t + 1);
      }
      // off-path output store
      if (h2 == 0 && tid < 256) out_al[((size_t)b * 400 + t) * 256 + tid] = awv;
    }
  } else if (bid < 232) {
    // ======== PROJ path: mel/gate = Wdh.dh(t-1) + M.aw(t-1) + bias ========
    const int wv = (bid - 224) * 8 + wid;   // 0..63
    int rows[2] = {wv * 2, wv * 2 + 1};
    float wdh[2][16], mreg[2][16][4], biasr[2];
#pragma unroll
    for (int rr = 0; rr < 2; ++rr) {
      int row = rows[rr];
      biasr[rr] = 0.f;
#pragma unroll
      for (int j = 0; j < 16; ++j) wdh[rr][j] = 0.f;
#pragma unroll
      for (int b2 = 0; b2 < 16; ++b2)
#pragma unroll
        for (int j = 0; j < 4; ++j) mreg[rr][b2][j] = 0.f;
      if (row <= 80) {
        const float* wsrc = (row < 80) ? p.Wproj + (size_t)row * 1536 : p.Wgate;
#pragma unroll
        for (int j = 0; j < 16; ++j) wdh[rr][j] = wsrc[lane + 64 * j];
        biasr[rr] = (row < 80) ? p.bproj[row] : p.bgate[0];
#pragma unroll
        for (int b2 = 0; b2 < 16; ++b2)
#pragma unroll
          for (int j = 0; j < 4; ++j)
            mreg[rr][b2][j] = Mx[((size_t)b2 * 81 + row) * 256 + lane + 64 * j];
      }
    }
    float* dhp = (float*)(smc + P_DHP);
    float* awp = (float*)(smc + P_AWP);
    __syncthreads();
    for (int t = 1; t <= TSTEPS; ++t) {
      const int pw = (t + 1) & 1;
      if (tid < 128) pollge(flg, DHFL + tid, t);
      else if (tid < 144) pollge(flg, AWF + tid - 128, t);
      __syncthreads();
      {
        const unsigned long long* ag = (const unsigned long long*)(awGF + (size_t)((t - 1) & 3) * 4096);
        const unsigned long long* dg = (const unsigned long long*)(dhfF + (size_t)pw * 16384);
        unsigned long long tw[4], td[16];
#pragma unroll
        for (int i = 0; i < 4; ++i) tw[i] = ldull_a(ag + tid + i * 512);
#pragma unroll
        for (int i = 0; i < 16; ++i) td[i] = ldull_a(dg + tid + i * 512);
#pragma unroll
        for (int i = 0; i < 4; ++i) ((unsigned long long*)awp)[tid + i * 512] = tw[i];
#pragma unroll
        for (int i = 0; i < 16; ++i) ((unsigned long long*)dhp)[tid + i * 512] = td[i];
      }
      __syncthreads();
      if (wv <= 40) {
        for (int b2 = 0; b2 < 16; ++b2) {
          float h[16];
#pragma unroll
          for (int j = 0; j < 16; ++j) h[j] = dhp[b2 * 1024 + lane + 64 * j];
#pragma unroll
          for (int rr = 0; rr < 2; ++rr) {
            if (rows[rr] > 80) continue;
            float d = 0.f;
#pragma unroll
            for (int j = 0; j < 16; ++j) d = fmaf(wdh[rr][j], h[j], d);
#pragma unroll
            for (int j = 0; j < 4; ++j) d = fmaf(mreg[rr][b2][j], awp[b2 * 256 + lane + 64 * j], d);
            for (int o = 32; o; o >>= 1) d += __shfl_xor(d, o);
            if (lane == 0) {
              d += biasr[rr];
              if (rows[rr] < 80) out_mel[((size_t)b2 * 80 + rows[rr]) * 400 + (t - 1)] = d;
              else out_gate[(size_t)b2 * 400 + (t - 1)] = d;
            }
          }
        }
      }
      __syncthreads();
      if (tid == 0) sig(flg, PRF + (bid - 224), t);
    }
  }
}

extern "C" void kernel_launch(void* const* d_in, const int* in_sizes, int n_in,
                              void* d_out, int out_size, void* d_ws, size_t ws_size,
                              hipStream_t stream) {
  (void)in_sizes; (void)n_in; (void)out_size; (void)ws_size;
  Ptrs p;
  p.memory = (const float*)d_in[0];
  p.dec_in = (const float*)d_in[1];
  p.Wpre1  = (const float*)d_in[2];
  p.Wpre2  = (const float*)d_in[3];
  p.Wih_a  = (const float*)d_in[4];
  p.Whh_a  = (const float*)d_in[5];
  p.bih_a  = (const float*)d_in[6];
  p.bhh_a  = (const float*)d_in[7];
  p.Wq     = (const float*)d_in[8];
  p.Wm     = (const float*)d_in[9];
  p.v      = (const float*)d_in[10];
  p.Wc     = (const float*)d_in[11];
  p.Wld    = (const float*)d_in[12];
  p.Wih_d  = (const float*)d_in[13];
  p.Whh_d  = (const float*)d_in[14];
  p.bih_d  = (const float*)d_in[15];
  p.bhh_d  = (const float*)d_in[16];
  p.Wproj  = (const float*)d_in[17];
  p.bproj  = (const float*)d_in[18];
  p.Wgate  = (const float*)d_in[19];
  p.bgate  = (const float*)d_in[20];
  p.mlen   = (const int*)d_in[21];
  p.ws  = (float*)d_ws;
  p.out = (float*)d_out;

  static bool attr_done = false;
  if (!attr_done) {
    hipFuncSetAttribute((const void*)k_scan,
                        hipFuncAttributeMaxDynamicSharedMemorySize, SMEM_BYTES);
    attr_done = true;
  }

  hipLaunchKernelGGL(k_zero,      dim3((ZERO_COUNT + 255) / 256), dim3(256), 0, stream, p);
  hipLaunchKernelGGL(k_transpose, dim3(336), dim3(256), 0, stream, p);
  hipLaunchKernelGGL(k_prenet,    dim3(400), dim3(256), 0, stream, p);
  hipLaunchKernelGGL(k_procmem,   dim3(256), dim3(256), 0, stream, p);
  hipLaunchKernelGGL(k_premix,    dim3(16),  dim3(512), 0, stream, p);
  hipLaunchKernelGGL(k_scan,      dim3(232), dim3(512), SMEM_BYTES, stream, p);
}

// Round 10
// 8231.142 us; speedup vs baseline: 1.1540x; 1.1540x over previous
//
#include <hip/hip_runtime.h>

typedef unsigned short ushort_t;
typedef unsigned int uint_t;
typedef float f32x4_t __attribute__((ext_vector_type(4)));
typedef short bf16x8_t __attribute__((ext_vector_type(8)));

// ---- problem constants ----
#define NBATCH 16
#define SMEM   256
#define TSTEPS 400

// ---- workspace layout (float offsets) ----
#define F_XSB   0u         // 400*16*256 bf16 = 819200 floats
#define F_PM    819200u    // 16*256*128 f32
#define F_MMIX  1343488u   // 16*81*256 f32 (M_b = Wctx . mem^T)
#define F_W1T   1675264u   // prenet W1T
#define F_W2T   1695744u
// ---- zeroed region ----
#define F_AHB   1761280u   // 2*16*1024 bf16 = 16384 floats
#define F_DHB   1777664u   // 16384
#define F_CTXB  1794048u   // 2*16*512 bf16 = 8192 floats
#define F_DHF   1802240u   // 2*16*1024 f32 = 32768
#define F_AWG   1835008u   // 4*16*256 f32 = 16384 (aw ring, slot t&3)
#define F_FLG   1851392u   // 344 slots * 16 ints = 5504 floats
#define ZERO_BASE  F_AHB
#define ZERO_COUNT 95616u
// ---- q-partials: [2 slots][64 blk][16 b][128 a] f32 = 262144 floats (1 MB) ----
#define F_QP    1856896u

// flag slot bases (stride 16 ints = 64B/slot: one line per flag)
#define AHF  0
#define CTXF 64     // 32 flags (merged ATT+CTX blocks)
#define DHFL 192
#define AWF  320
#define PRF  336

// ---- dynamic LDS layout (byte offsets); total 160000 B ----
// A-path:
#define A_AH    0        // 32768: ah [16][1024] bf16, swizzled
#define A_CTX   32768    // 16384: ctx [16][512] bf16, swizzled
#define A_XS    49152    // 8192:  xs  [16][256] bf16, swizzled
#define A_RED   57344    // 4096:  cross-half reduce
#define A_QWQ   61440    // 8192:  Wq[:, bid*16..+16] f32 [128 a][16 c]
#define A_QH    69632    // 1024:  h(t) f32 [16 b][16 c]
// D-path:
#define D_AH    0        // 32768
#define D_CTX   32768    // 16384
#define D_DH    49152    // 32768
#define D_COMB  81920    // 6144
// merged ATT+CTX:
#define M_LOCU  0        // 20480
#define M_QSM   20480    // 512
#define M_VSM   20992    // 512
#define M_ESM   21504    // 1024
#define M_RED   22528    // 256
#define M_SMAW  22784    // 1024
#define M_SMAWC 23808    // 1024
#define M_MEM   24832    // 131072: mem[b] half [256 s][256 c] bf16
#define M_PART  155904   // 4096: ctx partials [4][256] f32; ALSO qred overlay (phase-disjoint)
// PROJ:
#define P_DHP   0        // 65536
#define P_AWP   65536    // 16384
#define SMEM_BYTES 160000

struct Ptrs {
  const float *memory, *dec_in, *Wpre1, *Wpre2, *Wih_a, *Whh_a, *bih_a, *bhh_a,
              *Wq, *Wm, *v, *Wc, *Wld, *Wih_d, *Whh_d, *bih_d, *bhh_d,
              *Wproj, *bproj, *Wgate, *bgate;
  const int *mlen;
  float *ws;
  float *out;
};

__device__ __forceinline__ float ftanh(float x) {
  float e = __expf(2.f * x);
  return 1.f - 2.f / (e + 1.f);
}
__device__ __forceinline__ float fsig(float x) { return 1.f / (1.f + __expf(-x)); }

__device__ __forceinline__ unsigned f2bfbits(float x) {
  unsigned u = __builtin_bit_cast(unsigned, x);
  return (u + 0x7FFFu + ((u >> 16) & 1u)) >> 16;
}
__device__ __forceinline__ float bf2f(ushort_t u) {
  unsigned v = ((unsigned)u) << 16;
  return __builtin_bit_cast(float, v);
}
__device__ __forceinline__ bf16x8_t packbf8(const float* f) {
  bf16x8_t r;
#pragma unroll
  for (int j = 0; j < 8; ++j) r[j] = (short)f2bfbits(f[j]);
  return r;
}
__device__ __forceinline__ bf16x8_t pack_from_f4(const float* src) {
  const float4* s4 = (const float4*)src;
  float4 lo = s4[0], hi = s4[1];
  float tmp[8] = {lo.x, lo.y, lo.z, lo.w, hi.x, hi.y, hi.z, hi.w};
  return packbf8(tmp);
}
__device__ __forceinline__ bf16x8_t ldbf8(const ushort_t* p) {
  return *(const bf16x8_t*)p;
}
__device__ __forceinline__ unsigned long long ldull_a(const unsigned long long* p) {
  return __hip_atomic_load(p, __ATOMIC_RELAXED, __HIP_MEMORY_SCOPE_AGENT);
}
__device__ __forceinline__ void stull_a(unsigned long long* p, unsigned long long v) {
  __hip_atomic_store(p, v, __ATOMIC_RELAXED, __HIP_MEMORY_SCOPE_AGENT);
}
__device__ __forceinline__ void stf_a(float* p, float v) {
  __hip_atomic_store(p, v, __ATOMIC_RELAXED, __HIP_MEMORY_SCOPE_AGENT);
}
__device__ __forceinline__ float ldf_a(const float* p) {
  return __hip_atomic_load(p, __ATOMIC_RELAXED, __HIP_MEMORY_SCOPE_AGENT);
}
__device__ __forceinline__ void pollge(int* flg, int slot, int thr) {
  while (__hip_atomic_load(flg + slot * 16, __ATOMIC_RELAXED, __HIP_MEMORY_SCOPE_AGENT) < thr)
    __builtin_amdgcn_s_sleep(1);
}
__device__ __forceinline__ void sig(int* flg, int slot, int val) {
  __hip_atomic_store(flg + slot * 16, val, __ATOMIC_RELAXED, __HIP_MEMORY_SCOPE_AGENT);
}
// swizzled LDS helpers: byte ^= ((row&7)<<4)
__device__ __forceinline__ void lds_st8(char* smc, int base, int row, int row_sh,
                                        int bytecol, unsigned long long v) {
  *(unsigned long long*)(smc + base + (row << row_sh) + (bytecol ^ ((row & 7) << 4))) = v;
}
__device__ __forceinline__ bf16x8_t lds_bf8(const char* smc, int base, int row,
                                            int row_sh, int bytecol) {
  return *(const bf16x8_t*)(smc + base + (row << row_sh) + (bytecol ^ ((row & 7) << 4)));
}
#define MFMA16(a,b,c) __builtin_amdgcn_mfma_f32_16x16x32_bf16((a),(b),(c),0,0,0)

// ---------------- zero state ----------------
__global__ __launch_bounds__(256) void k_zero(Ptrs p) {
  unsigned i = blockIdx.x * 256 + threadIdx.x;
  if (i < ZERO_COUNT) p.ws[ZERO_BASE + i] = 0.f;
}

// ---------------- weight transposes for prenet ----------------
__global__ __launch_bounds__(256) void k_transpose(Ptrs p) {
  int i = blockIdx.x * 256 + threadIdx.x;
  if (i < 20480) {
    int m = i >> 8, c = i & 255;
    p.ws[F_W1T + i] = p.Wpre1[c * 80 + m];
  } else if (i < 20480 + 65536) {
    int j = i - 20480;
    int pp = j >> 8, q = j & 255;
    p.ws[F_W2T + j] = p.Wpre2[q * 256 + pp];
  }
}

// ---------------- prenet -> xsb (bf16) ----------------
__global__ __launch_bounds__(256) void k_prenet(Ptrs p) {
  __shared__ float dil[NBATCH * 80];
  __shared__ float h1[NBATCH * 256];
  const int t = blockIdx.x, tid = threadIdx.x;
  const float* W1T = p.ws + F_W1T;
  const float* W2T = p.ws + F_W2T;

  for (int i = tid; i < NBATCH * 80; i += 256) {
    int b = i / 80, m = i - b * 80;
    dil[i] = (t == 0) ? 0.f : p.dec_in[((size_t)b * 80 + m) * 400 + (t - 1)];
  }
  __syncthreads();

  float acc[NBATCH];
#pragma unroll
  for (int b = 0; b < NBATCH; ++b) acc[b] = 0.f;
  for (int m = 0; m < 80; ++m) {
    float w = W1T[m * 256 + tid];
#pragma unroll
    for (int b = 0; b < NBATCH; ++b) acc[b] = fmaf(dil[b * 80 + m], w, acc[b]);
  }
#pragma unroll
  for (int b = 0; b < NBATCH; ++b) h1[b * 256 + tid] = fmaxf(acc[b], 0.f);
  __syncthreads();

#pragma unroll
  for (int b = 0; b < NBATCH; ++b) acc[b] = 0.f;
  for (int q = 0; q < 256; ++q) {
    float w = W2T[q * 256 + tid];
#pragma unroll
    for (int b = 0; b < NBATCH; ++b) acc[b] = fmaf(h1[b * 256 + q], w, acc[b]);
  }
  ushort_t* xsbU = (ushort_t*)(p.ws + F_XSB);
#pragma unroll
  for (int b = 0; b < NBATCH; ++b)
    xsbU[((size_t)(t * NBATCH + b)) * 256 + tid] = (ushort_t)f2bfbits(fmaxf(acc[b], 0.f));
}

// ---------------- proc_mem fp32 ----------------
__global__ __launch_bounds__(256) void k_procmem(Ptrs p) {
  __shared__ alignas(16) float msl[16 * 512];
  const int b = blockIdx.x >> 4, s0 = (blockIdx.x & 15) << 4;
  const int tid = threadIdx.x;
  const float4* src = (const float4*)(p.memory + ((size_t)(b * SMEM + s0)) * 512);
  float4* dst = (float4*)msl;
  for (int i = tid; i < 16 * 512 / 4; i += 256) dst[i] = src[i];
  __syncthreads();

  const int a = tid & 127, sg = tid >> 7;
  const float4* wm = (const float4*)(p.Wm + (size_t)a * 512);
  float* pm = p.ws + F_PM;
  float acc[8];
#pragma unroll
  for (int j = 0; j < 8; ++j) acc[j] = 0.f;
  for (int k = 0; k < 128; ++k) {
    float4 w = wm[k];
#pragma unroll
    for (int j = 0; j < 8; ++j) {
      float4 m = ((const float4*)(msl + (size_t)(sg * 8 + j) * 512))[k];
      acc[j] += w.x * m.x + w.y * m.y + w.z * m.z + w.w * m.w;
    }
  }
#pragma unroll
  for (int j = 0; j < 8; ++j)
    pm[((size_t)(b * SMEM + s0 + sg * 8 + j)) * 128 + a] = acc[j];
}

// ---------------- premix: M[b][row][s] = Wctx[row][:] . memory[b][s][:] ----------------
__global__ __launch_bounds__(512) void k_premix(Ptrs p) {
  const int b = blockIdx.x, tid = threadIdx.x;
  float* M = p.ws + F_MMIX;
  for (int i = tid; i < 81 * 256; i += 512) {
    int row = i >> 8, s = i & 255;
    const float* wrow = (row < 80) ? p.Wproj + (size_t)row * 1536 + 1024 : p.Wgate + 1024;
    const float4* w4 = (const float4*)wrow;
    const float4* m4 = (const float4*)(p.memory + ((size_t)(b * 256 + s)) * 512);
    float acc = 0.f;
#pragma unroll 4
    for (int k = 0; k < 128; ++k) {
      float4 w = w4[k], m = m4[k];
      acc += w.x * m.x + w.y * m.y + w.z * m.z + w.w * m.w;
    }
    M[((size_t)b * 81 + row) * 256 + s] = acc;
  }
}

// ---------------- persistent dataflow scan: 232 blocks x 512 threads ----------------
// Cycle (2 hops): A(ah+qp) -> MERGED(aw+ctx) -> A. D/PROJ off-cycle.
// vs round 8: A's DHFL(t-1) guard moved from the start barrier to the CTXF wait
// (concurrent, disjoint threads) so D's latency no longer gates A's start.
__global__ __launch_bounds__(512, 1) void k_scan(Ptrs p) {
  extern __shared__ char smc[];
  const int bid = blockIdx.x, tid = threadIdx.x;
  const int wid = tid >> 6, lane = tid & 63;
  const int m16 = lane & 15, kq = lane >> 4;

  float* ws = p.ws;
  ushort_t* xsbU  = (ushort_t*)(ws + F_XSB);
  float*    pmF   = ws + F_PM;
  float*    Mx    = ws + F_MMIX;
  unsigned long long* ahb8 = (unsigned long long*)(ws + F_AHB);
  unsigned long long* dhb8 = (unsigned long long*)(ws + F_DHB);
  unsigned long long* ctxb8 = (unsigned long long*)(ws + F_CTXB);
  float*    dhfF  = ws + F_DHF;
  float*    awGF  = ws + F_AWG;
  float*    qpF   = ws + F_QP;
  int*      flg   = (int*)(ws + F_FLG);
  float* out_mel  = p.out;
  float* out_gate = p.out + 512000;
  float* out_al   = p.out + 518400;

  if (bid < 64) {
    // ======== A-path: A-LSTM(t) + q-partials; ah/xs MFMAs hidden under ctx wait ========
    const int ls = wid >> 1, half = wid & 1;
    const int strip = (bid << 2) | ls;
    const int gA = m16 & 3, jA = m16 >> 2;
    const int wrowA = gA * 1024 + strip * 4 + jA;
    bf16x8_t wA[28];
#pragma unroll
    for (int c = 0; c < 28; ++c) {
      int k0 = (half * 28 + c) * 32 + kq * 8;
      const float* src = (k0 < 768) ? p.Wih_a + (size_t)wrowA * 768 + k0
                                    : p.Whh_a + (size_t)wrowA * 1024 + (k0 - 768);
      wA[c] = pack_from_f4(src);
    }
    const int nnA = strip * 4 + kq;
    float biasA[4];
#pragma unroll
    for (int r = 0; r < 4; ++r) biasA[r] = p.bih_a[r * 1024 + nnA] + p.bhh_a[r * 1024 + nnA];
    float acState = 0.f;
    float* ared = (float*)(smc + A_RED);
    float* qwq  = (float*)(smc + A_QWQ);
    float* qh   = (float*)(smc + A_QH);
    for (int i = tid; i < 2048; i += 512) {
      int a = i >> 4, c = i & 15;
      qwq[i] = p.Wq[(size_t)a * 1024 + bid * 16 + c];
    }
    __syncthreads();

    for (int t = 0; t < TSTEPS; ++t) {
      const int pc = t & 1, pp = (t + 1) & 1;
      // start poll: ah(t-1) peers ONLY (D guard deferred to the ctx wait)
      if (tid < 64) pollge(flg, AHF + tid, t);
      __syncthreads();
      // stage ah(t-1) + xs(t)
      {
        const unsigned long long* ag = ahb8 + (size_t)pp * 4096;
        const unsigned long long* xg = (const unsigned long long*)xsbU + (size_t)t * 1024;
        unsigned long long tA[8], tX[2];
#pragma unroll
        for (int i = 0; i < 8; ++i) tA[i] = ldull_a(ag + tid + i * 512);
#pragma unroll
        for (int i = 0; i < 2; ++i) tX[i] = xg[tid + i * 512];
#pragma unroll
        for (int i = 0; i < 8; ++i) { int u = tid + i * 512; lds_st8(smc, A_AH, u >> 8, 11, (u & 255) * 8, tA[i]); }
#pragma unroll
        for (int i = 0; i < 2; ++i) { int u = tid + i * 512; lds_st8(smc, A_XS, u >> 6, 9, (u & 63) * 8, tX[i]); }
      }
      __syncthreads();
      // MFMA phase 1: all ah/xs-dependent chunks (runs while MERGED computes ctx)
      f32x4_t a0 = {0,0,0,0}, a1 = {0,0,0,0};
      if (half == 0) {
#pragma unroll
        for (int c = 0; c < 8; ++c) {
          bf16x8_t bf = lds_bf8(smc, A_XS, m16, 9, c * 64 + kq * 16);
          if (c & 1) a1 = MFMA16(wA[c], bf, a1); else a0 = MFMA16(wA[c], bf, a0);
        }
#pragma unroll
        for (int c = 24; c < 28; ++c) {
          bf16x8_t bf = lds_bf8(smc, A_AH, m16, 11, (c - 24) * 64 + kq * 16);
          if (c & 1) a1 = MFMA16(wA[c], bf, a1); else a0 = MFMA16(wA[c], bf, a0);
        }
      } else {
#pragma unroll
        for (int c = 0; c < 28; ++c) {
          bf16x8_t bf = lds_bf8(smc, A_AH, m16, 11, (4 + c) * 64 + kq * 16);
          if (c & 1) a1 = MFMA16(wA[c], bf, a1); else a0 = MFMA16(wA[c], bf, a0);
        }
#pragma unroll
        for (int r = 0; r < 4; ++r) ared[((ls * 64 + lane) << 2) + r] = a0[r] + a1[r];
      }
      // ctx(t-1) wait + D(t-1) write-guard, polled CONCURRENTLY (disjoint threads).
      // DHFL(t-1) lands well before CTXF(t) -> the guard costs ~0 here, but still
      // orders the ahb slot-(t&1) overwrite below after D(t-1)'s ah(t-2) staging.
      if (tid < 32) pollge(flg, CTXF + tid, t);
      else if (tid >= 64 && tid < 192) pollge(flg, DHFL + (tid - 64), t - 1);
      __syncthreads();
      {
        const unsigned long long* cg = ctxb8 + (size_t)pp * 2048;
        unsigned long long tC[4];
#pragma unroll
        for (int i = 0; i < 4; ++i) tC[i] = ldull_a(cg + tid + i * 512);
#pragma unroll
        for (int i = 0; i < 4; ++i) { int u = tid + i * 512; lds_st8(smc, A_CTX, u >> 7, 10, (u & 127) * 8, tC[i]); }
      }
      __syncthreads();
      if (half == 0) {
#pragma unroll
        for (int c = 8; c < 24; ++c) {
          bf16x8_t bf = lds_bf8(smc, A_CTX, m16, 10, (c - 8) * 64 + kq * 16);
          if (c & 1) a1 = MFMA16(wA[c], bf, a1); else a0 = MFMA16(wA[c], bf, a0);
        }
        float z[4];
#pragma unroll
        for (int r = 0; r < 4; ++r)
          z[r] = a0[r] + a1[r] + ared[((ls * 64 + lane) << 2) + r] + biasA[r];
        float cn = fsig(z[1]) * acState + fsig(z[0]) * ftanh(z[2]);
        acState = cn;
        float h = fsig(z[3]) * ftanh(cn);
        qh[(m16 << 4) + ls * 4 + kq] = h;
        unsigned hb = f2bfbits(h);
        unsigned b0 = __shfl(hb, m16);
        unsigned b1 = __shfl(hb, m16 + 16);
        unsigned b2 = __shfl(hb, m16 + 32);
        unsigned b3 = __shfl(hb, m16 + 48);
        if (kq == 0) {
          unsigned long long u = (unsigned long long)(b0 | (b1 << 16))
                               | ((unsigned long long)(b2 | (b3 << 16)) << 32);
          stull_a(ahb8 + ((size_t)(pc * 16 + m16)) * 256 + strip, u);
        }
      }
      __syncthreads();
      // q-partials: qp[blk][b][a] = sum_c Wq[a][blk*16+c] * h[b][blk*16+c]
      {
        int a = tid & 127, bg = tid >> 7;
        const float* wrow = qwq + a * 16;
        float s0 = 0.f, s1 = 0.f, s2 = 0.f, s3 = 0.f;
#pragma unroll
        for (int c = 0; c < 16; ++c) {
          float wv = wrow[c];
          s0 = fmaf(wv, qh[((bg * 4 + 0) << 4) + c], s0);
          s1 = fmaf(wv, qh[((bg * 4 + 1) << 4) + c], s1);
          s2 = fmaf(wv, qh[((bg * 4 + 2) << 4) + c], s2);
          s3 = fmaf(wv, qh[((bg * 4 + 3) << 4) + c], s3);
        }
        float* qps = qpF + (size_t)pc * 131072 + bid * 2048 + a;
        stf_a(qps + (size_t)(bg * 4 + 0) * 128, s0);
        stf_a(qps + (size_t)(bg * 4 + 1) * 128, s1);
        stf_a(qps + (size_t)(bg * 4 + 2) * 128, s2);
        stf_a(qps + (size_t)(bg * 4 + 3) * 128, s3);
      }
      __syncthreads();   // drains ahb + qp stores before flag
      if (tid == 0) sig(flg, AHF + bid, t + 1);
    }
  } else if (bid < 192) {
    // ======== D-path: pure D-LSTM(t-1) ========
    const int ls = wid >> 2, qt = wid & 3;
    const int strip = ((bid - 64) << 1) | ls;
    const int gD = m16 & 3, jD = m16 >> 2;
    const int wrowD = gD * 1024 + strip * 4 + jD;
    bf16x8_t wD[20];
#pragma unroll
    for (int c = 0; c < 20; ++c) {
      int k0 = (qt * 20 + c) * 32 + kq * 8;
      const float* src = (k0 < 1536) ? p.Wih_d + (size_t)wrowD * 1536 + k0
                                     : p.Whh_d + (size_t)wrowD * 1024 + (k0 - 1536);
      wD[c] = pack_from_f4(src);
    }
    const int nnD = strip * 4 + kq;
    float biasD[4];
#pragma unroll
    for (int r = 0; r < 4; ++r) biasD[r] = p.bih_d[r * 1024 + nnD] + p.bhh_d[r * 1024 + nnD];
    float dcState = 0.f;
    float* comb = (float*)(smc + D_COMB);
    __syncthreads();

    for (int t = 1; t <= TSTEPS; ++t) {
      const int pc = t & 1, pw = (t + 1) & 1;
      if (tid < 64) pollge(flg, AHF + tid, t);
      else if (tid >= 96 && tid < 224) pollge(flg, DHFL + (tid - 96), t - 1);
      else if (tid >= 224 && tid < 232) pollge(flg, PRF + (tid - 224), t - 2);
      __syncthreads();
      {
        const unsigned long long* ag = ahb8 + (size_t)pw * 4096;
        const unsigned long long* dg = dhb8 + (size_t)pc * 4096;
        unsigned long long tA[8], tD[8];
#pragma unroll
        for (int i = 0; i < 8; ++i) tA[i] = ldull_a(ag + tid + i * 512);
#pragma unroll
        for (int i = 0; i < 8; ++i) tD[i] = ldull_a(dg + tid + i * 512);
#pragma unroll
        for (int i = 0; i < 8; ++i) { int u = tid + i * 512; lds_st8(smc, D_AH, u >> 8, 11, (u & 255) * 8, tA[i]); }
#pragma unroll
        for (int i = 0; i < 8; ++i) { int u = tid + i * 512; lds_st8(smc, D_DH, u >> 8, 11, (u & 255) * 8, tD[i]); }
      }
      if (tid >= 64 && tid < 96) pollge(flg, CTXF + (tid - 64), t);
      __syncthreads();
      {
        const unsigned long long* cg = ctxb8 + (size_t)pw * 2048;
        unsigned long long tC[4];
#pragma unroll
        for (int i = 0; i < 4; ++i) tC[i] = ldull_a(cg + tid + i * 512);
#pragma unroll
        for (int i = 0; i < 4; ++i) { int u = tid + i * 512; lds_st8(smc, D_CTX, u >> 7, 10, (u & 127) * 8, tC[i]); }
      }
      __syncthreads();

      f32x4_t a0 = {0,0,0,0}, a1 = {0,0,0,0};
#define DFRAG_AH(ch)  lds_bf8(smc, D_AH,  m16, 11, (ch) * 64 + kq * 16)
#define DFRAG_CTX(ch) lds_bf8(smc, D_CTX, m16, 10, (ch) * 64 + kq * 16)
#define DFRAG_DH(ch)  lds_bf8(smc, D_DH,  m16, 11, (ch) * 64 + kq * 16)
#define DMFMA(BF) { bf16x8_t bf = (BF); \
        if (c & 1) a1 = MFMA16(wD[c], bf, a1); else a0 = MFMA16(wD[c], bf, a0); }
      if (qt == 0) {
#pragma unroll
        for (int c = 0; c < 20; ++c) DMFMA(DFRAG_AH(c))
      } else if (qt == 1) {
#pragma unroll
        for (int c = 0; c < 20; ++c) { if (c < 12) DMFMA(DFRAG_AH(20 + c)) else DMFMA(DFRAG_CTX(c - 12)) }
      } else if (qt == 2) {
#pragma unroll
        for (int c = 0; c < 20; ++c) { if (c < 8) DMFMA(DFRAG_CTX(8 + c)) else DMFMA(DFRAG_DH(c - 8)) }
      } else {
#pragma unroll
        for (int c = 0; c < 20; ++c) DMFMA(DFRAG_DH(12 + c))
      }
#undef DMFMA
      if (qt != 0) {
#pragma unroll
        for (int r = 0; r < 4; ++r)
          comb[(((ls * 3 + qt - 1) * 64 + lane) << 2) + r] = a0[r] + a1[r];
      }
      __syncthreads();
      if (qt == 0) {
        float z[4];
#pragma unroll
        for (int r = 0; r < 4; ++r) {
          z[r] = a0[r] + a1[r] + biasD[r];
#pragma unroll
          for (int j = 0; j < 3; ++j) z[r] += comb[(((ls * 3 + j) * 64 + lane) << 2) + r];
        }
        float cn = fsig(z[1]) * dcState + fsig(z[0]) * ftanh(z[2]);
        dcState = cn;
        float h = fsig(z[3]) * ftanh(cn);
        stf_a(dhfF + (size_t)pw * 16384 + m16 * 1024 + nnD, h);
        unsigned hb = f2bfbits(h);
        unsigned b0 = __shfl(hb, m16);
        unsigned b1 = __shfl(hb, m16 + 16);
        unsigned b2 = __shfl(hb, m16 + 32);
        unsigned b3 = __shfl(hb, m16 + 48);
        if (kq == 0) {
          unsigned long long u = (unsigned long long)(b0 | (b1 << 16))
                               | ((unsigned long long)(b2 | (b3 << 16)) << 32);
          stull_a(dhb8 + ((size_t)(pw * 16 + m16)) * 256 + strip, u);
        }
      }
      __syncthreads();
      if (tid == 0) sig(flg, DHFL + (bid - 64), t);
    }
  } else if (bid < 224) {
    // ======== MERGED ATT+CTX: 2 blocks/batch; e/softmax duplicated + ctx half ========
    const int cbid = bid - 192;              // 0..31
    const int b = cbid >> 1, h2 = cbid & 1;
    const int mlenb = p.mlen[b];
    ushort_t* locu = (ushort_t*)(smc + M_LOCU);
    float* qsm   = (float*)(smc + M_QSM);
    float* vsm   = (float*)(smc + M_VSM);
    float* esm   = (float*)(smc + M_ESM);
    float* red   = (float*)(smc + M_RED);
    float* smaw  = (float*)(smc + M_SMAW);
    float* smawc = (float*)(smc + M_SMAWC);
    ushort_t* memu2 = (ushort_t*)(smc + M_MEM);
    float* part  = (float*)(smc + M_PART);
    float* qred  = part;   // overlay: qred (q phase) / part (ctx phase) time-disjoint

    bf16x8_t wLd[8];
#pragma unroll
    for (int at = 0; at < 8; ++at)
      wLd[at] = pack_from_f4(p.Wld + ((size_t)(at * 16 + m16)) * 32 + kq * 8);
    bf16x8_t wC[2][2];
#pragma unroll
    for (int ft = 0; ft < 2; ++ft)
#pragma unroll
      for (int ck = 0; ck < 2; ++ck) {
        float tmp[8];
#pragma unroll
        for (int jj = 0; jj < 8; ++jj) {
          int k2 = ck * 32 + kq * 8 + jj;
          float vv = 0.f;
          if (k2 < 62) { int ch = (k2 < 31) ? 0 : 1; int k = k2 - 31 * ch;
            vv = p.Wc[((size_t)(ft * 16 + m16) * 2 + ch) * 31 + k]; }
          tmp[jj] = vv;
        }
        wC[ft][ck] = packbf8(tmp);
      }
    uint_t pmreg[2][8][2];
#pragma unroll
    for (int u = 0; u < 2; ++u) {
      int sloc = (wid * 2 + u) * 16 + m16;
#pragma unroll
      for (int at = 0; at < 8; ++at)
#pragma unroll
        for (int rp = 0; rp < 2; ++rp) {
          const float* src = pmF + ((size_t)(b * 256 + sloc)) * 128 + at * 16 + kq * 4 + rp * 2;
          pmreg[u][at][rp] = f2bfbits(src[0]) | (f2bfbits(src[1]) << 16);
        }
    }
    // one-time: stage mem[b][:, h2*256 .. +256] as bf16
    for (int i = tid; i < 16384; i += 512) {
      int s = i >> 6, c4 = i & 63;
      float4 m = *(const float4*)(p.memory + ((size_t)(b * 256 + s)) * 512 + h2 * 256 + c4 * 4);
      ushort_t* dst = memu2 + s * 256 + c4 * 4;
      dst[0] = (ushort_t)f2bfbits(m.x);
      dst[1] = (ushort_t)f2bfbits(m.y);
      dst[2] = (ushort_t)f2bfbits(m.z);
      dst[3] = (ushort_t)f2bfbits(m.w);
    }
    if (tid < 128) vsm[tid] = p.v[tid];
    if (tid < 256) { smaw[tid] = 0.f; smawc[tid] = 0.f; }
    __syncthreads();

    for (int t = 0; t < TSTEPS; ++t) {
      const int pc = t & 1;
      // conv(t) from own-LDS aw/awc (prev step): overlaps the ah wait
#pragma unroll
      for (int u = 0; u < 4; ++u) {
        int task = wid * 4 + u;
        int stile = task >> 1, ft = task & 1;
        int scol = stile * 16 + m16;
        f32x4_t acc = {0,0,0,0};
#pragma unroll
        for (int ck = 0; ck < 2; ++ck) {
          float tmp[8];
#pragma unroll
          for (int jj = 0; jj < 8; ++jj) {
            int k2 = ck * 32 + kq * 8 + jj;
            float vv = 0.f;
            if (k2 < 62) {
              int ch = (k2 < 31) ? 0 : 1; int k = k2 - 31 * ch;
              int sp = scol + k - 15;
              if (sp >= 0 && sp < 256) vv = (ch ? smawc : smaw)[sp];
            }
            tmp[jj] = vv;
          }
          acc = MFMA16(wC[ft][ck], packbf8(tmp), acc);
        }
#pragma unroll
        for (int r = 0; r < 4; ++r)
          locu[scol * 40 + ft * 16 + kq * 4 + r] = (ushort_t)f2bfbits(acc[r]);
      }
      // waits: ah(t)+qp fresh; DHFL stale (ctxb slot guard); PRF (awGF ring) — concurrent
      if (tid < 64) pollge(flg, AHF + tid, t + 1);
      else if (tid < 192) pollge(flg, DHFL + (tid - 64), t - 1);
      else if (tid < 200) pollge(flg, PRF + (tid - 192), t - 3);
      __syncthreads();
      // q[b] = sum over 64 A-block partials
      {
        int a = tid & 127, g = tid >> 7;
        const float* qps = qpF + (size_t)(t & 1) * 131072 + b * 128 + a;
        float s = 0.f;
#pragma unroll
        for (int k = 0; k < 16; ++k)
          s += ldf_a(qps + (size_t)(g * 16 + k) * 2048);
        qred[g * 128 + a] = s;
      }
      __syncthreads();
      if (tid < 128) qsm[tid] = qred[tid] + qred[128 + tid] + qred[256 + tid] + qred[384 + tid];
      __syncthreads();
      // fused pa+e: 2 s-tiles per wave
#pragma unroll
      for (int u = 0; u < 2; ++u) {
        int sloc = (wid * 2 + u) * 16 + m16;
        bf16x8_t Bfrag = ldbf8(locu + sloc * 40 + kq * 8);
        float eacc = 0.f;
#pragma unroll
        for (int at = 0; at < 8; ++at) {
          f32x4_t C = {0,0,0,0};
          C = MFMA16(wLd[at], Bfrag, C);
#pragma unroll
          for (int r = 0; r < 4; ++r) {
            int a = at * 16 + kq * 4 + r;
            uint_t pw_ = pmreg[u][at][r >> 1];
            float pmv = bf2f((ushort_t)((r & 1) ? (pw_ >> 16) : (pw_ & 0xFFFF)));
            eacc = fmaf(vsm[a], ftanh(C[r] + qsm[a] + pmv), eacc);
          }
        }
        eacc += __shfl_xor(eacc, 16);
        eacc += __shfl_xor(eacc, 32);
        if (sloc >= mlenb) eacc = -1.0e9f;
        if (kq == 0) esm[sloc] = eacc;
      }
      __syncthreads();
      // softmax over 256
      float ev = 0.f;
      if (tid < 256) {
        ev = esm[tid];
        float mv = ev;
        for (int o = 32; o; o >>= 1) mv = fmaxf(mv, __shfl_xor(mv, o));
        if (lane == 0) red[wid] = mv;
      }
      __syncthreads();
      float gmax = fmaxf(fmaxf(red[0], red[1]), fmaxf(red[2], red[3]));
      float pv = 0.f;
      if (tid < 256) {
        pv = __expf(ev - gmax);
        float sv = pv;
        for (int o = 32; o; o >>= 1) sv += __shfl_xor(sv, o);
        if (lane == 0) red[8 + wid] = sv;
      }
      __syncthreads();
      float gsum = red[8] + red[9] + red[10] + red[11];
      float awv = 0.f;
      if (tid < 256) {
        awv = pv / gsum;
        smaw[tid] = awv;
        smawc[tid] += awv;
        if (h2 == 0) stf_a(awGF + (size_t)(t & 3) * 4096 + b * 256 + tid, awv);
      }
      __syncthreads();
      // ctx(t) half = aw(t) . mem[b][:, h2*256..+256]  (all in LDS)
      {
        const int c = tid & 127, sg = tid >> 7;
        const uint_t* mrow = (const uint_t*)memu2;
        float c0 = 0.f, c1 = 0.f;
#pragma unroll 8
        for (int si = 0; si < 64; ++si) {
          int s = sg * 64 + si;
          uint_t mm = mrow[s * 128 + c];
          float av = smaw[s];
          c0 = fmaf(bf2f((ushort_t)(mm & 0xFFFF)), av, c0);
          c1 = fmaf(bf2f((ushort_t)(mm >> 16)), av, c1);
        }
        part[sg * 256 + c * 2] = c0;
        part[sg * 256 + c * 2 + 1] = c1;
      }
      __syncthreads();
      if (tid < 64) {
        unsigned pk[4];
#pragma unroll
        for (int j = 0; j < 4; ++j) {
          int col = tid * 4 + j;
          float v = part[col] + part[256 + col] + part[512 + col] + part[768 + col];
          pk[j] = f2bfbits(v);
        }
        unsigned long long u = (unsigned long long)(pk[0] | (pk[1] << 16))
                             | ((unsigned long long)(pk[2] | (pk[3] << 16)) << 32);
        stull_a(ctxb8 + ((size_t)(pc * 16 + b)) * 128 + h2 * 64 + tid, u);
      }
      __syncthreads();   // drain ctxb + awGF stores
      if (tid == 0) {
        sig(flg, CTXF + cbid, t + 1);
        if (h2 == 0) sig(flg, AWF + b, t + 1);
      }
      // off-path output store
      if (h2 == 0 && tid < 256) out_al[((size_t)b * 400 + t) * 256 + tid] = awv;
    }
  } else if (bid < 232) {
    // ======== PROJ path: mel/gate = Wdh.dh(t-1) + M.aw(t-1) + bias ========
    const int wv = (bid - 224) * 8 + wid;   // 0..63
    int rows[2] = {wv * 2, wv * 2 + 1};
    float wdh[2][16], mreg[2][16][4], biasr[2];
#pragma unroll
    for (int rr = 0; rr < 2; ++rr) {
      int row = rows[rr];
      biasr[rr] = 0.f;
#pragma unroll
      for (int j = 0; j < 16; ++j) wdh[rr][j] = 0.f;
#pragma unroll
      for (int b2 = 0; b2 < 16; ++b2)
#pragma unroll
        for (int j = 0; j < 4; ++j) mreg[rr][b2][j] = 0.f;
      if (row <= 80) {
        const float* wsrc = (row < 80) ? p.Wproj + (size_t)row * 1536 : p.Wgate;
#pragma unroll
        for (int j = 0; j < 16; ++j) wdh[rr][j] = wsrc[lane + 64 * j];
        biasr[rr] = (row < 80) ? p.bproj[row] : p.bgate[0];
#pragma unroll
        for (int b2 = 0; b2 < 16; ++b2)
#pragma unroll
          for (int j = 0; j < 4; ++j)
            mreg[rr][b2][j] = Mx[((size_t)b2 * 81 + row) * 256 + lane + 64 * j];
      }
    }
    float* dhp = (float*)(smc + P_DHP);
    float* awp = (float*)(smc + P_AWP);
    __syncthreads();
    for (int t = 1; t <= TSTEPS; ++t) {
      const int pw = (t + 1) & 1;
      if (tid < 128) pollge(flg, DHFL + tid, t);
      else if (tid < 144) pollge(flg, AWF + tid - 128, t);
      __syncthreads();
      {
        const unsigned long long* ag = (const unsigned long long*)(awGF + (size_t)((t - 1) & 3) * 4096);
        const unsigned long long* dg = (const unsigned long long*)(dhfF + (size_t)pw * 16384);
        unsigned long long tw[4], td[16];
#pragma unroll
        for (int i = 0; i < 4; ++i) tw[i] = ldull_a(ag + tid + i * 512);
#pragma unroll
        for (int i = 0; i < 16; ++i) td[i] = ldull_a(dg + tid + i * 512);
#pragma unroll
        for (int i = 0; i < 4; ++i) ((unsigned long long*)awp)[tid + i * 512] = tw[i];
#pragma unroll
        for (int i = 0; i < 16; ++i) ((unsigned long long*)dhp)[tid + i * 512] = td[i];
      }
      __syncthreads();
      if (wv <= 40) {
        for (int b2 = 0; b2 < 16; ++b2) {
          float h[16];
#pragma unroll
          for (int j = 0; j < 16; ++j) h[j] = dhp[b2 * 1024 + lane + 64 * j];
#pragma unroll
          for (int rr = 0; rr < 2; ++rr) {
            if (rows[rr] > 80) continue;
            float d = 0.f;
#pragma unroll
            for (int j = 0; j < 16; ++j) d = fmaf(wdh[rr][j], h[j], d);
#pragma unroll
            for (int j = 0; j < 4; ++j) d = fmaf(mreg[rr][b2][j], awp[b2 * 256 + lane + 64 * j], d);
            for (int o = 32; o; o >>= 1) d += __shfl_xor(d, o);
            if (lane == 0) {
              d += biasr[rr];
              if (rows[rr] < 80) out_mel[((size_t)b2 * 80 + rows[rr]) * 400 + (t - 1)] = d;
              else out_gate[(size_t)b2 * 400 + (t - 1)] = d;
            }
          }
        }
      }
      __syncthreads();
      if (tid == 0) sig(flg, PRF + (bid - 224), t);
    }
  }
}

extern "C" void kernel_launch(void* const* d_in, const int* in_sizes, int n_in,
                              void* d_out, int out_size, void* d_ws, size_t ws_size,
                              hipStream_t stream) {
  (void)in_sizes; (void)n_in; (void)out_size; (void)ws_size;
  Ptrs p;
  p.memory = (const float*)d_in[0];
  p.dec_in = (const float*)d_in[1];
  p.Wpre1  = (const float*)d_in[2];
  p.Wpre2  = (const float*)d_in[3];
  p.Wih_a  = (const float*)d_in[4];
  p.Whh_a  = (const float*)d_in[5];
  p.bih_a  = (const float*)d_in[6];
  p.bhh_a  = (const float*)d_in[7];
  p.Wq     = (const float*)d_in[8];
  p.Wm     = (const float*)d_in[9];
  p.v      = (const float*)d_in[10];
  p.Wc     = (const float*)d_in[11];
  p.Wld    = (const float*)d_in[12];
  p.Wih_d  = (const float*)d_in[13];
  p.Whh_d  = (const float*)d_in[14];
  p.bih_d  = (const float*)d_in[15];
  p.bhh_d  = (const float*)d_in[16];
  p.Wproj  = (const float*)d_in[17];
  p.bproj  = (const float*)d_in[18];
  p.Wgate  = (const float*)d_in[19];
  p.bgate  = (const float*)d_in[20];
  p.mlen   = (const int*)d_in[21];
  p.ws  = (float*)d_ws;
  p.out = (float*)d_out;

  static bool attr_done = false;
  if (!attr_done) {
    hipFuncSetAttribute((const void*)k_scan,
                        hipFuncAttributeMaxDynamicSharedMemorySize, SMEM_BYTES);
    attr_done = true;
  }

  hipLaunchKernelGGL(k_zero,      dim3((ZERO_COUNT + 255) / 256), dim3(256), 0, stream, p);
  hipLaunchKernelGGL(k_transpose, dim3(336), dim3(256), 0, stream, p);
  hipLaunchKernelGGL(k_prenet,    dim3(400), dim3(256), 0, stream, p);
  hipLaunchKernelGGL(k_procmem,   dim3(256), dim3(256), 0, stream, p);
  hipLaunchKernelGGL(k_premix,    dim3(16),  dim3(512), 0, stream, p);
  hipLaunchKernelGGL(k_scan,      dim3(232), dim3(512), SMEM_BYTES, stream, p);
}

// Round 11
// 7729.639 us; speedup vs baseline: 1.2288x; 1.0649x over previous
//
#include <hip/hip_runtime.h>

typedef unsigned short ushort_t;
typedef unsigned int uint_t;
typedef float f32x4_t __attribute__((ext_vector_type(4)));
typedef short bf16x8_t __attribute__((ext_vector_type(8)));

// ---- problem constants ----
#define NBATCH 16
#define SMEM   256
#define TSTEPS 400

// ---- workspace layout (float offsets) ----
#define F_XSB   0u         // 400*16*256 bf16 = 819200 floats
#define F_PM    819200u    // 16*256*128 f32
#define F_MMIX  1343488u   // 16*81*256 f32 (M_b = Wctx . mem^T)
#define F_W1T   1675264u   // prenet W1T
#define F_W2T   1695744u
// ---- zeroed region ----
#define F_AHB   1761280u   // 2*16*1024 bf16 = 16384 floats
#define F_DHB   1777664u   // 16384
#define F_CTXB  1794048u   // 2*16*512 bf16 = 8192 floats
#define F_DHF   1802240u   // 2*16*1024 f32 = 32768
#define F_AWG   1835008u   // 4*16*256 f32 = 16384 (aw ring, slot t&3)
#define F_FLG   1851392u   // 344 slots * 16 ints = 5504 floats
#define ZERO_BASE  F_AHB
#define ZERO_COUNT 95616u
// ---- q-partials: [2 slots][64 blk][16 b][128 a] f32 = 262144 floats (1 MB) ----
#define F_QP    1856896u

// flag slot bases (stride 16 ints = 64B/slot: one line per flag)
#define AHF  0
#define CTXF 64     // 32 flags (merged ATT+CTX blocks)
#define DHFL 192
#define AWF  320
#define PRF  336

// ---- dynamic LDS layout (byte offsets); total 160000 B ----
// A-path:
#define A_AH    0        // 32768: ah [16][1024] bf16, swizzled
#define A_CTX   32768    // 16384: ctx [16][512] bf16, swizzled
#define A_XS    49152    // 8192:  xs  [16][256] bf16, swizzled
#define A_RED   57344    // 4096:  cross-half reduce
#define A_QWQ   61440    // 8192:  Wq[:, bid*16..+16] f32 [128 a][16 c]
#define A_QH    69632    // 1024:  h(t) f32 [16 b][16 c]
// D-path:
#define D_AH    0        // 32768
#define D_CTX   32768    // 16384
#define D_DH    49152    // 32768
#define D_COMB  81920    // 6144
// merged ATT+CTX:
#define M_LOCU  0        // 20480
#define M_QSM   20480    // 512
#define M_VSM   20992    // 512
#define M_ESM   21504    // 1024
#define M_RED   22528    // 256
#define M_SMAW  22784    // 1024
#define M_SMAWC 23808    // 1024
#define M_MEM   24832    // 131072: mem[b] half [256 s][256 c] bf16
#define M_PART  155904   // 4096: ctx partials [4][256] f32; ALSO qred [8][128] overlay
// PROJ:
#define P_DHP   0        // 65536
#define P_AWP   65536    // 16384
#define SMEM_BYTES 160000

struct Ptrs {
  const float *memory, *dec_in, *Wpre1, *Wpre2, *Wih_a, *Whh_a, *bih_a, *bhh_a,
              *Wq, *Wm, *v, *Wc, *Wld, *Wih_d, *Whh_d, *bih_d, *bhh_d,
              *Wproj, *bproj, *Wgate, *bgate;
  const int *mlen;
  float *ws;
  float *out;
};

__device__ __forceinline__ float ftanh(float x) {
  float e = __expf(2.f * x);
  return 1.f - 2.f / (e + 1.f);
}
__device__ __forceinline__ float fsig(float x) { return 1.f / (1.f + __expf(-x)); }

__device__ __forceinline__ unsigned f2bfbits(float x) {
  unsigned u = __builtin_bit_cast(unsigned, x);
  return (u + 0x7FFFu + ((u >> 16) & 1u)) >> 16;
}
__device__ __forceinline__ float bf2f(ushort_t u) {
  unsigned v = ((unsigned)u) << 16;
  return __builtin_bit_cast(float, v);
}
__device__ __forceinline__ bf16x8_t packbf8(const float* f) {
  bf16x8_t r;
#pragma unroll
  for (int j = 0; j < 8; ++j) r[j] = (short)f2bfbits(f[j]);
  return r;
}
__device__ __forceinline__ bf16x8_t pack_from_f4(const float* src) {
  const float4* s4 = (const float4*)src;
  float4 lo = s4[0], hi = s4[1];
  float tmp[8] = {lo.x, lo.y, lo.z, lo.w, hi.x, hi.y, hi.z, hi.w};
  return packbf8(tmp);
}
__device__ __forceinline__ bf16x8_t ldbf8(const ushort_t* p) {
  return *(const bf16x8_t*)p;
}
__device__ __forceinline__ unsigned long long ldull_a(const unsigned long long* p) {
  return __hip_atomic_load(p, __ATOMIC_RELAXED, __HIP_MEMORY_SCOPE_AGENT);
}
__device__ __forceinline__ void stull_a(unsigned long long* p, unsigned long long v) {
  __hip_atomic_store(p, v, __ATOMIC_RELAXED, __HIP_MEMORY_SCOPE_AGENT);
}
__device__ __forceinline__ void stf_a(float* p, float v) {
  __hip_atomic_store(p, v, __ATOMIC_RELAXED, __HIP_MEMORY_SCOPE_AGENT);
}
__device__ __forceinline__ float ldf_a(const float* p) {
  return __hip_atomic_load(p, __ATOMIC_RELAXED, __HIP_MEMORY_SCOPE_AGENT);
}
__device__ __forceinline__ void pollge(int* flg, int slot, int thr) {
  while (__hip_atomic_load(flg + slot * 16, __ATOMIC_RELAXED, __HIP_MEMORY_SCOPE_AGENT) < thr)
    __builtin_amdgcn_s_sleep(1);
}
__device__ __forceinline__ void sig(int* flg, int slot, int val) {
  __hip_atomic_store(flg + slot * 16, val, __ATOMIC_RELAXED, __HIP_MEMORY_SCOPE_AGENT);
}
// swizzled LDS helpers: byte ^= ((row&7)<<4)
__device__ __forceinline__ void lds_st8(char* smc, int base, int row, int row_sh,
                                        int bytecol, unsigned long long v) {
  *(unsigned long long*)(smc + base + (row << row_sh) + (bytecol ^ ((row & 7) << 4))) = v;
}
__device__ __forceinline__ bf16x8_t lds_bf8(const char* smc, int base, int row,
                                            int row_sh, int bytecol) {
  return *(const bf16x8_t*)(smc + base + (row << row_sh) + (bytecol ^ ((row & 7) << 4)));
}
#define MFMA16(a,b,c) __builtin_amdgcn_mfma_f32_16x16x32_bf16((a),(b),(c),0,0,0)

// ---------------- zero state ----------------
__global__ __launch_bounds__(256) void k_zero(Ptrs p) {
  unsigned i = blockIdx.x * 256 + threadIdx.x;
  if (i < ZERO_COUNT) p.ws[ZERO_BASE + i] = 0.f;
}

// ---------------- weight transposes for prenet ----------------
__global__ __launch_bounds__(256) void k_transpose(Ptrs p) {
  int i = blockIdx.x * 256 + threadIdx.x;
  if (i < 20480) {
    int m = i >> 8, c = i & 255;
    p.ws[F_W1T + i] = p.Wpre1[c * 80 + m];
  } else if (i < 20480 + 65536) {
    int j = i - 20480;
    int pp = j >> 8, q = j & 255;
    p.ws[F_W2T + j] = p.Wpre2[q * 256 + pp];
  }
}

// ---------------- prenet -> xsb (bf16) ----------------
__global__ __launch_bounds__(256) void k_prenet(Ptrs p) {
  __shared__ float dil[NBATCH * 80];
  __shared__ float h1[NBATCH * 256];
  const int t = blockIdx.x, tid = threadIdx.x;
  const float* W1T = p.ws + F_W1T;
  const float* W2T = p.ws + F_W2T;

  for (int i = tid; i < NBATCH * 80; i += 256) {
    int b = i / 80, m = i - b * 80;
    dil[i] = (t == 0) ? 0.f : p.dec_in[((size_t)b * 80 + m) * 400 + (t - 1)];
  }
  __syncthreads();

  float acc[NBATCH];
#pragma unroll
  for (int b = 0; b < NBATCH; ++b) acc[b] = 0.f;
  for (int m = 0; m < 80; ++m) {
    float w = W1T[m * 256 + tid];
#pragma unroll
    for (int b = 0; b < NBATCH; ++b) acc[b] = fmaf(dil[b * 80 + m], w, acc[b]);
  }
#pragma unroll
  for (int b = 0; b < NBATCH; ++b) h1[b * 256 + tid] = fmaxf(acc[b], 0.f);
  __syncthreads();

#pragma unroll
  for (int b = 0; b < NBATCH; ++b) acc[b] = 0.f;
  for (int q = 0; q < 256; ++q) {
    float w = W2T[q * 256 + tid];
#pragma unroll
    for (int b = 0; b < NBATCH; ++b) acc[b] = fmaf(h1[b * 256 + q], w, acc[b]);
  }
  ushort_t* xsbU = (ushort_t*)(p.ws + F_XSB);
#pragma unroll
  for (int b = 0; b < NBATCH; ++b)
    xsbU[((size_t)(t * NBATCH + b)) * 256 + tid] = (ushort_t)f2bfbits(fmaxf(acc[b], 0.f));
}

// ---------------- proc_mem fp32 ----------------
__global__ __launch_bounds__(256) void k_procmem(Ptrs p) {
  __shared__ alignas(16) float msl[16 * 512];
  const int b = blockIdx.x >> 4, s0 = (blockIdx.x & 15) << 4;
  const int tid = threadIdx.x;
  const float4* src = (const float4*)(p.memory + ((size_t)(b * SMEM + s0)) * 512);
  float4* dst = (float4*)msl;
  for (int i = tid; i < 16 * 512 / 4; i += 256) dst[i] = src[i];
  __syncthreads();

  const int a = tid & 127, sg = tid >> 7;
  const float4* wm = (const float4*)(p.Wm + (size_t)a * 512);
  float* pm = p.ws + F_PM;
  float acc[8];
#pragma unroll
  for (int j = 0; j < 8; ++j) acc[j] = 0.f;
  for (int k = 0; k < 128; ++k) {
    float4 w = wm[k];
#pragma unroll
    for (int j = 0; j < 8; ++j) {
      float4 m = ((const float4*)(msl + (size_t)(sg * 8 + j) * 512))[k];
      acc[j] += w.x * m.x + w.y * m.y + w.z * m.z + w.w * m.w;
    }
  }
#pragma unroll
  for (int j = 0; j < 8; ++j)
    pm[((size_t)(b * SMEM + s0 + sg * 8 + j)) * 128 + a] = acc[j];
}

// ---------------- premix: M[b][row][s] = Wctx[row][:] . memory[b][s][:] ----------------
__global__ __launch_bounds__(512) void k_premix(Ptrs p) {
  const int b = blockIdx.x, tid = threadIdx.x;
  float* M = p.ws + F_MMIX;
  for (int i = tid; i < 81 * 256; i += 512) {
    int row = i >> 8, s = i & 255;
    const float* wrow = (row < 80) ? p.Wproj + (size_t)row * 1536 + 1024 : p.Wgate + 1024;
    const float4* w4 = (const float4*)wrow;
    const float4* m4 = (const float4*)(p.memory + ((size_t)(b * 256 + s)) * 512);
    float acc = 0.f;
#pragma unroll 4
    for (int k = 0; k < 128; ++k) {
      float4 w = w4[k], m = m4[k];
      acc += w.x * m.x + w.y * m.y + w.z * m.z + w.w * m.w;
    }
    M[((size_t)b * 81 + row) * 256 + s] = acc;
  }
}

// ---------------- persistent dataflow scan: 232 blocks x 512 threads ----------------
// Cycle (2 hops): A(ah+qp) -> MERGED(aw+ctx) -> A. D/PROJ off-cycle.
// vs round 10: (1) MERGED q-reduce vectorized to 8x8B agent loads;
// (2) D re-triggered off CTXF only (transitively implies AHF) so its 80KB/step
// staging burst no longer collides with the AHF->MERGED handoff window.
__global__ __launch_bounds__(512, 1) void k_scan(Ptrs p) {
  extern __shared__ char smc[];
  const int bid = blockIdx.x, tid = threadIdx.x;
  const int wid = tid >> 6, lane = tid & 63;
  const int m16 = lane & 15, kq = lane >> 4;

  float* ws = p.ws;
  ushort_t* xsbU  = (ushort_t*)(ws + F_XSB);
  float*    pmF   = ws + F_PM;
  float*    Mx    = ws + F_MMIX;
  unsigned long long* ahb8 = (unsigned long long*)(ws + F_AHB);
  unsigned long long* dhb8 = (unsigned long long*)(ws + F_DHB);
  unsigned long long* ctxb8 = (unsigned long long*)(ws + F_CTXB);
  float*    dhfF  = ws + F_DHF;
  float*    awGF  = ws + F_AWG;
  float*    qpF   = ws + F_QP;
  int*      flg   = (int*)(ws + F_FLG);
  float* out_mel  = p.out;
  float* out_gate = p.out + 512000;
  float* out_al   = p.out + 518400;

  if (bid < 64) {
    // ======== A-path: A-LSTM(t) + q-partials; ah/xs MFMAs hidden under ctx wait ========
    const int ls = wid >> 1, half = wid & 1;
    const int strip = (bid << 2) | ls;
    const int gA = m16 & 3, jA = m16 >> 2;
    const int wrowA = gA * 1024 + strip * 4 + jA;
    bf16x8_t wA[28];
#pragma unroll
    for (int c = 0; c < 28; ++c) {
      int k0 = (half * 28 + c) * 32 + kq * 8;
      const float* src = (k0 < 768) ? p.Wih_a + (size_t)wrowA * 768 + k0
                                    : p.Whh_a + (size_t)wrowA * 1024 + (k0 - 768);
      wA[c] = pack_from_f4(src);
    }
    const int nnA = strip * 4 + kq;
    float biasA[4];
#pragma unroll
    for (int r = 0; r < 4; ++r) biasA[r] = p.bih_a[r * 1024 + nnA] + p.bhh_a[r * 1024 + nnA];
    float acState = 0.f;
    float* ared = (float*)(smc + A_RED);
    float* qwq  = (float*)(smc + A_QWQ);
    float* qh   = (float*)(smc + A_QH);
    for (int i = tid; i < 2048; i += 512) {
      int a = i >> 4, c = i & 15;
      qwq[i] = p.Wq[(size_t)a * 1024 + bid * 16 + c];
    }
    __syncthreads();

    for (int t = 0; t < TSTEPS; ++t) {
      const int pc = t & 1, pp = (t + 1) & 1;
      // start poll: ah(t-1) peers ONLY (D guard deferred to the ctx wait)
      if (tid < 64) pollge(flg, AHF + tid, t);
      __syncthreads();
      // stage ah(t-1) + xs(t)
      {
        const unsigned long long* ag = ahb8 + (size_t)pp * 4096;
        const unsigned long long* xg = (const unsigned long long*)xsbU + (size_t)t * 1024;
        unsigned long long tA[8], tX[2];
#pragma unroll
        for (int i = 0; i < 8; ++i) tA[i] = ldull_a(ag + tid + i * 512);
#pragma unroll
        for (int i = 0; i < 2; ++i) tX[i] = xg[tid + i * 512];
#pragma unroll
        for (int i = 0; i < 8; ++i) { int u = tid + i * 512; lds_st8(smc, A_AH, u >> 8, 11, (u & 255) * 8, tA[i]); }
#pragma unroll
        for (int i = 0; i < 2; ++i) { int u = tid + i * 512; lds_st8(smc, A_XS, u >> 6, 9, (u & 63) * 8, tX[i]); }
      }
      __syncthreads();
      // MFMA phase 1: all ah/xs-dependent chunks (runs while MERGED computes ctx)
      f32x4_t a0 = {0,0,0,0}, a1 = {0,0,0,0};
      if (half == 0) {
#pragma unroll
        for (int c = 0; c < 8; ++c) {
          bf16x8_t bf = lds_bf8(smc, A_XS, m16, 9, c * 64 + kq * 16);
          if (c & 1) a1 = MFMA16(wA[c], bf, a1); else a0 = MFMA16(wA[c], bf, a0);
        }
#pragma unroll
        for (int c = 24; c < 28; ++c) {
          bf16x8_t bf = lds_bf8(smc, A_AH, m16, 11, (c - 24) * 64 + kq * 16);
          if (c & 1) a1 = MFMA16(wA[c], bf, a1); else a0 = MFMA16(wA[c], bf, a0);
        }
      } else {
#pragma unroll
        for (int c = 0; c < 28; ++c) {
          bf16x8_t bf = lds_bf8(smc, A_AH, m16, 11, (4 + c) * 64 + kq * 16);
          if (c & 1) a1 = MFMA16(wA[c], bf, a1); else a0 = MFMA16(wA[c], bf, a0);
        }
#pragma unroll
        for (int r = 0; r < 4; ++r) ared[((ls * 64 + lane) << 2) + r] = a0[r] + a1[r];
      }
      // ctx(t-1) wait + D(t-1) write-guard, polled CONCURRENTLY (disjoint threads).
      if (tid < 32) pollge(flg, CTXF + tid, t);
      else if (tid >= 64 && tid < 192) pollge(flg, DHFL + (tid - 64), t - 1);
      __syncthreads();
      {
        const unsigned long long* cg = ctxb8 + (size_t)pp * 2048;
        unsigned long long tC[4];
#pragma unroll
        for (int i = 0; i < 4; ++i) tC[i] = ldull_a(cg + tid + i * 512);
#pragma unroll
        for (int i = 0; i < 4; ++i) { int u = tid + i * 512; lds_st8(smc, A_CTX, u >> 7, 10, (u & 127) * 8, tC[i]); }
      }
      __syncthreads();
      if (half == 0) {
#pragma unroll
        for (int c = 8; c < 24; ++c) {
          bf16x8_t bf = lds_bf8(smc, A_CTX, m16, 10, (c - 8) * 64 + kq * 16);
          if (c & 1) a1 = MFMA16(wA[c], bf, a1); else a0 = MFMA16(wA[c], bf, a0);
        }
        float z[4];
#pragma unroll
        for (int r = 0; r < 4; ++r)
          z[r] = a0[r] + a1[r] + ared[((ls * 64 + lane) << 2) + r] + biasA[r];
        float cn = fsig(z[1]) * acState + fsig(z[0]) * ftanh(z[2]);
        acState = cn;
        float h = fsig(z[3]) * ftanh(cn);
        qh[(m16 << 4) + ls * 4 + kq] = h;
        unsigned hb = f2bfbits(h);
        unsigned b0 = __shfl(hb, m16);
        unsigned b1 = __shfl(hb, m16 + 16);
        unsigned b2 = __shfl(hb, m16 + 32);
        unsigned b3 = __shfl(hb, m16 + 48);
        if (kq == 0) {
          unsigned long long u = (unsigned long long)(b0 | (b1 << 16))
                               | ((unsigned long long)(b2 | (b3 << 16)) << 32);
          stull_a(ahb8 + ((size_t)(pc * 16 + m16)) * 256 + strip, u);
        }
      }
      __syncthreads();
      // q-partials: qp[blk][b][a] = sum_c Wq[a][blk*16+c] * h[b][blk*16+c]
      {
        int a = tid & 127, bg = tid >> 7;
        const float* wrow = qwq + a * 16;
        float s0 = 0.f, s1 = 0.f, s2 = 0.f, s3 = 0.f;
#pragma unroll
        for (int c = 0; c < 16; ++c) {
          float wv = wrow[c];
          s0 = fmaf(wv, qh[((bg * 4 + 0) << 4) + c], s0);
          s1 = fmaf(wv, qh[((bg * 4 + 1) << 4) + c], s1);
          s2 = fmaf(wv, qh[((bg * 4 + 2) << 4) + c], s2);
          s3 = fmaf(wv, qh[((bg * 4 + 3) << 4) + c], s3);
        }
        float* qps = qpF + (size_t)pc * 131072 + bid * 2048 + a;
        stf_a(qps + (size_t)(bg * 4 + 0) * 128, s0);
        stf_a(qps + (size_t)(bg * 4 + 1) * 128, s1);
        stf_a(qps + (size_t)(bg * 4 + 2) * 128, s2);
        stf_a(qps + (size_t)(bg * 4 + 3) * 128, s3);
      }
      __syncthreads();   // drains ahb + qp stores before flag
      if (tid == 0) sig(flg, AHF + bid, t + 1);
    }
  } else if (bid < 192) {
    // ======== D-path: pure D-LSTM(t-1), triggered off CTXF only ========
    // CTXF>=t transitively implies AHF>=t (MERGED(t-1) polled AHF>=t before
    // signaling), so D's staging burst fires ~4us AFTER the AHF handoff,
    // keeping the AHF->MERGED q-reduce window fabric-quiet.
    const int ls = wid >> 2, qt = wid & 3;
    const int strip = ((bid - 64) << 1) | ls;
    const int gD = m16 & 3, jD = m16 >> 2;
    const int wrowD = gD * 1024 + strip * 4 + jD;
    bf16x8_t wD[20];
#pragma unroll
    for (int c = 0; c < 20; ++c) {
      int k0 = (qt * 20 + c) * 32 + kq * 8;
      const float* src = (k0 < 1536) ? p.Wih_d + (size_t)wrowD * 1536 + k0
                                     : p.Whh_d + (size_t)wrowD * 1024 + (k0 - 1536);
      wD[c] = pack_from_f4(src);
    }
    const int nnD = strip * 4 + kq;
    float biasD[4];
#pragma unroll
    for (int r = 0; r < 4; ++r) biasD[r] = p.bih_d[r * 1024 + nnD] + p.bhh_d[r * 1024 + nnD];
    float dcState = 0.f;
    float* comb = (float*)(smc + D_COMB);
    __syncthreads();

    for (int t = 1; t <= TSTEPS; ++t) {
      const int pc = t & 1, pw = (t + 1) & 1;
      // single trigger: CTXF>=t (implies AHF>=t); DHFL peers; PRF guard (concurrent)
      if (tid < 32) pollge(flg, CTXF + tid, t);
      else if (tid >= 64 && tid < 192) pollge(flg, DHFL + (tid - 64), t - 1);
      else if (tid >= 192 && tid < 200) pollge(flg, PRF + (tid - 192), t - 2);
      __syncthreads();
      // stage ah(t-1) + dh(t-2), then ctx(t-1) (all inputs confirmed ready)
      {
        const unsigned long long* ag = ahb8 + (size_t)pw * 4096;
        const unsigned long long* dg = dhb8 + (size_t)pc * 4096;
        unsigned long long tA[8], tD[8];
#pragma unroll
        for (int i = 0; i < 8; ++i) tA[i] = ldull_a(ag + tid + i * 512);
#pragma unroll
        for (int i = 0; i < 8; ++i) tD[i] = ldull_a(dg + tid + i * 512);
#pragma unroll
        for (int i = 0; i < 8; ++i) { int u = tid + i * 512; lds_st8(smc, D_AH, u >> 8, 11, (u & 255) * 8, tA[i]); }
#pragma unroll
        for (int i = 0; i < 8; ++i) { int u = tid + i * 512; lds_st8(smc, D_DH, u >> 8, 11, (u & 255) * 8, tD[i]); }
      }
      {
        const unsigned long long* cg = ctxb8 + (size_t)pw * 2048;
        unsigned long long tC[4];
#pragma unroll
        for (int i = 0; i < 4; ++i) tC[i] = ldull_a(cg + tid + i * 512);
#pragma unroll
        for (int i = 0; i < 4; ++i) { int u = tid + i * 512; lds_st8(smc, D_CTX, u >> 7, 10, (u & 127) * 8, tC[i]); }
      }
      __syncthreads();

      f32x4_t a0 = {0,0,0,0}, a1 = {0,0,0,0};
#define DFRAG_AH(ch)  lds_bf8(smc, D_AH,  m16, 11, (ch) * 64 + kq * 16)
#define DFRAG_CTX(ch) lds_bf8(smc, D_CTX, m16, 10, (ch) * 64 + kq * 16)
#define DFRAG_DH(ch)  lds_bf8(smc, D_DH,  m16, 11, (ch) * 64 + kq * 16)
#define DMFMA(BF) { bf16x8_t bf = (BF); \
        if (c & 1) a1 = MFMA16(wD[c], bf, a1); else a0 = MFMA16(wD[c], bf, a0); }
      if (qt == 0) {
#pragma unroll
        for (int c = 0; c < 20; ++c) DMFMA(DFRAG_AH(c))
      } else if (qt == 1) {
#pragma unroll
        for (int c = 0; c < 20; ++c) { if (c < 12) DMFMA(DFRAG_AH(20 + c)) else DMFMA(DFRAG_CTX(c - 12)) }
      } else if (qt == 2) {
#pragma unroll
        for (int c = 0; c < 20; ++c) { if (c < 8) DMFMA(DFRAG_CTX(8 + c)) else DMFMA(DFRAG_DH(c - 8)) }
      } else {
#pragma unroll
        for (int c = 0; c < 20; ++c) DMFMA(DFRAG_DH(12 + c))
      }
#undef DMFMA
      if (qt != 0) {
#pragma unroll
        for (int r = 0; r < 4; ++r)
          comb[(((ls * 3 + qt - 1) * 64 + lane) << 2) + r] = a0[r] + a1[r];
      }
      __syncthreads();
      if (qt == 0) {
        float z[4];
#pragma unroll
        for (int r = 0; r < 4; ++r) {
          z[r] = a0[r] + a1[r] + biasD[r];
#pragma unroll
          for (int j = 0; j < 3; ++j) z[r] += comb[(((ls * 3 + j) * 64 + lane) << 2) + r];
        }
        float cn = fsig(z[1]) * dcState + fsig(z[0]) * ftanh(z[2]);
        dcState = cn;
        float h = fsig(z[3]) * ftanh(cn);
        stf_a(dhfF + (size_t)pw * 16384 + m16 * 1024 + nnD, h);
        unsigned hb = f2bfbits(h);
        unsigned b0 = __shfl(hb, m16);
        unsigned b1 = __shfl(hb, m16 + 16);
        unsigned b2 = __shfl(hb, m16 + 32);
        unsigned b3 = __shfl(hb, m16 + 48);
        if (kq == 0) {
          unsigned long long u = (unsigned long long)(b0 | (b1 << 16))
                               | ((unsigned long long)(b2 | (b3 << 16)) << 32);
          stull_a(dhb8 + ((size_t)(pw * 16 + m16)) * 256 + strip, u);
        }
      }
      __syncthreads();
      if (tid == 0) sig(flg, DHFL + (bid - 64), t);
    }
  } else if (bid < 224) {
    // ======== MERGED ATT+CTX: 2 blocks/batch; e/softmax duplicated + ctx half ========
    const int cbid = bid - 192;              // 0..31
    const int b = cbid >> 1, h2 = cbid & 1;
    const int mlenb = p.mlen[b];
    ushort_t* locu = (ushort_t*)(smc + M_LOCU);
    float* qsm   = (float*)(smc + M_QSM);
    float* vsm   = (float*)(smc + M_VSM);
    float* esm   = (float*)(smc + M_ESM);
    float* red   = (float*)(smc + M_RED);
    float* smaw  = (float*)(smc + M_SMAW);
    float* smawc = (float*)(smc + M_SMAWC);
    ushort_t* memu2 = (ushort_t*)(smc + M_MEM);
    float* part  = (float*)(smc + M_PART);
    float* qred  = part;   // overlay: qred [8][128] (q phase) / part (ctx phase)

    bf16x8_t wLd[8];
#pragma unroll
    for (int at = 0; at < 8; ++at)
      wLd[at] = pack_from_f4(p.Wld + ((size_t)(at * 16 + m16)) * 32 + kq * 8);
    bf16x8_t wC[2][2];
#pragma unroll
    for (int ft = 0; ft < 2; ++ft)
#pragma unroll
      for (int ck = 0; ck < 2; ++ck) {
        float tmp[8];
#pragma unroll
        for (int jj = 0; jj < 8; ++jj) {
          int k2 = ck * 32 + kq * 8 + jj;
          float vv = 0.f;
          if (k2 < 62) { int ch = (k2 < 31) ? 0 : 1; int k = k2 - 31 * ch;
            vv = p.Wc[((size_t)(ft * 16 + m16) * 2 + ch) * 31 + k]; }
          tmp[jj] = vv;
        }
        wC[ft][ck] = packbf8(tmp);
      }
    uint_t pmreg[2][8][2];
#pragma unroll
    for (int u = 0; u < 2; ++u) {
      int sloc = (wid * 2 + u) * 16 + m16;
#pragma unroll
      for (int at = 0; at < 8; ++at)
#pragma unroll
        for (int rp = 0; rp < 2; ++rp) {
          const float* src = pmF + ((size_t)(b * 256 + sloc)) * 128 + at * 16 + kq * 4 + rp * 2;
          pmreg[u][at][rp] = f2bfbits(src[0]) | (f2bfbits(src[1]) << 16);
        }
    }
    // one-time: stage mem[b][:, h2*256 .. +256] as bf16
    for (int i = tid; i < 16384; i += 512) {
      int s = i >> 6, c4 = i & 63;
      float4 m = *(const float4*)(p.memory + ((size_t)(b * 256 + s)) * 512 + h2 * 256 + c4 * 4);
      ushort_t* dst = memu2 + s * 256 + c4 * 4;
      dst[0] = (ushort_t)f2bfbits(m.x);
      dst[1] = (ushort_t)f2bfbits(m.y);
      dst[2] = (ushort_t)f2bfbits(m.z);
      dst[3] = (ushort_t)f2bfbits(m.w);
    }
    if (tid < 128) vsm[tid] = p.v[tid];
    if (tid < 256) { smaw[tid] = 0.f; smawc[tid] = 0.f; }
    __syncthreads();

    for (int t = 0; t < TSTEPS; ++t) {
      const int pc = t & 1;
      // conv(t) from own-LDS aw/awc (prev step): overlaps the ah wait
#pragma unroll
      for (int u = 0; u < 4; ++u) {
        int task = wid * 4 + u;
        int stile = task >> 1, ft = task & 1;
        int scol = stile * 16 + m16;
        f32x4_t acc = {0,0,0,0};
#pragma unroll
        for (int ck = 0; ck < 2; ++ck) {
          float tmp[8];
#pragma unroll
          for (int jj = 0; jj < 8; ++jj) {
            int k2 = ck * 32 + kq * 8 + jj;
            float vv = 0.f;
            if (k2 < 62) {
              int ch = (k2 < 31) ? 0 : 1; int k = k2 - 31 * ch;
              int sp = scol + k - 15;
              if (sp >= 0 && sp < 256) vv = (ch ? smawc : smaw)[sp];
            }
            tmp[jj] = vv;
          }
          acc = MFMA16(wC[ft][ck], packbf8(tmp), acc);
        }
#pragma unroll
        for (int r = 0; r < 4; ++r)
          locu[scol * 40 + ft * 16 + kq * 4 + r] = (ushort_t)f2bfbits(acc[r]);
      }
      // waits: ah(t)+qp fresh; DHFL stale (ctxb slot guard); PRF (awGF ring) — concurrent
      if (tid < 64) pollge(flg, AHF + tid, t + 1);
      else if (tid < 192) pollge(flg, DHFL + (tid - 64), t - 1);
      else if (tid < 200) pollge(flg, PRF + (tid - 192), t - 3);
      __syncthreads();
      // q[b] = sum over 64 A-block partials — vectorized: 8 x 8B agent loads/thread
      {
        int a2 = (tid & 63) * 2, g = tid >> 6;    // 8 groups x 8 blocks
        const unsigned long long* qps =
            (const unsigned long long*)(qpF + (size_t)(t & 1) * 131072 + b * 128 + a2);
        float sx = 0.f, sy = 0.f;
#pragma unroll
        for (int j = 0; j < 8; ++j) {
          unsigned long long uv = ldull_a(qps + (size_t)(g * 8 + j) * 1024);
          float2 f = __builtin_bit_cast(float2, uv);
          sx += f.x; sy += f.y;
        }
        qred[g * 128 + a2] = sx;
        qred[g * 128 + a2 + 1] = sy;
      }
      __syncthreads();
      if (tid < 128) {
        float s = 0.f;
#pragma unroll
        for (int g = 0; g < 8; ++g) s += qred[g * 128 + tid];
        qsm[tid] = s;
      }
      __syncthreads();
      // fused pa+e: 2 s-tiles per wave
#pragma unroll
      for (int u = 0; u < 2; ++u) {
        int sloc = (wid * 2 + u) * 16 + m16;
        bf16x8_t Bfrag = ldbf8(locu + sloc * 40 + kq * 8);
        float eacc = 0.f;
#pragma unroll
        for (int at = 0; at < 8; ++at) {
          f32x4_t C = {0,0,0,0};
          C = MFMA16(wLd[at], Bfrag, C);
#pragma unroll
          for (int r = 0; r < 4; ++r) {
            int a = at * 16 + kq * 4 + r;
            uint_t pw_ = pmreg[u][at][r >> 1];
            float pmv = bf2f((ushort_t)((r & 1) ? (pw_ >> 16) : (pw_ & 0xFFFF)));
            eacc = fmaf(vsm[a], ftanh(C[r] + qsm[a] + pmv), eacc);
          }
        }
        eacc += __shfl_xor(eacc, 16);
        eacc += __shfl_xor(eacc, 32);
        if (sloc >= mlenb) eacc = -1.0e9f;
        if (kq == 0) esm[sloc] = eacc;
      }
      __syncthreads();
      // softmax over 256
      float ev = 0.f;
      if (tid < 256) {
        ev = esm[tid];
        float mv = ev;
        for (int o = 32; o; o >>= 1) mv = fmaxf(mv, __shfl_xor(mv, o));
        if (lane == 0) red[wid] = mv;
      }
      __syncthreads();
      float gmax = fmaxf(fmaxf(red[0], red[1]), fmaxf(red[2], red[3]));
      float pv = 0.f;
      if (tid < 256) {
        pv = __expf(ev - gmax);
        float sv = pv;
        for (int o = 32; o; o >>= 1) sv += __shfl_xor(sv, o);
        if (lane == 0) red[8 + wid] = sv;
      }
      __syncthreads();
      float gsum = red[8] + red[9] + red[10] + red[11];
      float awv = 0.f;
      if (tid < 256) {
        awv = pv / gsum;
        smaw[tid] = awv;
        smawc[tid] += awv;
        if (h2 == 0) stf_a(awGF + (size_t)(t & 3) * 4096 + b * 256 + tid, awv);
      }
      __syncthreads();
      // ctx(t) half = aw(t) . mem[b][:, h2*256..+256]  (all in LDS)
      {
        const int c = tid & 127, sg = tid >> 7;
        const uint_t* mrow = (const uint_t*)memu2;
        float c0 = 0.f, c1 = 0.f;
#pragma unroll 8
        for (int si = 0; si < 64; ++si) {
          int s = sg * 64 + si;
          uint_t mm = mrow[s * 128 + c];
          float av = smaw[s];
          c0 = fmaf(bf2f((ushort_t)(mm & 0xFFFF)), av, c0);
          c1 = fmaf(bf2f((ushort_t)(mm >> 16)), av, c1);
        }
        part[sg * 256 + c * 2] = c0;
        part[sg * 256 + c * 2 + 1] = c1;
      }
      __syncthreads();
      if (tid < 64) {
        unsigned pk[4];
#pragma unroll
        for (int j = 0; j < 4; ++j) {
          int col = tid * 4 + j;
          float v = part[col] + part[256 + col] + part[512 + col] + part[768 + col];
          pk[j] = f2bfbits(v);
        }
        unsigned long long u = (unsigned long long)(pk[0] | (pk[1] << 16))
                             | ((unsigned long long)(pk[2] | (pk[3] << 16)) << 32);
        stull_a(ctxb8 + ((size_t)(pc * 16 + b)) * 128 + h2 * 64 + tid, u);
      }
      __syncthreads();   // drain ctxb + awGF stores
      if (tid == 0) {
        sig(flg, CTXF + cbid, t + 1);
        if (h2 == 0) sig(flg, AWF + b, t + 1);
      }
      // off-path output store
      if (h2 == 0 && tid < 256) out_al[((size_t)b * 400 + t) * 256 + tid] = awv;
    }
  } else if (bid < 232) {
    // ======== PROJ path: mel/gate = Wdh.dh(t-1) + M.aw(t-1) + bias ========
    const int wv = (bid - 224) * 8 + wid;   // 0..63
    int rows[2] = {wv * 2, wv * 2 + 1};
    float wdh[2][16], mreg[2][16][4], biasr[2];
#pragma unroll
    for (int rr = 0; rr < 2; ++rr) {
      int row = rows[rr];
      biasr[rr] = 0.f;
#pragma unroll
      for (int j = 0; j < 16; ++j) wdh[rr][j] = 0.f;
#pragma unroll
      for (int b2 = 0; b2 < 16; ++b2)
#pragma unroll
        for (int j = 0; j < 4; ++j) mreg[rr][b2][j] = 0.f;
      if (row <= 80) {
        const float* wsrc = (row < 80) ? p.Wproj + (size_t)row * 1536 : p.Wgate;
#pragma unroll
        for (int j = 0; j < 16; ++j) wdh[rr][j] = wsrc[lane + 64 * j];
        biasr[rr] = (row < 80) ? p.bproj[row] : p.bgate[0];
#pragma unroll
        for (int b2 = 0; b2 < 16; ++b2)
#pragma unroll
          for (int j = 0; j < 4; ++j)
            mreg[rr][b2][j] = Mx[((size_t)b2 * 81 + row) * 256 + lane + 64 * j];
      }
    }
    float* dhp = (float*)(smc + P_DHP);
    float* awp = (float*)(smc + P_AWP);
    __syncthreads();
    for (int t = 1; t <= TSTEPS; ++t) {
      const int pw = (t + 1) & 1;
      if (tid < 128) pollge(flg, DHFL + tid, t);
      else if (tid < 144) pollge(flg, AWF + tid - 128, t);
      __syncthreads();
      {
        const unsigned long long* ag = (const unsigned long long*)(awGF + (size_t)((t - 1) & 3) * 4096);
        const unsigned long long* dg = (const unsigned long long*)(dhfF + (size_t)pw * 16384);
        unsigned long long tw[4], td[16];
#pragma unroll
        for (int i = 0; i < 4; ++i) tw[i] = ldull_a(ag + tid + i * 512);
#pragma unroll
        for (int i = 0; i < 16; ++i) td[i] = ldull_a(dg + tid + i * 512);
#pragma unroll
        for (int i = 0; i < 4; ++i) ((unsigned long long*)awp)[tid + i * 512] = tw[i];
#pragma unroll
        for (int i = 0; i < 16; ++i) ((unsigned long long*)dhp)[tid + i * 512] = td[i];
      }
      __syncthreads();
      if (wv <= 40) {
        for (int b2 = 0; b2 < 16; ++b2) {
          float h[16];
#pragma unroll
          for (int j = 0; j < 16; ++j) h[j] = dhp[b2 * 1024 + lane + 64 * j];
#pragma unroll
          for (int rr = 0; rr < 2; ++rr) {
            if (rows[rr] > 80) continue;
            float d = 0.f;
#pragma unroll
            for (int j = 0; j < 16; ++j) d = fmaf(wdh[rr][j], h[j], d);
#pragma unroll
            for (int j = 0; j < 4; ++j) d = fmaf(mreg[rr][b2][j], awp[b2 * 256 + lane + 64 * j], d);
            for (int o = 32; o; o >>= 1) d += __shfl_xor(d, o);
            if (lane == 0) {
              d += biasr[rr];
              if (rows[rr] < 80) out_mel[((size_t)b2 * 80 + rows[rr]) * 400 + (t - 1)] = d;
              else out_gate[(size_t)b2 * 400 + (t - 1)] = d;
            }
          }
        }
      }
      __syncthreads();
      if (tid == 0) sig(flg, PRF + (bid - 224), t);
    }
  }
}

extern "C" void kernel_launch(void* const* d_in, const int* in_sizes, int n_in,
                              void* d_out, int out_size, void* d_ws, size_t ws_size,
                              hipStream_t stream) {
  (void)in_sizes; (void)n_in; (void)out_size; (void)ws_size;
  Ptrs p;
  p.memory = (const float*)d_in[0];
  p.dec_in = (const float*)d_in[1];
  p.Wpre1  = (const float*)d_in[2];
  p.Wpre2  = (const float*)d_in[3];
  p.Wih_a  = (const float*)d_in[4];
  p.Whh_a  = (const float*)d_in[5];
  p.bih_a  = (const float*)d_in[6];
  p.bhh_a  = (const float*)d_in[7];
  p.Wq     = (const float*)d_in[8];
  p.Wm     = (const float*)d_in[9];
  p.v      = (const float*)d_in[10];
  p.Wc     = (const float*)d_in[11];
  p.Wld    = (const float*)d_in[12];
  p.Wih_d  = (const float*)d_in[13];
  p.Whh_d  = (const float*)d_in[14];
  p.bih_d  = (const float*)d_in[15];
  p.bhh_d  = (const float*)d_in[16];
  p.Wproj  = (const float*)d_in[17];
  p.bproj  = (const float*)d_in[18];
  p.Wgate  = (const float*)d_in[19];
  p.bgate  = (const float*)d_in[20];
  p.mlen   = (const int*)d_in[21];
  p.ws  = (float*)d_ws;
  p.out = (float*)d_out;

  static bool attr_done = false;
  if (!attr_done) {
    hipFuncSetAttribute((const void*)k_scan,
                        hipFuncAttributeMaxDynamicSharedMemorySize, SMEM_BYTES);
    attr_done = true;
  }

  hipLaunchKernelGGL(k_zero,      dim3((ZERO_COUNT + 255) / 256), dim3(256), 0, stream, p);
  hipLaunchKernelGGL(k_transpose, dim3(336), dim3(256), 0, stream, p);
  hipLaunchKernelGGL(k_prenet,    dim3(400), dim3(256), 0, stream, p);
  hipLaunchKernelGGL(k_procmem,   dim3(256), dim3(256), 0, stream, p);
  hipLaunchKernelGGL(k_premix,    dim3(16),  dim3(512), 0, stream, p);
  hipLaunchKernelGGL(k_scan,      dim3(232), dim3(512), SMEM_BYTES, stream, p);
}

// Round 12
// 7722.337 us; speedup vs baseline: 1.2300x; 1.0009x over previous
//
#include <hip/hip_runtime.h>

typedef unsigned short ushort_t;
typedef unsigned int uint_t;
typedef float f32x4_t __attribute__((ext_vector_type(4)));
typedef short bf16x8_t __attribute__((ext_vector_type(8)));

// ---- problem constants ----
#define NBATCH 16
#define SMEM   256
#define TSTEPS 400

// ---- workspace layout (float offsets) ----
#define F_XSB   0u         // 400*16*256 bf16 = 819200 floats
#define F_PM    819200u    // 16*256*128 f32
#define F_MMIX  1343488u   // 16*81*256 f32 (M_b = Wctx . mem^T)
#define F_W1T   1675264u   // prenet W1T
#define F_W2T   1695744u
// ---- zeroed region ----
#define F_AHB   1761280u   // 2*16*1024 bf16 = 16384 floats
#define F_DHB   1777664u   // 16384
#define F_CTXB  1794048u   // 2*16*512 bf16 = 8192 floats
#define F_DHF   1802240u   // 2*16*1024 f32 = 32768
#define F_AWG   1835008u   // 4*16*256 f32 = 16384 (aw ring, slot t&3)
#define F_FLG   1851392u   // 4 replicas x 344 slots x 16 ints = 22016 floats
#define ZERO_BASE  F_AHB
#define ZERO_COUNT 112128u
// ---- q-partials: [2 slots][64 blk][16 b][128 a] f32 = 262144 floats (1 MB) ----
#define F_QP    1873408u

// flag slot bases (stride 16 ints = 64B/slot; 4 replicas at +344 slots each)
#define AHF  0
#define CTXF 64     // 32 flags (merged ATT+CTX blocks)
#define DHFL 192
#define AWF  320
#define PRF  336
#define FREP 344    // replica stride in slots

// ---- dynamic LDS layout (byte offsets); total 160000 B ----
// A-path:
#define A_AH    0        // 32768: ah [16][1024] bf16, swizzled
#define A_CTX   32768    // 16384: ctx [16][512] bf16, swizzled
#define A_XS    49152    // 8192:  xs  [16][256] bf16, swizzled
#define A_RED   57344    // 4096:  cross-half reduce
#define A_QWQ   61440    // 8192:  Wq[:, bid*16..+16] f32 [128 a][16 c]
#define A_QH    69632    // 1024:  h(t) f32 [16 b][16 c]
// D-path:
#define D_AH    0        // 32768
#define D_CTX   32768    // 16384
#define D_DH    49152    // 32768
#define D_COMB  81920    // 6144
// merged ATT+CTX:
#define M_LOCU  0        // 20480
#define M_QSM   20480    // 512
#define M_VSM   20992    // 512
#define M_ESM   21504    // 1024
#define M_RED   22528    // 256
#define M_SMAW  22784    // 1024
#define M_SMAWC 23808    // 1024
#define M_MEM   24832    // 131072: mem[b] half [256 s][256 c] bf16
#define M_PART  155904   // 4096: ctx partials [4][256] f32; ALSO qred [8][128] overlay
// PROJ:
#define P_DHP   0        // 65536
#define P_AWP   65536    // 16384
#define SMEM_BYTES 160000

struct Ptrs {
  const float *memory, *dec_in, *Wpre1, *Wpre2, *Wih_a, *Whh_a, *bih_a, *bhh_a,
              *Wq, *Wm, *v, *Wc, *Wld, *Wih_d, *Whh_d, *bih_d, *bhh_d,
              *Wproj, *bproj, *Wgate, *bgate;
  const int *mlen;
  float *ws;
  float *out;
};

__device__ __forceinline__ float ftanh(float x) {
  float e = __expf(2.f * x);
  return 1.f - 2.f / (e + 1.f);
}
__device__ __forceinline__ float fsig(float x) { return 1.f / (1.f + __expf(-x)); }

__device__ __forceinline__ unsigned f2bfbits(float x) {
  unsigned u = __builtin_bit_cast(unsigned, x);
  return (u + 0x7FFFu + ((u >> 16) & 1u)) >> 16;
}
__device__ __forceinline__ float bf2f(ushort_t u) {
  unsigned v = ((unsigned)u) << 16;
  return __builtin_bit_cast(float, v);
}
__device__ __forceinline__ bf16x8_t packbf8(const float* f) {
  bf16x8_t r;
#pragma unroll
  for (int j = 0; j < 8; ++j) r[j] = (short)f2bfbits(f[j]);
  return r;
}
__device__ __forceinline__ bf16x8_t pack_from_f4(const float* src) {
  const float4* s4 = (const float4*)src;
  float4 lo = s4[0], hi = s4[1];
  float tmp[8] = {lo.x, lo.y, lo.z, lo.w, hi.x, hi.y, hi.z, hi.w};
  return packbf8(tmp);
}
__device__ __forceinline__ bf16x8_t ldbf8(const ushort_t* p) {
  return *(const bf16x8_t*)p;
}
__device__ __forceinline__ unsigned long long ldull_a(const unsigned long long* p) {
  return __hip_atomic_load(p, __ATOMIC_RELAXED, __HIP_MEMORY_SCOPE_AGENT);
}
__device__ __forceinline__ void stull_a(unsigned long long* p, unsigned long long v) {
  __hip_atomic_store(p, v, __ATOMIC_RELAXED, __HIP_MEMORY_SCOPE_AGENT);
}
__device__ __forceinline__ void stf_a(float* p, float v) {
  __hip_atomic_store(p, v, __ATOMIC_RELAXED, __HIP_MEMORY_SCOPE_AGENT);
}
__device__ __forceinline__ float ldf_a(const float* p) {
  return __hip_atomic_load(p, __ATOMIC_RELAXED, __HIP_MEMORY_SCOPE_AGENT);
}
// flag replication: writer stores 4 replicas; poller reads replica (bid&3).
// Spreads ~200 pollers/line across 4 lines so flag STORES don't queue behind
// poll-read storms at the line's home node.
__device__ __forceinline__ void pollge(int* flg, int slot, int thr, int rep) {
  while (__hip_atomic_load(flg + (slot + rep * FREP) * 16, __ATOMIC_RELAXED,
                           __HIP_MEMORY_SCOPE_AGENT) < thr)
    __builtin_amdgcn_s_sleep(1);
}
// backoff variant for slack pollers (D's CTXF, PROJ): 8x less poll traffic
__device__ __forceinline__ void pollge_bk(int* flg, int slot, int thr, int rep) {
  while (__hip_atomic_load(flg + (slot + rep * FREP) * 16, __ATOMIC_RELAXED,
                           __HIP_MEMORY_SCOPE_AGENT) < thr)
    __builtin_amdgcn_s_sleep(8);
}
__device__ __forceinline__ void sig(int* flg, int slot, int val) {
#pragma unroll
  for (int r = 0; r < 4; ++r)
    __hip_atomic_store(flg + (slot + r * FREP) * 16, val, __ATOMIC_RELAXED,
                       __HIP_MEMORY_SCOPE_AGENT);
}
// swizzled LDS helpers: byte ^= ((row&7)<<4)
__device__ __forceinline__ void lds_st8(char* smc, int base, int row, int row_sh,
                                        int bytecol, unsigned long long v) {
  *(unsigned long long*)(smc + base + (row << row_sh) + (bytecol ^ ((row & 7) << 4))) = v;
}
__device__ __forceinline__ bf16x8_t lds_bf8(const char* smc, int base, int row,
                                            int row_sh, int bytecol) {
  return *(const bf16x8_t*)(smc + base + (row << row_sh) + (bytecol ^ ((row & 7) << 4)));
}
#define MFMA16(a,b,c) __builtin_amdgcn_mfma_f32_16x16x32_bf16((a),(b),(c),0,0,0)

// ---------------- zero state ----------------
__global__ __launch_bounds__(256) void k_zero(Ptrs p) {
  unsigned i = blockIdx.x * 256 + threadIdx.x;
  if (i < ZERO_COUNT) p.ws[ZERO_BASE + i] = 0.f;
}

// ---------------- weight transposes for prenet ----------------
__global__ __launch_bounds__(256) void k_transpose(Ptrs p) {
  int i = blockIdx.x * 256 + threadIdx.x;
  if (i < 20480) {
    int m = i >> 8, c = i & 255;
    p.ws[F_W1T + i] = p.Wpre1[c * 80 + m];
  } else if (i < 20480 + 65536) {
    int j = i - 20480;
    int pp = j >> 8, q = j & 255;
    p.ws[F_W2T + j] = p.Wpre2[q * 256 + pp];
  }
}

// ---------------- prenet -> xsb (bf16) ----------------
__global__ __launch_bounds__(256) void k_prenet(Ptrs p) {
  __shared__ float dil[NBATCH * 80];
  __shared__ float h1[NBATCH * 256];
  const int t = blockIdx.x, tid = threadIdx.x;
  const float* W1T = p.ws + F_W1T;
  const float* W2T = p.ws + F_W2T;

  for (int i = tid; i < NBATCH * 80; i += 256) {
    int b = i / 80, m = i - b * 80;
    dil[i] = (t == 0) ? 0.f : p.dec_in[((size_t)b * 80 + m) * 400 + (t - 1)];
  }
  __syncthreads();

  float acc[NBATCH];
#pragma unroll
  for (int b = 0; b < NBATCH; ++b) acc[b] = 0.f;
  for (int m = 0; m < 80; ++m) {
    float w = W1T[m * 256 + tid];
#pragma unroll
    for (int b = 0; b < NBATCH; ++b) acc[b] = fmaf(dil[b * 80 + m], w, acc[b]);
  }
#pragma unroll
  for (int b = 0; b < NBATCH; ++b) h1[b * 256 + tid] = fmaxf(acc[b], 0.f);
  __syncthreads();

#pragma unroll
  for (int b = 0; b < NBATCH; ++b) acc[b] = 0.f;
  for (int q = 0; q < 256; ++q) {
    float w = W2T[q * 256 + tid];
#pragma unroll
    for (int b = 0; b < NBATCH; ++b) acc[b] = fmaf(h1[b * 256 + q], w, acc[b]);
  }
  ushort_t* xsbU = (ushort_t*)(p.ws + F_XSB);
#pragma unroll
  for (int b = 0; b < NBATCH; ++b)
    xsbU[((size_t)(t * NBATCH + b)) * 256 + tid] = (ushort_t)f2bfbits(fmaxf(acc[b], 0.f));
}

// ---------------- proc_mem fp32 ----------------
__global__ __launch_bounds__(256) void k_procmem(Ptrs p) {
  __shared__ alignas(16) float msl[16 * 512];
  const int b = blockIdx.x >> 4, s0 = (blockIdx.x & 15) << 4;
  const int tid = threadIdx.x;
  const float4* src = (const float4*)(p.memory + ((size_t)(b * SMEM + s0)) * 512);
  float4* dst = (float4*)msl;
  for (int i = tid; i < 16 * 512 / 4; i += 256) dst[i] = src[i];
  __syncthreads();

  const int a = tid & 127, sg = tid >> 7;
  const float4* wm = (const float4*)(p.Wm + (size_t)a * 512);
  float* pm = p.ws + F_PM;
  float acc[8];
#pragma unroll
  for (int j = 0; j < 8; ++j) acc[j] = 0.f;
  for (int k = 0; k < 128; ++k) {
    float4 w = wm[k];
#pragma unroll
    for (int j = 0; j < 8; ++j) {
      float4 m = ((const float4*)(msl + (size_t)(sg * 8 + j) * 512))[k];
      acc[j] += w.x * m.x + w.y * m.y + w.z * m.z + w.w * m.w;
    }
  }
#pragma unroll
  for (int j = 0; j < 8; ++j)
    pm[((size_t)(b * SMEM + s0 + sg * 8 + j)) * 128 + a] = acc[j];
}

// ---------------- premix: M[b][row][s] = Wctx[row][:] . memory[b][s][:] ----------------
__global__ __launch_bounds__(512) void k_premix(Ptrs p) {
  const int b = blockIdx.x, tid = threadIdx.x;
  float* M = p.ws + F_MMIX;
  for (int i = tid; i < 81 * 256; i += 512) {
    int row = i >> 8, s = i & 255;
    const float* wrow = (row < 80) ? p.Wproj + (size_t)row * 1536 + 1024 : p.Wgate + 1024;
    const float4* w4 = (const float4*)wrow;
    const float4* m4 = (const float4*)(p.memory + ((size_t)(b * 256 + s)) * 512);
    float acc = 0.f;
#pragma unroll 4
    for (int k = 0; k < 128; ++k) {
      float4 w = w4[k], m = m4[k];
      acc += w.x * m.x + w.y * m.y + w.z * m.z + w.w * m.w;
    }
    M[((size_t)b * 81 + row) * 256 + s] = acc;
  }
}

// ---------------- persistent dataflow scan: 232 blocks x 512 threads ----------------
// Cycle (2 hops): A(ah+qp) -> MERGED(aw+ctx) -> A. D/PROJ off-cycle.
// vs round 11: flags replicated x4 (poller spreads by bid&3), slack pollers
// back off 8x, A's qp stores vectorized to 2x8B.
__global__ __launch_bounds__(512, 1) void k_scan(Ptrs p) {
  extern __shared__ char smc[];
  const int bid = blockIdx.x, tid = threadIdx.x;
  const int wid = tid >> 6, lane = tid & 63;
  const int m16 = lane & 15, kq = lane >> 4;
  const int rep = bid & 3;

  float* ws = p.ws;
  ushort_t* xsbU  = (ushort_t*)(ws + F_XSB);
  float*    pmF   = ws + F_PM;
  float*    Mx    = ws + F_MMIX;
  unsigned long long* ahb8 = (unsigned long long*)(ws + F_AHB);
  unsigned long long* dhb8 = (unsigned long long*)(ws + F_DHB);
  unsigned long long* ctxb8 = (unsigned long long*)(ws + F_CTXB);
  float*    dhfF  = ws + F_DHF;
  float*    awGF  = ws + F_AWG;
  float*    qpF   = ws + F_QP;
  int*      flg   = (int*)(ws + F_FLG);
  float* out_mel  = p.out;
  float* out_gate = p.out + 512000;
  float* out_al   = p.out + 518400;

  if (bid < 64) {
    // ======== A-path: A-LSTM(t) + q-partials; ah/xs MFMAs hidden under ctx wait ========
    const int ls = wid >> 1, half = wid & 1;
    const int strip = (bid << 2) | ls;
    const int gA = m16 & 3, jA = m16 >> 2;
    const int wrowA = gA * 1024 + strip * 4 + jA;
    bf16x8_t wA[28];
#pragma unroll
    for (int c = 0; c < 28; ++c) {
      int k0 = (half * 28 + c) * 32 + kq * 8;
      const float* src = (k0 < 768) ? p.Wih_a + (size_t)wrowA * 768 + k0
                                    : p.Whh_a + (size_t)wrowA * 1024 + (k0 - 768);
      wA[c] = pack_from_f4(src);
    }
    const int nnA = strip * 4 + kq;
    float biasA[4];
#pragma unroll
    for (int r = 0; r < 4; ++r) biasA[r] = p.bih_a[r * 1024 + nnA] + p.bhh_a[r * 1024 + nnA];
    float acState = 0.f;
    float* ared = (float*)(smc + A_RED);
    float* qwq  = (float*)(smc + A_QWQ);
    float* qh   = (float*)(smc + A_QH);
    for (int i = tid; i < 2048; i += 512) {
      int a = i >> 4, c = i & 15;
      qwq[i] = p.Wq[(size_t)a * 1024 + bid * 16 + c];
    }
    __syncthreads();

    for (int t = 0; t < TSTEPS; ++t) {
      const int pc = t & 1, pp = (t + 1) & 1;
      // start poll: ah(t-1) peers ONLY (D guard deferred to the ctx wait)
      if (tid < 64) pollge(flg, AHF + tid, t, rep);
      __syncthreads();
      // stage ah(t-1) + xs(t)
      {
        const unsigned long long* ag = ahb8 + (size_t)pp * 4096;
        const unsigned long long* xg = (const unsigned long long*)xsbU + (size_t)t * 1024;
        unsigned long long tA[8], tX[2];
#pragma unroll
        for (int i = 0; i < 8; ++i) tA[i] = ldull_a(ag + tid + i * 512);
#pragma unroll
        for (int i = 0; i < 2; ++i) tX[i] = xg[tid + i * 512];
#pragma unroll
        for (int i = 0; i < 8; ++i) { int u = tid + i * 512; lds_st8(smc, A_AH, u >> 8, 11, (u & 255) * 8, tA[i]); }
#pragma unroll
        for (int i = 0; i < 2; ++i) { int u = tid + i * 512; lds_st8(smc, A_XS, u >> 6, 9, (u & 63) * 8, tX[i]); }
      }
      __syncthreads();
      // MFMA phase 1: all ah/xs-dependent chunks (runs while MERGED computes ctx)
      f32x4_t a0 = {0,0,0,0}, a1 = {0,0,0,0};
      if (half == 0) {
#pragma unroll
        for (int c = 0; c < 8; ++c) {
          bf16x8_t bf = lds_bf8(smc, A_XS, m16, 9, c * 64 + kq * 16);
          if (c & 1) a1 = MFMA16(wA[c], bf, a1); else a0 = MFMA16(wA[c], bf, a0);
        }
#pragma unroll
        for (int c = 24; c < 28; ++c) {
          bf16x8_t bf = lds_bf8(smc, A_AH, m16, 11, (c - 24) * 64 + kq * 16);
          if (c & 1) a1 = MFMA16(wA[c], bf, a1); else a0 = MFMA16(wA[c], bf, a0);
        }
      } else {
#pragma unroll
        for (int c = 0; c < 28; ++c) {
          bf16x8_t bf = lds_bf8(smc, A_AH, m16, 11, (4 + c) * 64 + kq * 16);
          if (c & 1) a1 = MFMA16(wA[c], bf, a1); else a0 = MFMA16(wA[c], bf, a0);
        }
#pragma unroll
        for (int r = 0; r < 4; ++r) ared[((ls * 64 + lane) << 2) + r] = a0[r] + a1[r];
      }
      // ctx(t-1) wait + D(t-1) write-guard, polled CONCURRENTLY (disjoint threads).
      if (tid < 32) pollge(flg, CTXF + tid, t, rep);
      else if (tid >= 64 && tid < 192) pollge(flg, DHFL + (tid - 64), t - 1, rep);
      __syncthreads();
      {
        const unsigned long long* cg = ctxb8 + (size_t)pp * 2048;
        unsigned long long tC[4];
#pragma unroll
        for (int i = 0; i < 4; ++i) tC[i] = ldull_a(cg + tid + i * 512);
#pragma unroll
        for (int i = 0; i < 4; ++i) { int u = tid + i * 512; lds_st8(smc, A_CTX, u >> 7, 10, (u & 127) * 8, tC[i]); }
      }
      __syncthreads();
      if (half == 0) {
#pragma unroll
        for (int c = 8; c < 24; ++c) {
          bf16x8_t bf = lds_bf8(smc, A_CTX, m16, 10, (c - 8) * 64 + kq * 16);
          if (c & 1) a1 = MFMA16(wA[c], bf, a1); else a0 = MFMA16(wA[c], bf, a0);
        }
        float z[4];
#pragma unroll
        for (int r = 0; r < 4; ++r)
          z[r] = a0[r] + a1[r] + ared[((ls * 64 + lane) << 2) + r] + biasA[r];
        float cn = fsig(z[1]) * acState + fsig(z[0]) * ftanh(z[2]);
        acState = cn;
        float h = fsig(z[3]) * ftanh(cn);
        qh[(m16 << 4) + ls * 4 + kq] = h;
        unsigned hb = f2bfbits(h);
        unsigned b0 = __shfl(hb, m16);
        unsigned b1 = __shfl(hb, m16 + 16);
        unsigned b2 = __shfl(hb, m16 + 32);
        unsigned b3 = __shfl(hb, m16 + 48);
        if (kq == 0) {
          unsigned long long u = (unsigned long long)(b0 | (b1 << 16))
                               | ((unsigned long long)(b2 | (b3 << 16)) << 32);
          stull_a(ahb8 + ((size_t)(pc * 16 + m16)) * 256 + strip, u);
        }
      }
      __syncthreads();
      // q-partials: thread (b=tid&15, ag=tid>>4) computes a=ag*4..+3 for batch b
      // -> 4 contiguous floats in [b][a] layout -> two 8B agent stores
      {
        int b = tid & 15, ag = tid >> 4;
        const float* hrow = qh + b * 16;
        float s0 = 0.f, s1 = 0.f, s2 = 0.f, s3 = 0.f;
#pragma unroll
        for (int c = 0; c < 16; ++c) {
          float hv = hrow[c];
          s0 = fmaf(qwq[(ag * 4 + 0) * 16 + c], hv, s0);
          s1 = fmaf(qwq[(ag * 4 + 1) * 16 + c], hv, s1);
          s2 = fmaf(qwq[(ag * 4 + 2) * 16 + c], hv, s2);
          s3 = fmaf(qwq[(ag * 4 + 3) * 16 + c], hv, s3);
        }
        unsigned long long u0 = (unsigned long long)__builtin_bit_cast(unsigned, s0)
                              | ((unsigned long long)__builtin_bit_cast(unsigned, s1) << 32);
        unsigned long long u1 = (unsigned long long)__builtin_bit_cast(unsigned, s2)
                              | ((unsigned long long)__builtin_bit_cast(unsigned, s3) << 32);
        unsigned long long* qps =
            (unsigned long long*)(qpF + (size_t)pc * 131072 + bid * 2048 + b * 128 + ag * 4);
        stull_a(qps, u0);
        stull_a(qps + 1, u1);
      }
      __syncthreads();   // drains ahb + qp stores before flag
      if (tid == 0) sig(flg, AHF + bid, t + 1);
    }
  } else if (bid < 192) {
    // ======== D-path: pure D-LSTM(t-1), triggered off CTXF only ========
    const int ls = wid >> 2, qt = wid & 3;
    const int strip = ((bid - 64) << 1) | ls;
    const int gD = m16 & 3, jD = m16 >> 2;
    const int wrowD = gD * 1024 + strip * 4 + jD;
    bf16x8_t wD[20];
#pragma unroll
    for (int c = 0; c < 20; ++c) {
      int k0 = (qt * 20 + c) * 32 + kq * 8;
      const float* src = (k0 < 1536) ? p.Wih_d + (size_t)wrowD * 1536 + k0
                                     : p.Whh_d + (size_t)wrowD * 1024 + (k0 - 1536);
      wD[c] = pack_from_f4(src);
    }
    const int nnD = strip * 4 + kq;
    float biasD[4];
#pragma unroll
    for (int r = 0; r < 4; ++r) biasD[r] = p.bih_d[r * 1024 + nnD] + p.bhh_d[r * 1024 + nnD];
    float dcState = 0.f;
    float* comb = (float*)(smc + D_COMB);
    __syncthreads();

    for (int t = 1; t <= TSTEPS; ++t) {
      const int pc = t & 1, pw = (t + 1) & 1;
      // single trigger: CTXF>=t (implies AHF>=t), with 8x backoff (slack path)
      if (tid < 32) pollge_bk(flg, CTXF + tid, t, rep);
      else if (tid >= 64 && tid < 192) pollge(flg, DHFL + (tid - 64), t - 1, rep);
      else if (tid >= 192 && tid < 200) pollge(flg, PRF + (tid - 192), t - 2, rep);
      __syncthreads();
      {
        const unsigned long long* ag = ahb8 + (size_t)pw * 4096;
        const unsigned long long* dg = dhb8 + (size_t)pc * 4096;
        unsigned long long tA[8], tD[8];
#pragma unroll
        for (int i = 0; i < 8; ++i) tA[i] = ldull_a(ag + tid + i * 512);
#pragma unroll
        for (int i = 0; i < 8; ++i) tD[i] = ldull_a(dg + tid + i * 512);
#pragma unroll
        for (int i = 0; i < 8; ++i) { int u = tid + i * 512; lds_st8(smc, D_AH, u >> 8, 11, (u & 255) * 8, tA[i]); }
#pragma unroll
        for (int i = 0; i < 8; ++i) { int u = tid + i * 512; lds_st8(smc, D_DH, u >> 8, 11, (u & 255) * 8, tD[i]); }
      }
      {
        const unsigned long long* cg = ctxb8 + (size_t)pw * 2048;
        unsigned long long tC[4];
#pragma unroll
        for (int i = 0; i < 4; ++i) tC[i] = ldull_a(cg + tid + i * 512);
#pragma unroll
        for (int i = 0; i < 4; ++i) { int u = tid + i * 512; lds_st8(smc, D_CTX, u >> 7, 10, (u & 127) * 8, tC[i]); }
      }
      __syncthreads();

      f32x4_t a0 = {0,0,0,0}, a1 = {0,0,0,0};
#define DFRAG_AH(ch)  lds_bf8(smc, D_AH,  m16, 11, (ch) * 64 + kq * 16)
#define DFRAG_CTX(ch) lds_bf8(smc, D_CTX, m16, 10, (ch) * 64 + kq * 16)
#define DFRAG_DH(ch)  lds_bf8(smc, D_DH,  m16, 11, (ch) * 64 + kq * 16)
#define DMFMA(BF) { bf16x8_t bf = (BF); \
        if (c & 1) a1 = MFMA16(wD[c], bf, a1); else a0 = MFMA16(wD[c], bf, a0); }
      if (qt == 0) {
#pragma unroll
        for (int c = 0; c < 20; ++c) DMFMA(DFRAG_AH(c))
      } else if (qt == 1) {
#pragma unroll
        for (int c = 0; c < 20; ++c) { if (c < 12) DMFMA(DFRAG_AH(20 + c)) else DMFMA(DFRAG_CTX(c - 12)) }
      } else if (qt == 2) {
#pragma unroll
        for (int c = 0; c < 20; ++c) { if (c < 8) DMFMA(DFRAG_CTX(8 + c)) else DMFMA(DFRAG_DH(c - 8)) }
      } else {
#pragma unroll
        for (int c = 0; c < 20; ++c) DMFMA(DFRAG_DH(12 + c))
      }
#undef DMFMA
      if (qt != 0) {
#pragma unroll
        for (int r = 0; r < 4; ++r)
          comb[(((ls * 3 + qt - 1) * 64 + lane) << 2) + r] = a0[r] + a1[r];
      }
      __syncthreads();
      if (qt == 0) {
        float z[4];
#pragma unroll
        for (int r = 0; r < 4; ++r) {
          z[r] = a0[r] + a1[r] + biasD[r];
#pragma unroll
          for (int j = 0; j < 3; ++j) z[r] += comb[(((ls * 3 + j) * 64 + lane) << 2) + r];
        }
        float cn = fsig(z[1]) * dcState + fsig(z[0]) * ftanh(z[2]);
        dcState = cn;
        float h = fsig(z[3]) * ftanh(cn);
        stf_a(dhfF + (size_t)pw * 16384 + m16 * 1024 + nnD, h);
        unsigned hb = f2bfbits(h);
        unsigned b0 = __shfl(hb, m16);
        unsigned b1 = __shfl(hb, m16 + 16);
        unsigned b2 = __shfl(hb, m16 + 32);
        unsigned b3 = __shfl(hb, m16 + 48);
        if (kq == 0) {
          unsigned long long u = (unsigned long long)(b0 | (b1 << 16))
                               | ((unsigned long long)(b2 | (b3 << 16)) << 32);
          stull_a(dhb8 + ((size_t)(pw * 16 + m16)) * 256 + strip, u);
        }
      }
      __syncthreads();
      if (tid == 0) sig(flg, DHFL + (bid - 64), t);
    }
  } else if (bid < 224) {
    // ======== MERGED ATT+CTX: 2 blocks/batch; e/softmax duplicated + ctx half ========
    const int cbid = bid - 192;              // 0..31
    const int b = cbid >> 1, h2 = cbid & 1;
    const int mlenb = p.mlen[b];
    ushort_t* locu = (ushort_t*)(smc + M_LOCU);
    float* qsm   = (float*)(smc + M_QSM);
    float* vsm   = (float*)(smc + M_VSM);
    float* esm   = (float*)(smc + M_ESM);
    float* red   = (float*)(smc + M_RED);
    float* smaw  = (float*)(smc + M_SMAW);
    float* smawc = (float*)(smc + M_SMAWC);
    ushort_t* memu2 = (ushort_t*)(smc + M_MEM);
    float* part  = (float*)(smc + M_PART);
    float* qred  = part;   // overlay: qred [8][128] (q phase) / part (ctx phase)

    bf16x8_t wLd[8];
#pragma unroll
    for (int at = 0; at < 8; ++at)
      wLd[at] = pack_from_f4(p.Wld + ((size_t)(at * 16 + m16)) * 32 + kq * 8);
    bf16x8_t wC[2][2];
#pragma unroll
    for (int ft = 0; ft < 2; ++ft)
#pragma unroll
      for (int ck = 0; ck < 2; ++ck) {
        float tmp[8];
#pragma unroll
        for (int jj = 0; jj < 8; ++jj) {
          int k2 = ck * 32 + kq * 8 + jj;
          float vv = 0.f;
          if (k2 < 62) { int ch = (k2 < 31) ? 0 : 1; int k = k2 - 31 * ch;
            vv = p.Wc[((size_t)(ft * 16 + m16) * 2 + ch) * 31 + k]; }
          tmp[jj] = vv;
        }
        wC[ft][ck] = packbf8(tmp);
      }
    uint_t pmreg[2][8][2];
#pragma unroll
    for (int u = 0; u < 2; ++u) {
      int sloc = (wid * 2 + u) * 16 + m16;
#pragma unroll
      for (int at = 0; at < 8; ++at)
#pragma unroll
        for (int rp = 0; rp < 2; ++rp) {
          const float* src = pmF + ((size_t)(b * 256 + sloc)) * 128 + at * 16 + kq * 4 + rp * 2;
          pmreg[u][at][rp] = f2bfbits(src[0]) | (f2bfbits(src[1]) << 16);
        }
    }
    // one-time: stage mem[b][:, h2*256 .. +256] as bf16
    for (int i = tid; i < 16384; i += 512) {
      int s = i >> 6, c4 = i & 63;
      float4 m = *(const float4*)(p.memory + ((size_t)(b * 256 + s)) * 512 + h2 * 256 + c4 * 4);
      ushort_t* dst = memu2 + s * 256 + c4 * 4;
      dst[0] = (ushort_t)f2bfbits(m.x);
      dst[1] = (ushort_t)f2bfbits(m.y);
      dst[2] = (ushort_t)f2bfbits(m.z);
      dst[3] = (ushort_t)f2bfbits(m.w);
    }
    if (tid < 128) vsm[tid] = p.v[tid];
    if (tid < 256) { smaw[tid] = 0.f; smawc[tid] = 0.f; }
    __syncthreads();

    for (int t = 0; t < TSTEPS; ++t) {
      const int pc = t & 1;
      // conv(t) from own-LDS aw/awc (prev step): overlaps the ah wait
#pragma unroll
      for (int u = 0; u < 4; ++u) {
        int task = wid * 4 + u;
        int stile = task >> 1, ft = task & 1;
        int scol = stile * 16 + m16;
        f32x4_t acc = {0,0,0,0};
#pragma unroll
        for (int ck = 0; ck < 2; ++ck) {
          float tmp[8];
#pragma unroll
          for (int jj = 0; jj < 8; ++jj) {
            int k2 = ck * 32 + kq * 8 + jj;
            float vv = 0.f;
            if (k2 < 62) {
              int ch = (k2 < 31) ? 0 : 1; int k = k2 - 31 * ch;
              int sp = scol + k - 15;
              if (sp >= 0 && sp < 256) vv = (ch ? smawc : smaw)[sp];
            }
            tmp[jj] = vv;
          }
          acc = MFMA16(wC[ft][ck], packbf8(tmp), acc);
        }
#pragma unroll
        for (int r = 0; r < 4; ++r)
          locu[scol * 40 + ft * 16 + kq * 4 + r] = (ushort_t)f2bfbits(acc[r]);
      }
      // waits: ah(t)+qp fresh; DHFL stale (ctxb slot guard); PRF (awGF ring)
      if (tid < 64) pollge(flg, AHF + tid, t + 1, rep);
      else if (tid < 192) pollge(flg, DHFL + (tid - 64), t - 1, rep);
      else if (tid < 200) pollge(flg, PRF + (tid - 192), t - 3, rep);
      __syncthreads();
      // q[b] = sum over 64 A-block partials — 8 x 8B agent loads/thread
      {
        int a2 = (tid & 63) * 2, g = tid >> 6;    // 8 groups x 8 blocks
        const unsigned long long* qps =
            (const unsigned long long*)(qpF + (size_t)(t & 1) * 131072 + b * 128 + a2);
        float sx = 0.f, sy = 0.f;
#pragma unroll
        for (int j = 0; j < 8; ++j) {
          unsigned long long uv = ldull_a(qps + (size_t)(g * 8 + j) * 1024);
          float2 f = __builtin_bit_cast(float2, uv);
          sx += f.x; sy += f.y;
        }
        qred[g * 128 + a2] = sx;
        qred[g * 128 + a2 + 1] = sy;
      }
      __syncthreads();
      if (tid < 128) {
        float s = 0.f;
#pragma unroll
        for (int g = 0; g < 8; ++g) s += qred[g * 128 + tid];
        qsm[tid] = s;
      }
      __syncthreads();
      // fused pa+e: 2 s-tiles per wave
#pragma unroll
      for (int u = 0; u < 2; ++u) {
        int sloc = (wid * 2 + u) * 16 + m16;
        bf16x8_t Bfrag = ldbf8(locu + sloc * 40 + kq * 8);
        float eacc = 0.f;
#pragma unroll
        for (int at = 0; at < 8; ++at) {
          f32x4_t C = {0,0,0,0};
          C = MFMA16(wLd[at], Bfrag, C);
#pragma unroll
          for (int r = 0; r < 4; ++r) {
            int a = at * 16 + kq * 4 + r;
            uint_t pw_ = pmreg[u][at][r >> 1];
            float pmv = bf2f((ushort_t)((r & 1) ? (pw_ >> 16) : (pw_ & 0xFFFF)));
            eacc = fmaf(vsm[a], ftanh(C[r] + qsm[a] + pmv), eacc);
          }
        }
        eacc += __shfl_xor(eacc, 16);
        eacc += __shfl_xor(eacc, 32);
        if (sloc >= mlenb) eacc = -1.0e9f;
        if (kq == 0) esm[sloc] = eacc;
      }
      __syncthreads();
      // softmax over 256
      float ev = 0.f;
      if (tid < 256) {
        ev = esm[tid];
        float mv = ev;
        for (int o = 32; o; o >>= 1) mv = fmaxf(mv, __shfl_xor(mv, o));
        if (lane == 0) red[wid] = mv;
      }
      __syncthreads();
      float gmax = fmaxf(fmaxf(red[0], red[1]), fmaxf(red[2], red[3]));
      float pv = 0.f;
      if (tid < 256) {
        pv = __expf(ev - gmax);
        float sv = pv;
        for (int o = 32; o; o >>= 1) sv += __shfl_xor(sv, o);
        if (lane == 0) red[8 + wid] = sv;
      }
      __syncthreads();
      float gsum = red[8] + red[9] + red[10] + red[11];
      float awv = 0.f;
      if (tid < 256) {
        awv = pv / gsum;
        smaw[tid] = awv;
        smawc[tid] += awv;
        if (h2 == 0) stf_a(awGF + (size_t)(t & 3) * 4096 + b * 256 + tid, awv);
      }
      __syncthreads();
      // ctx(t) half = aw(t) . mem[b][:, h2*256..+256]  (all in LDS)
      {
        const int c = tid & 127, sg = tid >> 7;
        const uint_t* mrow = (const uint_t*)memu2;
        float c0 = 0.f, c1 = 0.f;
#pragma unroll 8
        for (int si = 0; si < 64; ++si) {
          int s = sg * 64 + si;
          uint_t mm = mrow[s * 128 + c];
          float av = smaw[s];
          c0 = fmaf(bf2f((ushort_t)(mm & 0xFFFF)), av, c0);
          c1 = fmaf(bf2f((ushort_t)(mm >> 16)), av, c1);
        }
        part[sg * 256 + c * 2] = c0;
        part[sg * 256 + c * 2 + 1] = c1;
      }
      __syncthreads();
      if (tid < 64) {
        unsigned pk[4];
#pragma unroll
        for (int j = 0; j < 4; ++j) {
          int col = tid * 4 + j;
          float v = part[col] + part[256 + col] + part[512 + col] + part[768 + col];
          pk[j] = f2bfbits(v);
        }
        unsigned long long u = (unsigned long long)(pk[0] | (pk[1] << 16))
                             | ((unsigned long long)(pk[2] | (pk[3] << 16)) << 32);
        stull_a(ctxb8 + ((size_t)(pc * 16 + b)) * 128 + h2 * 64 + tid, u);
      }
      __syncthreads();   // drain ctxb + awGF stores
      if (tid == 0) {
        sig(flg, CTXF + cbid, t + 1);
        if (h2 == 0) sig(flg, AWF + b, t + 1);
      }
      // off-path output store
      if (h2 == 0 && tid < 256) out_al[((size_t)b * 400 + t) * 256 + tid] = awv;
    }
  } else if (bid < 232) {
    // ======== PROJ path: mel/gate = Wdh.dh(t-1) + M.aw(t-1) + bias ========
    const int wv = (bid - 224) * 8 + wid;   // 0..63
    int rows[2] = {wv * 2, wv * 2 + 1};
    float wdh[2][16], mreg[2][16][4], biasr[2];
#pragma unroll
    for (int rr = 0; rr < 2; ++rr) {
      int row = rows[rr];
      biasr[rr] = 0.f;
#pragma unroll
      for (int j = 0; j < 16; ++j) wdh[rr][j] = 0.f;
#pragma unroll
      for (int b2 = 0; b2 < 16; ++b2)
#pragma unroll
        for (int j = 0; j < 4; ++j) mreg[rr][b2][j] = 0.f;
      if (row <= 80) {
        const float* wsrc = (row < 80) ? p.Wproj + (size_t)row * 1536 : p.Wgate;
#pragma unroll
        for (int j = 0; j < 16; ++j) wdh[rr][j] = wsrc[lane + 64 * j];
        biasr[rr] = (row < 80) ? p.bproj[row] : p.bgate[0];
#pragma unroll
        for (int b2 = 0; b2 < 16; ++b2)
#pragma unroll
          for (int j = 0; j < 4; ++j)
            mreg[rr][b2][j] = Mx[((size_t)b2 * 81 + row) * 256 + lane + 64 * j];
      }
    }
    float* dhp = (float*)(smc + P_DHP);
    float* awp = (float*)(smc + P_AWP);
    __syncthreads();
    for (int t = 1; t <= TSTEPS; ++t) {
      const int pw = (t + 1) & 1;
      if (tid < 128) pollge_bk(flg, DHFL + tid, t, rep);
      else if (tid < 144) pollge_bk(flg, AWF + tid - 128, t, rep);
      __syncthreads();
      {
        const unsigned long long* ag = (const unsigned long long*)(awGF + (size_t)((t - 1) & 3) * 4096);
        const unsigned long long* dg = (const unsigned long long*)(dhfF + (size_t)pw * 16384);
        unsigned long long tw[4], td[16];
#pragma unroll
        for (int i = 0; i < 4; ++i) tw[i] = ldull_a(ag + tid + i * 512);
#pragma unroll
        for (int i = 0; i < 16; ++i) td[i] = ldull_a(dg + tid + i * 512);
#pragma unroll
        for (int i = 0; i < 4; ++i) ((unsigned long long*)awp)[tid + i * 512] = tw[i];
#pragma unroll
        for (int i = 0; i < 16; ++i) ((unsigned long long*)dhp)[tid + i * 512] = td[i];
      }
      __syncthreads();
      if (wv <= 40) {
        for (int b2 = 0; b2 < 16; ++b2) {
          float h[16];
#pragma unroll
          for (int j = 0; j < 16; ++j) h[j] = dhp[b2 * 1024 + lane + 64 * j];
#pragma unroll
          for (int rr = 0; rr < 2; ++rr) {
            if (rows[rr] > 80) continue;
            float d = 0.f;
#pragma unroll
            for (int j = 0; j < 16; ++j) d = fmaf(wdh[rr][j], h[j], d);
#pragma unroll
            for (int j = 0; j < 4; ++j) d = fmaf(mreg[rr][b2][j], awp[b2 * 256 + lane + 64 * j], d);
            for (int o = 32; o; o >>= 1) d += __shfl_xor(d, o);
            if (lane == 0) {
              d += biasr[rr];
              if (rows[rr] < 80) out_mel[((size_t)b2 * 80 + rows[rr]) * 400 + (t - 1)] = d;
              else out_gate[(size_t)b2 * 400 + (t - 1)] = d;
            }
          }
        }
      }
      __syncthreads();
      if (tid == 0) sig(flg, PRF + (bid - 224), t);
    }
  }
}

extern "C" void kernel_launch(void* const* d_in, const int* in_sizes, int n_in,
                              void* d_out, int out_size, void* d_ws, size_t ws_size,
                              hipStream_t stream) {
  (void)in_sizes; (void)n_in; (void)out_size; (void)ws_size;
  Ptrs p;
  p.memory = (const float*)d_in[0];
  p.dec_in = (const float*)d_in[1];
  p.Wpre1  = (const float*)d_in[2];
  p.Wpre2  = (const float*)d_in[3];
  p.Wih_a  = (const float*)d_in[4];
  p.Whh_a  = (const float*)d_in[5];
  p.bih_a  = (const float*)d_in[6];
  p.bhh_a  = (const float*)d_in[7];
  p.Wq     = (const float*)d_in[8];
  p.Wm     = (const float*)d_in[9];
  p.v      = (const float*)d_in[10];
  p.Wc     = (const float*)d_in[11];
  p.Wld    = (const float*)d_in[12];
  p.Wih_d  = (const float*)d_in[13];
  p.Whh_d  = (const float*)d_in[14];
  p.bih_d  = (const float*)d_in[15];
  p.bhh_d  = (const float*)d_in[16];
  p.Wproj  = (const float*)d_in[17];
  p.bproj  = (const float*)d_in[18];
  p.Wgate  = (const float*)d_in[19];
  p.bgate  = (const float*)d_in[20];
  p.mlen   = (const int*)d_in[21];
  p.ws  = (float*)d_ws;
  p.out = (float*)d_out;

  static bool attr_done = false;
  if (!attr_done) {
    hipFuncSetAttribute((const void*)k_scan,
                        hipFuncAttributeMaxDynamicSharedMemorySize, SMEM_BYTES);
    attr_done = true;
  }

  hipLaunchKernelGGL(k_zero,      dim3((ZERO_COUNT + 255) / 256), dim3(256), 0, stream, p);
  hipLaunchKernelGGL(k_transpose, dim3(336), dim3(256), 0, stream, p);
  hipLaunchKernelGGL(k_prenet,    dim3(400), dim3(256), 0, stream, p);
  hipLaunchKernelGGL(k_procmem,   dim3(256), dim3(256), 0, stream, p);
  hipLaunchKernelGGL(k_premix,    dim3(16),  dim3(512), 0, stream, p);
  hipLaunchKernelGGL(k_scan,      dim3(232), dim3(512), SMEM_BYTES, stream, p);
}

// Round 13
// 7682.045 us; speedup vs baseline: 1.2364x; 1.0052x over previous
//
#include <hip/hip_runtime.h>

typedef unsigned short ushort_t;
typedef unsigned int uint_t;
typedef float f32x4_t __attribute__((ext_vector_type(4)));
typedef short bf16x8_t __attribute__((ext_vector_type(8)));

// ---- problem constants ----
#define NBATCH 16
#define SMEM   256
#define TSTEPS 400

// ---- workspace layout (float offsets) ----
#define F_XSB   0u         // 400*16*256 bf16 = 819200 floats
#define F_PM    819200u    // 16*256*128 f32
#define F_MMIX  1343488u   // 16*81*256 f32 (M_b = Wctx . mem^T)
#define F_W1T   1675264u   // prenet W1T
#define F_W2T   1695744u
// ---- zeroed region ----
#define F_AHB   1761280u   // 2*16*1024 bf16 = 16384 floats
#define F_DHB   1777664u   // 16384
#define F_CTXB  1794048u   // 2*16*512 bf16 = 8192 floats
#define F_DHF   1802240u   // 2*16*1024 f32 = 32768
#define F_AWG   1835008u   // 4*16*256 f32 = 16384 (aw ring, slot t&3)
#define F_FLG   1851392u   // 4 replicas x 344 slots x 16 ints = 22016 floats
#define ZERO_BASE  F_AHB
#define ZERO_COUNT 112128u
// ---- q-partials: [2 slots][64 blk][16 b][128 a] f32 = 262144 floats (1 MB) ----
#define F_QP    1873408u

// flag slot bases (stride 16 ints = 64B/slot; 4 replicas at +344 slots each)
#define AHF  0
#define CTXF 64     // 32 flags (merged ATT+CTX blocks)
#define DHFL 192
#define AWF  320
#define PRF  336
#define FREP 344    // replica stride in slots

// ---- dynamic LDS layout (byte offsets); total 160000 B ----
// A-path:
#define A_AH    0        // 32768: ah [16][1024] bf16, swizzled
#define A_CTX   32768    // 16384: ctx [16][512] bf16, swizzled
#define A_XS    49152    // 8192:  xs  [16][256] bf16, swizzled
#define A_RED   57344    // 4096:  cross-half reduce
#define A_QWQ   61440    // 8192:  Wq[:, bid*16..+16] f32 [128 a][16 c]
#define A_QH    69632    // 1024:  h(t) f32 [16 b][16 c]
// D-path:
#define D_AH    0        // 32768
#define D_CTX   32768    // 16384
#define D_DH    49152    // 32768
#define D_COMB  81920    // 6144
// merged ATT+CTX:
#define M_LOCU  0        // 20480
#define M_QSM   20480    // 512
#define M_VSM   20992    // 512
#define M_ESM   21504    // 1024
#define M_RED   22528    // 256
#define M_SMAW  22784    // 1024
#define M_SMAWC 23808    // 1024
#define M_MEM   24832    // 131072: mem[b] half [256 s][256 c] bf16
#define M_PART  155904   // 4096: ctx partials [4][256] f32; ALSO qred [8][128] overlay
// PROJ:
#define P_DHP   0        // 65536
#define P_AWP   65536    // 16384
#define SMEM_BYTES 160000

struct Ptrs {
  const float *memory, *dec_in, *Wpre1, *Wpre2, *Wih_a, *Whh_a, *bih_a, *bhh_a,
              *Wq, *Wm, *v, *Wc, *Wld, *Wih_d, *Whh_d, *bih_d, *bhh_d,
              *Wproj, *bproj, *Wgate, *bgate;
  const int *mlen;
  float *ws;
  float *out;
};

__device__ __forceinline__ float ftanh(float x) {
  float e = __expf(2.f * x);
  return 1.f - 2.f / (e + 1.f);
}
__device__ __forceinline__ float fsig(float x) { return 1.f / (1.f + __expf(-x)); }

__device__ __forceinline__ unsigned f2bfbits(float x) {
  unsigned u = __builtin_bit_cast(unsigned, x);
  return (u + 0x7FFFu + ((u >> 16) & 1u)) >> 16;
}
__device__ __forceinline__ float bf2f(ushort_t u) {
  unsigned v = ((unsigned)u) << 16;
  return __builtin_bit_cast(float, v);
}
__device__ __forceinline__ bf16x8_t packbf8(const float* f) {
  bf16x8_t r;
#pragma unroll
  for (int j = 0; j < 8; ++j) r[j] = (short)f2bfbits(f[j]);
  return r;
}
__device__ __forceinline__ bf16x8_t pack_from_f4(const float* src) {
  const float4* s4 = (const float4*)src;
  float4 lo = s4[0], hi = s4[1];
  float tmp[8] = {lo.x, lo.y, lo.z, lo.w, hi.x, hi.y, hi.z, hi.w};
  return packbf8(tmp);
}
__device__ __forceinline__ bf16x8_t ldbf8(const ushort_t* p) {
  return *(const bf16x8_t*)p;
}
__device__ __forceinline__ unsigned long long ldull_a(const unsigned long long* p) {
  return __hip_atomic_load(p, __ATOMIC_RELAXED, __HIP_MEMORY_SCOPE_AGENT);
}
__device__ __forceinline__ void stull_a(unsigned long long* p, unsigned long long v) {
  __hip_atomic_store(p, v, __ATOMIC_RELAXED, __HIP_MEMORY_SCOPE_AGENT);
}
__device__ __forceinline__ void stf_a(float* p, float v) {
  __hip_atomic_store(p, v, __ATOMIC_RELAXED, __HIP_MEMORY_SCOPE_AGENT);
}
__device__ __forceinline__ float ldf_a(const float* p) {
  return __hip_atomic_load(p, __ATOMIC_RELAXED, __HIP_MEMORY_SCOPE_AGENT);
}
// flag replication: writer stores 4 replicas; poller reads replica (bid&3).
__device__ __forceinline__ void pollge(int* flg, int slot, int thr, int rep) {
  while (__hip_atomic_load(flg + (slot + rep * FREP) * 16, __ATOMIC_RELAXED,
                           __HIP_MEMORY_SCOPE_AGENT) < thr)
    __builtin_amdgcn_s_sleep(1);
}
// backoff variant for slack pollers: 8x less poll traffic
__device__ __forceinline__ void pollge_bk(int* flg, int slot, int thr, int rep) {
  while (__hip_atomic_load(flg + (slot + rep * FREP) * 16, __ATOMIC_RELAXED,
                           __HIP_MEMORY_SCOPE_AGENT) < thr)
    __builtin_amdgcn_s_sleep(8);
}
__device__ __forceinline__ void sig(int* flg, int slot, int val) {
#pragma unroll
  for (int r = 0; r < 4; ++r)
    __hip_atomic_store(flg + (slot + r * FREP) * 16, val, __ATOMIC_RELAXED,
                       __HIP_MEMORY_SCOPE_AGENT);
}
// swizzled LDS helpers: byte ^= ((row&7)<<4)
__device__ __forceinline__ void lds_st8(char* smc, int base, int row, int row_sh,
                                        int bytecol, unsigned long long v) {
  *(unsigned long long*)(smc + base + (row << row_sh) + (bytecol ^ ((row & 7) << 4))) = v;
}
__device__ __forceinline__ bf16x8_t lds_bf8(const char* smc, int base, int row,
                                            int row_sh, int bytecol) {
  return *(const bf16x8_t*)(smc + base + (row << row_sh) + (bytecol ^ ((row & 7) << 4)));
}
#define MFMA16(a,b,c) __builtin_amdgcn_mfma_f32_16x16x32_bf16((a),(b),(c),0,0,0)

// ---------------- zero state ----------------
__global__ __launch_bounds__(256) void k_zero(Ptrs p) {
  unsigned i = blockIdx.x * 256 + threadIdx.x;
  if (i < ZERO_COUNT) p.ws[ZERO_BASE + i] = 0.f;
}

// ---------------- weight transposes for prenet ----------------
__global__ __launch_bounds__(256) void k_transpose(Ptrs p) {
  int i = blockIdx.x * 256 + threadIdx.x;
  if (i < 20480) {
    int m = i >> 8, c = i & 255;
    p.ws[F_W1T + i] = p.Wpre1[c * 80 + m];
  } else if (i < 20480 + 65536) {
    int j = i - 20480;
    int pp = j >> 8, q = j & 255;
    p.ws[F_W2T + j] = p.Wpre2[q * 256 + pp];
  }
}

// ---------------- prenet -> xsb (bf16) ----------------
__global__ __launch_bounds__(256) void k_prenet(Ptrs p) {
  __shared__ float dil[NBATCH * 80];
  __shared__ float h1[NBATCH * 256];
  const int t = blockIdx.x, tid = threadIdx.x;
  const float* W1T = p.ws + F_W1T;
  const float* W2T = p.ws + F_W2T;

  for (int i = tid; i < NBATCH * 80; i += 256) {
    int b = i / 80, m = i - b * 80;
    dil[i] = (t == 0) ? 0.f : p.dec_in[((size_t)b * 80 + m) * 400 + (t - 1)];
  }
  __syncthreads();

  float acc[NBATCH];
#pragma unroll
  for (int b = 0; b < NBATCH; ++b) acc[b] = 0.f;
  for (int m = 0; m < 80; ++m) {
    float w = W1T[m * 256 + tid];
#pragma unroll
    for (int b = 0; b < NBATCH; ++b) acc[b] = fmaf(dil[b * 80 + m], w, acc[b]);
  }
#pragma unroll
  for (int b = 0; b < NBATCH; ++b) h1[b * 256 + tid] = fmaxf(acc[b], 0.f);
  __syncthreads();

#pragma unroll
  for (int b = 0; b < NBATCH; ++b) acc[b] = 0.f;
  for (int q = 0; q < 256; ++q) {
    float w = W2T[q * 256 + tid];
#pragma unroll
    for (int b = 0; b < NBATCH; ++b) acc[b] = fmaf(h1[b * 256 + q], w, acc[b]);
  }
  ushort_t* xsbU = (ushort_t*)(p.ws + F_XSB);
#pragma unroll
  for (int b = 0; b < NBATCH; ++b)
    xsbU[((size_t)(t * NBATCH + b)) * 256 + tid] = (ushort_t)f2bfbits(fmaxf(acc[b], 0.f));
}

// ---------------- proc_mem fp32 ----------------
__global__ __launch_bounds__(256) void k_procmem(Ptrs p) {
  __shared__ alignas(16) float msl[16 * 512];
  const int b = blockIdx.x >> 4, s0 = (blockIdx.x & 15) << 4;
  const int tid = threadIdx.x;
  const float4* src = (const float4*)(p.memory + ((size_t)(b * SMEM + s0)) * 512);
  float4* dst = (float4*)msl;
  for (int i = tid; i < 16 * 512 / 4; i += 256) dst[i] = src[i];
  __syncthreads();

  const int a = tid & 127, sg = tid >> 7;
  const float4* wm = (const float4*)(p.Wm + (size_t)a * 512);
  float* pm = p.ws + F_PM;
  float acc[8];
#pragma unroll
  for (int j = 0; j < 8; ++j) acc[j] = 0.f;
  for (int k = 0; k < 128; ++k) {
    float4 w = wm[k];
#pragma unroll
    for (int j = 0; j < 8; ++j) {
      float4 m = ((const float4*)(msl + (size_t)(sg * 8 + j) * 512))[k];
      acc[j] += w.x * m.x + w.y * m.y + w.z * m.z + w.w * m.w;
    }
  }
#pragma unroll
  for (int j = 0; j < 8; ++j)
    pm[((size_t)(b * SMEM + s0 + sg * 8 + j)) * 128 + a] = acc[j];
}

// ---------------- premix: M[b][row][s] = Wctx[row][:] . memory[b][s][:] ----------------
__global__ __launch_bounds__(512) void k_premix(Ptrs p) {
  const int b = blockIdx.x, tid = threadIdx.x;
  float* M = p.ws + F_MMIX;
  for (int i = tid; i < 81 * 256; i += 512) {
    int row = i >> 8, s = i & 255;
    const float* wrow = (row < 80) ? p.Wproj + (size_t)row * 1536 + 1024 : p.Wgate + 1024;
    const float4* w4 = (const float4*)wrow;
    const float4* m4 = (const float4*)(p.memory + ((size_t)(b * 256 + s)) * 512);
    float acc = 0.f;
#pragma unroll 4
    for (int k = 0; k < 128; ++k) {
      float4 w = w4[k], m = m4[k];
      acc += w.x * m.x + w.y * m.y + w.z * m.z + w.w * m.w;
    }
    M[((size_t)b * 81 + row) * 256 + s] = acc;
  }
}

// ---------------- persistent dataflow scan: 232 blocks x 512 threads ----------------
// Cycle (2 hops): A(ah+qp) -> MERGED(aw+ctx) -> A. D/PROJ off-cycle.
// vs round 12: D's staging is SPREAD across the step's quiet windows
// (dh at iteration start, ah at AHF, only ctx in the CTXF window) so the
// 10MB/step D burst no longer congests A's critical ctx-stage window.
__global__ __launch_bounds__(512, 1) void k_scan(Ptrs p) {
  extern __shared__ char smc[];
  const int bid = blockIdx.x, tid = threadIdx.x;
  const int wid = tid >> 6, lane = tid & 63;
  const int m16 = lane & 15, kq = lane >> 4;
  const int rep = bid & 3;

  float* ws = p.ws;
  ushort_t* xsbU  = (ushort_t*)(ws + F_XSB);
  float*    pmF   = ws + F_PM;
  float*    Mx    = ws + F_MMIX;
  unsigned long long* ahb8 = (unsigned long long*)(ws + F_AHB);
  unsigned long long* dhb8 = (unsigned long long*)(ws + F_DHB);
  unsigned long long* ctxb8 = (unsigned long long*)(ws + F_CTXB);
  float*    dhfF  = ws + F_DHF;
  float*    awGF  = ws + F_AWG;
  float*    qpF   = ws + F_QP;
  int*      flg   = (int*)(ws + F_FLG);
  float* out_mel  = p.out;
  float* out_gate = p.out + 512000;
  float* out_al   = p.out + 518400;

  if (bid < 64) {
    // ======== A-path: A-LSTM(t) + q-partials; ah/xs MFMAs hidden under ctx wait ========
    const int ls = wid >> 1, half = wid & 1;
    const int strip = (bid << 2) | ls;
    const int gA = m16 & 3, jA = m16 >> 2;
    const int wrowA = gA * 1024 + strip * 4 + jA;
    bf16x8_t wA[28];
#pragma unroll
    for (int c = 0; c < 28; ++c) {
      int k0 = (half * 28 + c) * 32 + kq * 8;
      const float* src = (k0 < 768) ? p.Wih_a + (size_t)wrowA * 768 + k0
                                    : p.Whh_a + (size_t)wrowA * 1024 + (k0 - 768);
      wA[c] = pack_from_f4(src);
    }
    const int nnA = strip * 4 + kq;
    float biasA[4];
#pragma unroll
    for (int r = 0; r < 4; ++r) biasA[r] = p.bih_a[r * 1024 + nnA] + p.bhh_a[r * 1024 + nnA];
    float acState = 0.f;
    float* ared = (float*)(smc + A_RED);
    float* qwq  = (float*)(smc + A_QWQ);
    float* qh   = (float*)(smc + A_QH);
    for (int i = tid; i < 2048; i += 512) {
      int a = i >> 4, c = i & 15;
      qwq[i] = p.Wq[(size_t)a * 1024 + bid * 16 + c];
    }
    __syncthreads();

    for (int t = 0; t < TSTEPS; ++t) {
      const int pc = t & 1, pp = (t + 1) & 1;
      // start poll: ah(t-1) peers ONLY (D guard deferred to the ctx wait)
      if (tid < 64) pollge(flg, AHF + tid, t, rep);
      __syncthreads();
      // stage ah(t-1) + xs(t)
      {
        const unsigned long long* ag = ahb8 + (size_t)pp * 4096;
        const unsigned long long* xg = (const unsigned long long*)xsbU + (size_t)t * 1024;
        unsigned long long tA[8], tX[2];
#pragma unroll
        for (int i = 0; i < 8; ++i) tA[i] = ldull_a(ag + tid + i * 512);
#pragma unroll
        for (int i = 0; i < 2; ++i) tX[i] = xg[tid + i * 512];
#pragma unroll
        for (int i = 0; i < 8; ++i) { int u = tid + i * 512; lds_st8(smc, A_AH, u >> 8, 11, (u & 255) * 8, tA[i]); }
#pragma unroll
        for (int i = 0; i < 2; ++i) { int u = tid + i * 512; lds_st8(smc, A_XS, u >> 6, 9, (u & 63) * 8, tX[i]); }
      }
      __syncthreads();
      // MFMA phase 1: all ah/xs-dependent chunks (runs while MERGED computes ctx)
      f32x4_t a0 = {0,0,0,0}, a1 = {0,0,0,0};
      if (half == 0) {
#pragma unroll
        for (int c = 0; c < 8; ++c) {
          bf16x8_t bf = lds_bf8(smc, A_XS, m16, 9, c * 64 + kq * 16);
          if (c & 1) a1 = MFMA16(wA[c], bf, a1); else a0 = MFMA16(wA[c], bf, a0);
        }
#pragma unroll
        for (int c = 24; c < 28; ++c) {
          bf16x8_t bf = lds_bf8(smc, A_AH, m16, 11, (c - 24) * 64 + kq * 16);
          if (c & 1) a1 = MFMA16(wA[c], bf, a1); else a0 = MFMA16(wA[c], bf, a0);
        }
      } else {
#pragma unroll
        for (int c = 0; c < 28; ++c) {
          bf16x8_t bf = lds_bf8(smc, A_AH, m16, 11, (4 + c) * 64 + kq * 16);
          if (c & 1) a1 = MFMA16(wA[c], bf, a1); else a0 = MFMA16(wA[c], bf, a0);
        }
#pragma unroll
        for (int r = 0; r < 4; ++r) ared[((ls * 64 + lane) << 2) + r] = a0[r] + a1[r];
      }
      // ctx(t-1) wait + D(t-1) write-guard, polled CONCURRENTLY (disjoint threads).
      if (tid < 32) pollge(flg, CTXF + tid, t, rep);
      else if (tid >= 64 && tid < 192) pollge(flg, DHFL + (tid - 64), t - 1, rep);
      __syncthreads();
      {
        const unsigned long long* cg = ctxb8 + (size_t)pp * 2048;
        unsigned long long tC[4];
#pragma unroll
        for (int i = 0; i < 4; ++i) tC[i] = ldull_a(cg + tid + i * 512);
#pragma unroll
        for (int i = 0; i < 4; ++i) { int u = tid + i * 512; lds_st8(smc, A_CTX, u >> 7, 10, (u & 127) * 8, tC[i]); }
      }
      __syncthreads();
      if (half == 0) {
#pragma unroll
        for (int c = 8; c < 24; ++c) {
          bf16x8_t bf = lds_bf8(smc, A_CTX, m16, 10, (c - 8) * 64 + kq * 16);
          if (c & 1) a1 = MFMA16(wA[c], bf, a1); else a0 = MFMA16(wA[c], bf, a0);
        }
        float z[4];
#pragma unroll
        for (int r = 0; r < 4; ++r)
          z[r] = a0[r] + a1[r] + ared[((ls * 64 + lane) << 2) + r] + biasA[r];
        float cn = fsig(z[1]) * acState + fsig(z[0]) * ftanh(z[2]);
        acState = cn;
        float h = fsig(z[3]) * ftanh(cn);
        qh[(m16 << 4) + ls * 4 + kq] = h;
        unsigned hb = f2bfbits(h);
        unsigned b0 = __shfl(hb, m16);
        unsigned b1 = __shfl(hb, m16 + 16);
        unsigned b2 = __shfl(hb, m16 + 32);
        unsigned b3 = __shfl(hb, m16 + 48);
        if (kq == 0) {
          unsigned long long u = (unsigned long long)(b0 | (b1 << 16))
                               | ((unsigned long long)(b2 | (b3 << 16)) << 32);
          stull_a(ahb8 + ((size_t)(pc * 16 + m16)) * 256 + strip, u);
        }
      }
      __syncthreads();
      // q-partials: thread (b=tid&15, ag=tid>>4) computes a=ag*4..+3 for batch b
      {
        int b = tid & 15, ag = tid >> 4;
        const float* hrow = qh + b * 16;
        float s0 = 0.f, s1 = 0.f, s2 = 0.f, s3 = 0.f;
#pragma unroll
        for (int c = 0; c < 16; ++c) {
          float hv = hrow[c];
          s0 = fmaf(qwq[(ag * 4 + 0) * 16 + c], hv, s0);
          s1 = fmaf(qwq[(ag * 4 + 1) * 16 + c], hv, s1);
          s2 = fmaf(qwq[(ag * 4 + 2) * 16 + c], hv, s2);
          s3 = fmaf(qwq[(ag * 4 + 3) * 16 + c], hv, s3);
        }
        unsigned long long u0 = (unsigned long long)__builtin_bit_cast(unsigned, s0)
                              | ((unsigned long long)__builtin_bit_cast(unsigned, s1) << 32);
        unsigned long long u1 = (unsigned long long)__builtin_bit_cast(unsigned, s2)
                              | ((unsigned long long)__builtin_bit_cast(unsigned, s3) << 32);
        unsigned long long* qps =
            (unsigned long long*)(qpF + (size_t)pc * 131072 + bid * 2048 + b * 128 + ag * 4);
        stull_a(qps, u0);
        stull_a(qps + 1, u1);
      }
      __syncthreads();   // drains ahb + qp stores before flag
      if (tid == 0) sig(flg, AHF + bid, t + 1);
    }
  } else if (bid < 192) {
    // ======== D-path: pure D-LSTM(t-1); staging SPREAD by input readiness ========
    // dh(t-2): ready since DHFL(t-1) -> stage at iteration start (quiet window)
    // ah(t-1): ready since AHF(t)    -> stage second (lands in MERGED's VALU phase)
    // ctx(t-1): ready at CTXF(t)     -> only 16KB left in the contended window
    const int ls = wid >> 2, qt = wid & 3;
    const int strip = ((bid - 64) << 1) | ls;
    const int gD = m16 & 3, jD = m16 >> 2;
    const int wrowD = gD * 1024 + strip * 4 + jD;
    bf16x8_t wD[20];
#pragma unroll
    for (int c = 0; c < 20; ++c) {
      int k0 = (qt * 20 + c) * 32 + kq * 8;
      const float* src = (k0 < 1536) ? p.Wih_d + (size_t)wrowD * 1536 + k0
                                     : p.Whh_d + (size_t)wrowD * 1024 + (k0 - 1536);
      wD[c] = pack_from_f4(src);
    }
    const int nnD = strip * 4 + kq;
    float biasD[4];
#pragma unroll
    for (int r = 0; r < 4; ++r) biasD[r] = p.bih_d[r * 1024 + nnD] + p.bhh_d[r * 1024 + nnD];
    float dcState = 0.f;
    float* comb = (float*)(smc + D_COMB);
    __syncthreads();

    for (int t = 1; t <= TSTEPS; ++t) {
      const int pc = t & 1, pw = (t + 1) & 1;
      // phase 1: dhb slot guard (peers staged at t-1) + PROJ ring guard; both
      // pre-satisfied -> stage dh(t-2) immediately in the quiet window
      if (tid < 128) pollge_bk(flg, DHFL + tid, t - 1, rep);
      else if (tid < 136) pollge_bk(flg, PRF + (tid - 128), t - 2, rep);
      __syncthreads();
      {
        const unsigned long long* dg = dhb8 + (size_t)pc * 4096;
        unsigned long long tD[8];
#pragma unroll
        for (int i = 0; i < 8; ++i) tD[i] = ldull_a(dg + tid + i * 512);
#pragma unroll
        for (int i = 0; i < 8; ++i) { int u = tid + i * 512; lds_st8(smc, D_DH, u >> 8, 11, (u & 255) * 8, tD[i]); }
      }
      // phase 2: ah(t-1) (AHF long satisfied; backoff poll)
      if (tid < 64) pollge_bk(flg, AHF + tid, t, rep);
      __syncthreads();
      {
        const unsigned long long* ag = ahb8 + (size_t)pw * 4096;
        unsigned long long tA[8];
#pragma unroll
        for (int i = 0; i < 8; ++i) tA[i] = ldull_a(ag + tid + i * 512);
#pragma unroll
        for (int i = 0; i < 8; ++i) { int u = tid + i * 512; lds_st8(smc, D_AH, u >> 8, 11, (u & 255) * 8, tA[i]); }
      }
      // phase 3: ctx(t-1) — the only stage left in the CTXF window
      if (tid < 32) pollge_bk(flg, CTXF + tid, t, rep);
      __syncthreads();
      {
        const unsigned long long* cg = ctxb8 + (size_t)pw * 2048;
        unsigned long long tC[4];
#pragma unroll
        for (int i = 0; i < 4; ++i) tC[i] = ldull_a(cg + tid + i * 512);
#pragma unroll
        for (int i = 0; i < 4; ++i) { int u = tid + i * 512; lds_st8(smc, D_CTX, u >> 7, 10, (u & 127) * 8, tC[i]); }
      }
      __syncthreads();

      f32x4_t a0 = {0,0,0,0}, a1 = {0,0,0,0};
#define DFRAG_AH(ch)  lds_bf8(smc, D_AH,  m16, 11, (ch) * 64 + kq * 16)
#define DFRAG_CTX(ch) lds_bf8(smc, D_CTX, m16, 10, (ch) * 64 + kq * 16)
#define DFRAG_DH(ch)  lds_bf8(smc, D_DH,  m16, 11, (ch) * 64 + kq * 16)
#define DMFMA(BF) { bf16x8_t bf = (BF); \
        if (c & 1) a1 = MFMA16(wD[c], bf, a1); else a0 = MFMA16(wD[c], bf, a0); }
      if (qt == 0) {
#pragma unroll
        for (int c = 0; c < 20; ++c) DMFMA(DFRAG_AH(c))
      } else if (qt == 1) {
#pragma unroll
        for (int c = 0; c < 20; ++c) { if (c < 12) DMFMA(DFRAG_AH(20 + c)) else DMFMA(DFRAG_CTX(c - 12)) }
      } else if (qt == 2) {
#pragma unroll
        for (int c = 0; c < 20; ++c) { if (c < 8) DMFMA(DFRAG_CTX(8 + c)) else DMFMA(DFRAG_DH(c - 8)) }
      } else {
#pragma unroll
        for (int c = 0; c < 20; ++c) DMFMA(DFRAG_DH(12 + c))
      }
#undef DMFMA
      if (qt != 0) {
#pragma unroll
        for (int r = 0; r < 4; ++r)
          comb[(((ls * 3 + qt - 1) * 64 + lane) << 2) + r] = a0[r] + a1[r];
      }
      __syncthreads();
      if (qt == 0) {
        float z[4];
#pragma unroll
        for (int r = 0; r < 4; ++r) {
          z[r] = a0[r] + a1[r] + biasD[r];
#pragma unroll
          for (int j = 0; j < 3; ++j) z[r] += comb[(((ls * 3 + j) * 64 + lane) << 2) + r];
        }
        float cn = fsig(z[1]) * dcState + fsig(z[0]) * ftanh(z[2]);
        dcState = cn;
        float h = fsig(z[3]) * ftanh(cn);
        stf_a(dhfF + (size_t)pw * 16384 + m16 * 1024 + nnD, h);
        unsigned hb = f2bfbits(h);
        unsigned b0 = __shfl(hb, m16);
        unsigned b1 = __shfl(hb, m16 + 16);
        unsigned b2 = __shfl(hb, m16 + 32);
        unsigned b3 = __shfl(hb, m16 + 48);
        if (kq == 0) {
          unsigned long long u = (unsigned long long)(b0 | (b1 << 16))
                               | ((unsigned long long)(b2 | (b3 << 16)) << 32);
          stull_a(dhb8 + ((size_t)(pw * 16 + m16)) * 256 + strip, u);
        }
      }
      __syncthreads();
      if (tid == 0) sig(flg, DHFL + (bid - 64), t);
    }
  } else if (bid < 224) {
    // ======== MERGED ATT+CTX: 2 blocks/batch; e/softmax duplicated + ctx half ========
    const int cbid = bid - 192;              // 0..31
    const int b = cbid >> 1, h2 = cbid & 1;
    const int mlenb = p.mlen[b];
    ushort_t* locu = (ushort_t*)(smc + M_LOCU);
    float* qsm   = (float*)(smc + M_QSM);
    float* vsm   = (float*)(smc + M_VSM);
    float* esm   = (float*)(smc + M_ESM);
    float* red   = (float*)(smc + M_RED);
    float* smaw  = (float*)(smc + M_SMAW);
    float* smawc = (float*)(smc + M_SMAWC);
    ushort_t* memu2 = (ushort_t*)(smc + M_MEM);
    float* part  = (float*)(smc + M_PART);
    float* qred  = part;   // overlay: qred [8][128] (q phase) / part (ctx phase)

    bf16x8_t wLd[8];
#pragma unroll
    for (int at = 0; at < 8; ++at)
      wLd[at] = pack_from_f4(p.Wld + ((size_t)(at * 16 + m16)) * 32 + kq * 8);
    bf16x8_t wC[2][2];
#pragma unroll
    for (int ft = 0; ft < 2; ++ft)
#pragma unroll
      for (int ck = 0; ck < 2; ++ck) {
        float tmp[8];
#pragma unroll
        for (int jj = 0; jj < 8; ++jj) {
          int k2 = ck * 32 + kq * 8 + jj;
          float vv = 0.f;
          if (k2 < 62) { int ch = (k2 < 31) ? 0 : 1; int k = k2 - 31 * ch;
            vv = p.Wc[((size_t)(ft * 16 + m16) * 2 + ch) * 31 + k]; }
          tmp[jj] = vv;
        }
        wC[ft][ck] = packbf8(tmp);
      }
    uint_t pmreg[2][8][2];
#pragma unroll
    for (int u = 0; u < 2; ++u) {
      int sloc = (wid * 2 + u) * 16 + m16;
#pragma unroll
      for (int at = 0; at < 8; ++at)
#pragma unroll
        for (int rp = 0; rp < 2; ++rp) {
          const float* src = pmF + ((size_t)(b * 256 + sloc)) * 128 + at * 16 + kq * 4 + rp * 2;
          pmreg[u][at][rp] = f2bfbits(src[0]) | (f2bfbits(src[1]) << 16);
        }
    }
    // one-time: stage mem[b][:, h2*256 .. +256] as bf16
    for (int i = tid; i < 16384; i += 512) {
      int s = i >> 6, c4 = i & 63;
      float4 m = *(const float4*)(p.memory + ((size_t)(b * 256 + s)) * 512 + h2 * 256 + c4 * 4);
      ushort_t* dst = memu2 + s * 256 + c4 * 4;
      dst[0] = (ushort_t)f2bfbits(m.x);
      dst[1] = (ushort_t)f2bfbits(m.y);
      dst[2] = (ushort_t)f2bfbits(m.z);
      dst[3] = (ushort_t)f2bfbits(m.w);
    }
    if (tid < 128) vsm[tid] = p.v[tid];
    if (tid < 256) { smaw[tid] = 0.f; smawc[tid] = 0.f; }
    __syncthreads();

    for (int t = 0; t < TSTEPS; ++t) {
      const int pc = t & 1;
      // conv(t) from own-LDS aw/awc (prev step): overlaps the ah wait
#pragma unroll
      for (int u = 0; u < 4; ++u) {
        int task = wid * 4 + u;
        int stile = task >> 1, ft = task & 1;
        int scol = stile * 16 + m16;
        f32x4_t acc = {0,0,0,0};
#pragma unroll
        for (int ck = 0; ck < 2; ++ck) {
          float tmp[8];
#pragma unroll
          for (int jj = 0; jj < 8; ++jj) {
            int k2 = ck * 32 + kq * 8 + jj;
            float vv = 0.f;
            if (k2 < 62) {
              int ch = (k2 < 31) ? 0 : 1; int k = k2 - 31 * ch;
              int sp = scol + k - 15;
              if (sp >= 0 && sp < 256) vv = (ch ? smawc : smaw)[sp];
            }
            tmp[jj] = vv;
          }
          acc = MFMA16(wC[ft][ck], packbf8(tmp), acc);
        }
#pragma unroll
        for (int r = 0; r < 4; ++r)
          locu[scol * 40 + ft * 16 + kq * 4 + r] = (ushort_t)f2bfbits(acc[r]);
      }
      // waits: ah(t)+qp fresh; DHFL stale (ctxb slot guard); PRF (awGF ring)
      if (tid < 64) pollge(flg, AHF + tid, t + 1, rep);
      else if (tid < 192) pollge(flg, DHFL + (tid - 64), t - 1, rep);
      else if (tid < 200) pollge(flg, PRF + (tid - 192), t - 3, rep);
      __syncthreads();
      // q[b] = sum over 64 A-block partials — 8 x 8B agent loads/thread
      {
        int a2 = (tid & 63) * 2, g = tid >> 6;    // 8 groups x 8 blocks
        const unsigned long long* qps =
            (const unsigned long long*)(qpF + (size_t)(t & 1) * 131072 + b * 128 + a2);
        float sx = 0.f, sy = 0.f;
#pragma unroll
        for (int j = 0; j < 8; ++j) {
          unsigned long long uv = ldull_a(qps + (size_t)(g * 8 + j) * 1024);
          float2 f = __builtin_bit_cast(float2, uv);
          sx += f.x; sy += f.y;
        }
        qred[g * 128 + a2] = sx;
        qred[g * 128 + a2 + 1] = sy;
      }
      __syncthreads();
      if (tid < 128) {
        float s = 0.f;
#pragma unroll
        for (int g = 0; g < 8; ++g) s += qred[g * 128 + tid];
        qsm[tid] = s;
      }
      __syncthreads();
      // fused pa+e: 2 s-tiles per wave
#pragma unroll
      for (int u = 0; u < 2; ++u) {
        int sloc = (wid * 2 + u) * 16 + m16;
        bf16x8_t Bfrag = ldbf8(locu + sloc * 40 + kq * 8);
        float eacc = 0.f;
#pragma unroll
        for (int at = 0; at < 8; ++at) {
          f32x4_t C = {0,0,0,0};
          C = MFMA16(wLd[at], Bfrag, C);
#pragma unroll
          for (int r = 0; r < 4; ++r) {
            int a = at * 16 + kq * 4 + r;
            uint_t pw_ = pmreg[u][at][r >> 1];
            float pmv = bf2f((ushort_t)((r & 1) ? (pw_ >> 16) : (pw_ & 0xFFFF)));
            eacc = fmaf(vsm[a], ftanh(C[r] + qsm[a] + pmv), eacc);
          }
        }
        eacc += __shfl_xor(eacc, 16);
        eacc += __shfl_xor(eacc, 32);
        if (sloc >= mlenb) eacc = -1.0e9f;
        if (kq == 0) esm[sloc] = eacc;
      }
      __syncthreads();
      // softmax over 256
      float ev = 0.f;
      if (tid < 256) {
        ev = esm[tid];
        float mv = ev;
        for (int o = 32; o; o >>= 1) mv = fmaxf(mv, __shfl_xor(mv, o));
        if (lane == 0) red[wid] = mv;
      }
      __syncthreads();
      float gmax = fmaxf(fmaxf(red[0], red[1]), fmaxf(red[2], red[3]));
      float pv = 0.f;
      if (tid < 256) {
        pv = __expf(ev - gmax);
        float sv = pv;
        for (int o = 32; o; o >>= 1) sv += __shfl_xor(sv, o);
        if (lane == 0) red[8 + wid] = sv;
      }
      __syncthreads();
      float gsum = red[8] + red[9] + red[10] + red[11];
      float awv = 0.f;
      if (tid < 256) {
        awv = pv / gsum;
        smaw[tid] = awv;
        smawc[tid] += awv;
        if (h2 == 0) stf_a(awGF + (size_t)(t & 3) * 4096 + b * 256 + tid, awv);
      }
      __syncthreads();
      // ctx(t) half = aw(t) . mem[b][:, h2*256..+256]  (all in LDS)
      {
        const int c = tid & 127, sg = tid >> 7;
        const uint_t* mrow = (const uint_t*)memu2;
        float c0 = 0.f, c1 = 0.f;
#pragma unroll 8
        for (int si = 0; si < 64; ++si) {
          int s = sg * 64 + si;
          uint_t mm = mrow[s * 128 + c];
          float av = smaw[s];
          c0 = fmaf(bf2f((ushort_t)(mm & 0xFFFF)), av, c0);
          c1 = fmaf(bf2f((ushort_t)(mm >> 16)), av, c1);
        }
        part[sg * 256 + c * 2] = c0;
        part[sg * 256 + c * 2 + 1] = c1;
      }
      __syncthreads();
      if (tid < 64) {
        unsigned pk[4];
#pragma unroll
        for (int j = 0; j < 4; ++j) {
          int col = tid * 4 + j;
          float v = part[col] + part[256 + col] + part[512 + col] + part[768 + col];
          pk[j] = f2bfbits(v);
        }
        unsigned long long u = (unsigned long long)(pk[0] | (pk[1] << 16))
                             | ((unsigned long long)(pk[2] | (pk[3] << 16)) << 32);
        stull_a(ctxb8 + ((size_t)(pc * 16 + b)) * 128 + h2 * 64 + tid, u);
      }
      __syncthreads();   // drain ctxb + awGF stores
      if (tid == 0) {
        sig(flg, CTXF + cbid, t + 1);
        if (h2 == 0) sig(flg, AWF + b, t + 1);
      }
      // off-path output store
      if (h2 == 0 && tid < 256) out_al[((size_t)b * 400 + t) * 256 + tid] = awv;
    }
  } else if (bid < 232) {
    // ======== PROJ path: mel/gate = Wdh.dh(t-1) + M.aw(t-1) + bias ========
    const int wv = (bid - 224) * 8 + wid;   // 0..63
    int rows[2] = {wv * 2, wv * 2 + 1};
    float wdh[2][16], mreg[2][16][4], biasr[2];
#pragma unroll
    for (int rr = 0; rr < 2; ++rr) {
      int row = rows[rr];
      biasr[rr] = 0.f;
#pragma unroll
      for (int j = 0; j < 16; ++j) wdh[rr][j] = 0.f;
#pragma unroll
      for (int b2 = 0; b2 < 16; ++b2)
#pragma unroll
        for (int j = 0; j < 4; ++j) mreg[rr][b2][j] = 0.f;
      if (row <= 80) {
        const float* wsrc = (row < 80) ? p.Wproj + (size_t)row * 1536 : p.Wgate;
#pragma unroll
        for (int j = 0; j < 16; ++j) wdh[rr][j] = wsrc[lane + 64 * j];
        biasr[rr] = (row < 80) ? p.bproj[row] : p.bgate[0];
#pragma unroll
        for (int b2 = 0; b2 < 16; ++b2)
#pragma unroll
          for (int j = 0; j < 4; ++j)
            mreg[rr][b2][j] = Mx[((size_t)b2 * 81 + row) * 256 + lane + 64 * j];
      }
    }
    float* dhp = (float*)(smc + P_DHP);
    float* awp = (float*)(smc + P_AWP);
    __syncthreads();
    for (int t = 1; t <= TSTEPS; ++t) {
      const int pw = (t + 1) & 1;
      if (tid < 128) pollge_bk(flg, DHFL + tid, t, rep);
      else if (tid < 144) pollge_bk(flg, AWF + tid - 128, t, rep);
      __syncthreads();
      {
        const unsigned long long* ag = (const unsigned long long*)(awGF + (size_t)((t - 1) & 3) * 4096);
        const unsigned long long* dg = (const unsigned long long*)(dhfF + (size_t)pw * 16384);
        unsigned long long tw[4], td[16];
#pragma unroll
        for (int i = 0; i < 4; ++i) tw[i] = ldull_a(ag + tid + i * 512);
#pragma unroll
        for (int i = 0; i < 16; ++i) td[i] = ldull_a(dg + tid + i * 512);
#pragma unroll
        for (int i = 0; i < 4; ++i) ((unsigned long long*)awp)[tid + i * 512] = tw[i];
#pragma unroll
        for (int i = 0; i < 16; ++i) ((unsigned long long*)dhp)[tid + i * 512] = td[i];
      }
      __syncthreads();
      if (wv <= 40) {
        for (int b2 = 0; b2 < 16; ++b2) {
          float h[16];
#pragma unroll
          for (int j = 0; j < 16; ++j) h[j] = dhp[b2 * 1024 + lane + 64 * j];
#pragma unroll
          for (int rr = 0; rr < 2; ++rr) {
            if (rows[rr] > 80) continue;
            float d = 0.f;
#pragma unroll
            for (int j = 0; j < 16; ++j) d = fmaf(wdh[rr][j], h[j], d);
#pragma unroll
            for (int j = 0; j < 4; ++j) d = fmaf(mreg[rr][b2][j], awp[b2 * 256 + lane + 64 * j], d);
            for (int o = 32; o; o >>= 1) d += __shfl_xor(d, o);
            if (lane == 0) {
              d += biasr[rr];
              if (rows[rr] < 80) out_mel[((size_t)b2 * 80 + rows[rr]) * 400 + (t - 1)] = d;
              else out_gate[(size_t)b2 * 400 + (t - 1)] = d;
            }
          }
        }
      }
      __syncthreads();
      if (tid == 0) sig(flg, PRF + (bid - 224), t);
    }
  }
}

extern "C" void kernel_launch(void* const* d_in, const int* in_sizes, int n_in,
                              void* d_out, int out_size, void* d_ws, size_t ws_size,
                              hipStream_t stream) {
  (void)in_sizes; (void)n_in; (void)out_size; (void)ws_size;
  Ptrs p;
  p.memory = (const float*)d_in[0];
  p.dec_in = (const float*)d_in[1];
  p.Wpre1  = (const float*)d_in[2];
  p.Wpre2  = (const float*)d_in[3];
  p.Wih_a  = (const float*)d_in[4];
  p.Whh_a  = (const float*)d_in[5];
  p.bih_a  = (const float*)d_in[6];
  p.bhh_a  = (const float*)d_in[7];
  p.Wq     = (const float*)d_in[8];
  p.Wm     = (const float*)d_in[9];
  p.v      = (const float*)d_in[10];
  p.Wc     = (const float*)d_in[11];
  p.Wld    = (const float*)d_in[12];
  p.Wih_d  = (const float*)d_in[13];
  p.Whh_d  = (const float*)d_in[14];
  p.bih_d  = (const float*)d_in[15];
  p.bhh_d  = (const float*)d_in[16];
  p.Wproj  = (const float*)d_in[17];
  p.bproj  = (const float*)d_in[18];
  p.Wgate  = (const float*)d_in[19];
  p.bgate  = (const float*)d_in[20];
  p.mlen   = (const int*)d_in[21];
  p.ws  = (float*)d_ws;
  p.out = (float*)d_out;

  static bool attr_done = false;
  if (!attr_done) {
    hipFuncSetAttribute((const void*)k_scan,
                        hipFuncAttributeMaxDynamicSharedMemorySize, SMEM_BYTES);
    attr_done = true;
  }

  hipLaunchKernelGGL(k_zero,      dim3((ZERO_COUNT + 255) / 256), dim3(256), 0, stream, p);
  hipLaunchKernelGGL(k_transpose, dim3(336), dim3(256), 0, stream, p);
  hipLaunchKernelGGL(k_prenet,    dim3(400), dim3(256), 0, stream, p);
  hipLaunchKernelGGL(k_procmem,   dim3(256), dim3(256), 0, stream, p);
  hipLaunchKernelGGL(k_premix,    dim3(16),  dim3(512), 0, stream, p);
  hipLaunchKernelGGL(k_scan,      dim3(232), dim3(512), SMEM_BYTES, stream, p);
}